// Round 4
// baseline (14929.747 us; speedup 1.0000x reference)
//
#include <hip/hip_runtime.h>
#include <hip/hip_bf16.h>
#include <math.h>

#define V_ 50257
#define L_ 6
#define H_ 12
#define D_ 768
#define HD_ 64
#define FF_ 3072
#define B_ 2
#define T_ 1024
#define NTOK (B_*T_)
#define EOS_ 50256

// ---------------- embedding: x = token_emb[idx] + pos_emb ----------------
__global__ void k_embed(const int* __restrict__ idx, const float* __restrict__ tok,
                        const float* __restrict__ pos, float* __restrict__ x) {
  int gid = blockIdx.x * blockDim.x + threadIdx.x;
  const int total = NTOK * D_;
  if (gid >= total) return;
  int row = gid / D_;
  int d = gid - row * D_;
  int t = row & (T_ - 1);
  x[gid] = tok[(size_t)idx[row] * D_ + d] + pos[t * D_ + d];
}

// ---------------- doc ids: exclusive prefix count of EOS ----------------
__global__ void k_docid(const int* __restrict__ idx, int* __restrict__ doc) {
  int b = threadIdx.x;
  if (b >= B_) return;
  int c = 0;
  for (int t = 0; t < T_; ++t) {
    int e = (idx[b*T_ + t] == EOS_) ? 1 : 0;
    doc[b*T_ + t] = c;
    c += e;
  }
}

// ---------------- layernorm: one wave (64 lanes) per row ----------------
__global__ void k_ln(const float* __restrict__ x, const float* __restrict__ g,
                     const float* __restrict__ b, float* __restrict__ out) {
  int row = blockIdx.x;
  const float* xr = x + (size_t)row * D_;
  int lane = threadIdx.x;
  float vals[D_/64];
  float s = 0.f;
  #pragma unroll
  for (int i = 0; i < D_/64; ++i) { vals[i] = xr[lane + i*64]; s += vals[i]; }
  #pragma unroll
  for (int o = 1; o < 64; o <<= 1) s += __shfl_xor(s, o);
  float mu = s * (1.f/D_);
  float v = 0.f;
  #pragma unroll
  for (int i = 0; i < D_/64; ++i) { float d0 = vals[i]-mu; v += d0*d0; }
  #pragma unroll
  for (int o = 1; o < 64; o <<= 1) v += __shfl_xor(v, o);
  float inv = rsqrtf(v * (1.f/D_) + 1e-5f);
  #pragma unroll
  for (int i = 0; i < D_/64; ++i) {
    int d = lane + i*64;
    out[(size_t)row*D_ + d] = (vals[i]-mu)*inv*g[d] + b[d];
  }
}

// ------- generic GEMM: C = A[M,K] @ B[K,N] + bias (+gelu) (+R) -------
// R may alias C (residual add in-place) -> no __restrict__ on them.
__global__ void k_gemm(const float* __restrict__ A, const float* __restrict__ Bm,
                       const float* __restrict__ bias, const float* R,
                       float* C, int M, int N, int K, int gelu) {
  __shared__ float As[32][33];
  __shared__ float Bs[32][33];
  int tx = threadIdx.x, ty = threadIdx.y;
  int bx = blockIdx.x * 32, by = blockIdx.y * 32;
  int r0 = ty*2, r1 = r0+1, c0 = tx*2, c1 = c0+1;
  float acc00=0.f, acc01=0.f, acc10=0.f, acc11=0.f;
  for (int k0 = 0; k0 < K; k0 += 32) {
    #pragma unroll
    for (int i = 0; i < 2; ++i) {
      int ar = by + r0 + i;
      int br = k0 + r0 + i;
      #pragma unroll
      for (int j = 0; j < 2; ++j) {
        int ac = k0 + c0 + j;
        int bc = bx + c0 + j;
        As[r0+i][c0+j] = (ar < M) ? A[(size_t)ar*K + ac] : 0.f;
        Bs[r0+i][c0+j] = (bc < N) ? Bm[(size_t)br*N + bc] : 0.f;
      }
    }
    __syncthreads();
    #pragma unroll
    for (int kk = 0; kk < 32; ++kk) {
      float a0 = As[r0][kk], a1 = As[r1][kk];
      float b0 = Bs[kk][c0], b1 = Bs[kk][c1];
      acc00 += a0*b0; acc01 += a0*b1; acc10 += a1*b0; acc11 += a1*b1;
    }
    __syncthreads();
  }
  float accs[2][2] = {{acc00,acc01},{acc10,acc11}};
  #pragma unroll
  for (int i = 0; i < 2; ++i) {
    int rr = by + r0 + i;
    if (rr >= M) continue;
    #pragma unroll
    for (int j = 0; j < 2; ++j) {
      int cc = bx + c0 + j;
      if (cc >= N) continue;
      float v = accs[i][j] + bias[cc];
      if (gelu) v = 0.5f * v * (1.f + erff(v * 0.70710678118654752f));
      if (R) v += R[(size_t)rr*N + cc];
      C[(size_t)rr*N + cc] = v;
    }
  }
}

// ------- logits NT GEMM: C[M,N] = A[M,K] @ Bt[N,K]^T, f32 out -------
__global__ void k_gemm_nt(const float* __restrict__ A, const float* __restrict__ Bt,
                          float* __restrict__ C, int M, int N, int K) {
  __shared__ float As[32][33];
  __shared__ float Bs[32][33];
  int tx = threadIdx.x, ty = threadIdx.y;
  int bx = blockIdx.x * 32, by = blockIdx.y * 32;
  int r0 = ty*2, r1 = r0+1, c0 = tx*2, c1 = c0+1;
  float acc00=0.f, acc01=0.f, acc10=0.f, acc11=0.f;
  for (int k0 = 0; k0 < K; k0 += 32) {
    #pragma unroll
    for (int i = 0; i < 2; ++i) {
      int ar = by + r0 + i;
      int br = bx + r0 + i;
      #pragma unroll
      for (int j = 0; j < 2; ++j) {
        int kc = k0 + c0 + j;
        As[r0+i][c0+j] = (ar < M) ? A[(size_t)ar*K + kc] : 0.f;
        Bs[r0+i][c0+j] = (br < N) ? Bt[(size_t)br*K + kc] : 0.f;
      }
    }
    __syncthreads();
    #pragma unroll
    for (int kk = 0; kk < 32; ++kk) {
      float a0 = As[r0][kk], a1 = As[r1][kk];
      float b0 = Bs[c0][kk], b1 = Bs[c1][kk];
      acc00 += a0*b0; acc01 += a0*b1; acc10 += a1*b0; acc11 += a1*b1;
    }
    __syncthreads();
  }
  float accs[2][2] = {{acc00,acc01},{acc10,acc11}};
  #pragma unroll
  for (int i = 0; i < 2; ++i) {
    int rr = by + r0 + i;
    if (rr >= M) continue;
    #pragma unroll
    for (int j = 0; j < 2; ++j) {
      int cc = bx + c0 + j;
      if (cc >= N) continue;
      C[(size_t)rr*N + cc] = accs[i][j];
    }
  }
}

// ---------------- attention: one wave per (b,h,q) row ----------------
__global__ void k_attn(const float* __restrict__ qkv, const int* __restrict__ doc,
                       float* __restrict__ y) {
  int qi = blockIdx.x, h = blockIdx.y, b = blockIdx.z;
  int lane = threadIdx.x;
  __shared__ float qs[HD_];
  __shared__ float sc[T_];
  int rowq = b*T_ + qi;
  const float* Q = qkv + (size_t)rowq*(3*D_) + h*HD_;
  qs[lane] = Q[lane];
  __syncthreads();
  int mydoc = doc[rowq];
  float lmax = -1e30f;
  for (int k = lane; k <= qi; k += 64) {
    float s = -1e30f;
    if (doc[b*T_ + k] == mydoc) {
      const float* Kp = qkv + (size_t)(b*T_ + k)*(3*D_) + D_ + h*HD_;
      float acc = 0.f;
      #pragma unroll 8
      for (int d = 0; d < HD_; ++d) acc += qs[d]*Kp[d];
      s = acc * 0.125f;   // 1/sqrt(64)
    }
    sc[k] = s;
    lmax = fmaxf(lmax, s);
  }
  #pragma unroll
  for (int o = 1; o < 64; o <<= 1) lmax = fmaxf(lmax, __shfl_xor(lmax, o));
  __syncthreads();
  float lsum = 0.f;
  for (int k = lane; k <= qi; k += 64) {
    float p = (sc[k] > -1e29f) ? __expf(sc[k]-lmax) : 0.f;
    sc[k] = p;
    lsum += p;
  }
  #pragma unroll
  for (int o = 1; o < 64; o <<= 1) lsum += __shfl_xor(lsum, o);
  __syncthreads();
  float inv = 1.f / lsum;
  float acc = 0.f;
  const float* Vb = qkv + (size_t)(b*T_)*(3*D_) + 2*D_ + h*HD_ + lane;
  for (int k = 0; k <= qi; ++k) {
    acc += sc[k] * Vb[(size_t)k*(3*D_)];
  }
  y[(size_t)rowq*D_ + h*HD_ + lane] = acc * inv;
}

// ---------------- per-row log-softmax loss terms ----------------
__global__ void k_rowloss(const float* __restrict__ logits,
                          const int* __restrict__ tgt, float* __restrict__ rl) {
  __shared__ float red[4];
  int row = blockIdx.x;
  const float* lr = logits + (size_t)row * V_;
  int tid = threadIdx.x;
  float m = -1e30f;
  for (int v = tid; v < V_; v += 256) m = fmaxf(m, lr[v]);
  #pragma unroll
  for (int o = 1; o < 64; o <<= 1) m = fmaxf(m, __shfl_xor(m, o));
  if ((tid & 63) == 0) red[tid >> 6] = m;
  __syncthreads();
  m = fmaxf(fmaxf(red[0], red[1]), fmaxf(red[2], red[3]));
  __syncthreads();
  float s = 0.f;
  for (int v = tid; v < V_; v += 256) s += __expf(lr[v] - m);
  #pragma unroll
  for (int o = 1; o < 64; o <<= 1) s += __shfl_xor(s, o);
  if ((tid & 63) == 0) red[tid >> 6] = s;
  __syncthreads();
  if (tid == 0) {
    s = red[0]+red[1]+red[2]+red[3];
    rl[row] = (logf(s) + m) - lr[tgt[row]];
  }
}

// ---------------- final loss = mean(rl) ----------------
__global__ void k_loss(const float* __restrict__ rl, float* __restrict__ out) {
  __shared__ float red[4];
  int tid = threadIdx.x;
  float s = 0.f;
  for (int i = tid; i < NTOK; i += 256) s += rl[i];
  #pragma unroll
  for (int o = 1; o < 64; o <<= 1) s += __shfl_xor(s, o);
  if ((tid & 63) == 0) red[tid >> 6] = s;
  __syncthreads();
  if (tid == 0) {
    s = red[0]+red[1]+red[2]+red[3];
    out[0] = s / (float)NTOK;
  }
}

extern "C" void kernel_launch(void* const* d_in, const int* in_sizes, int n_in,
                              void* d_out, int out_size, void* d_ws, size_t ws_size,
                              hipStream_t stream) {
  const int*   idx   = (const int*)d_in[0];
  const int*   tgt   = (const int*)d_in[1];
  const float* tok   = (const float*)d_in[2];
  const float* pos   = (const float*)d_in[3];
  const float* ln1_g = (const float*)d_in[4];
  const float* ln1_b = (const float*)d_in[5];
  const float* ln2_g = (const float*)d_in[6];
  const float* ln2_b = (const float*)d_in[7];
  const float* W_qkv = (const float*)d_in[8];
  const float* b_qkv = (const float*)d_in[9];
  const float* W_proj= (const float*)d_in[10];
  const float* b_proj= (const float*)d_in[11];
  const float* W_fc1 = (const float*)d_in[12];
  const float* b_fc1 = (const float*)d_in[13];
  const float* W_fc2 = (const float*)d_in[14];
  const float* b_fc2 = (const float*)d_in[15];
  const float* lnf_g = (const float*)d_in[16];
  const float* lnf_b = (const float*)d_in[17];

  float* out = (float*)d_out;   // reference output dtype is float32

  // d_out (411.7 MB f32: logits + loss, only written at the end) doubles as
  // scratch for the big per-layer activations; all dead before the logits GEMM.
  // Only h (live DURING logits GEMM), doc, rl live in d_ws (6.31 MB).
  char* ob = (char*)d_out;
  float* x   = (float*)(ob + 0);
  float* qkv = (float*)(ob + (size_t)6291456);
  float* y   = (float*)(ob + (size_t)25165824);
  float* tff = (float*)(ob + (size_t)31457280);   // ends 56,623,104 < 411,705,348

  char* wb = (char*)d_ws;
  float* h   = (float*)(wb + 0);
  int*   doc = (int*)  (wb + (size_t)6291456);
  float* rl  = (float*)(wb + (size_t)6299648);

  k_embed<<<(NTOK*D_ + 255)/256, 256, 0, stream>>>(idx, tok, pos, x);
  k_docid<<<1, 64, 0, stream>>>(idx, doc);

  dim3 blk(16,16);
  for (int l = 0; l < L_; ++l) {
    k_ln<<<NTOK, 64, 0, stream>>>(x, ln1_g + l*D_, ln1_b + l*D_, h);
    k_gemm<<<dim3((3*D_)/32, NTOK/32), blk, 0, stream>>>(
        h, W_qkv + (size_t)l*D_*3*D_, b_qkv + (size_t)l*3*D_, nullptr, qkv,
        NTOK, 3*D_, D_, 0);
    k_attn<<<dim3(T_, H_, B_), 64, 0, stream>>>(qkv, doc, y);
    k_gemm<<<dim3(D_/32, NTOK/32), blk, 0, stream>>>(
        y, W_proj + (size_t)l*D_*D_, b_proj + (size_t)l*D_, x, x,
        NTOK, D_, D_, 0);
    k_ln<<<NTOK, 64, 0, stream>>>(x, ln2_g + l*D_, ln2_b + l*D_, h);
    k_gemm<<<dim3(FF_/32, NTOK/32), blk, 0, stream>>>(
        h, W_fc1 + (size_t)l*D_*FF_, b_fc1 + (size_t)l*FF_, nullptr, tff,
        NTOK, FF_, D_, 1);
    k_gemm<<<dim3(D_/32, NTOK/32), blk, 0, stream>>>(
        tff, W_fc2 + (size_t)l*FF_*D_, b_fc2 + (size_t)l*D_, x, x,
        NTOK, D_, FF_, 0);
  }
  // final LN into ws (x lives in d_out and is about to be overwritten)
  k_ln<<<NTOK, 64, 0, stream>>>(x, lnf_g, lnf_b, h);
  // logits GEMM overwrites ALL of d_out's logit region; reads only h (ws) + tok
  k_gemm_nt<<<dim3((V_ + 31)/32, NTOK/32), blk, 0, stream>>>(
      h, tok, out, NTOK, V_, D_);
  k_rowloss<<<NTOK, 256, 0, stream>>>(out, tgt, rl);
  k_loss<<<1, 256, 0, stream>>>(rl, out + (size_t)NTOK*V_);
}

// Round 5
// 5899.228 us; speedup vs baseline: 2.5308x; 2.5308x over previous
//
#include <hip/hip_runtime.h>
#include <hip/hip_bf16.h>
#include <math.h>

#define V_ 50257
#define L_ 6
#define H_ 12
#define D_ 768
#define HD_ 64
#define FF_ 3072
#define B_ 2
#define T_ 1024
#define NTOK (B_*T_)
#define EOS_ 50256

typedef __attribute__((ext_vector_type(8))) short s16x8;
typedef __attribute__((ext_vector_type(4))) float f32x4;

__device__ __forceinline__ short f2bf(float f) {
  __hip_bfloat16 h = __float2bfloat16(f);
  return *reinterpret_cast<short*>(&h);
}

// ---------------- embedding: x = token_emb[idx] + pos_emb ----------------
__global__ void k_embed(const int* __restrict__ idx, const float* __restrict__ tok,
                        const float* __restrict__ pos, float* __restrict__ x) {
  int gid = blockIdx.x * blockDim.x + threadIdx.x;
  const int total = NTOK * D_;
  if (gid >= total) return;
  int row = gid / D_;
  int d = gid - row * D_;
  int t = row & (T_ - 1);
  x[gid] = tok[(size_t)idx[row] * D_ + d] + pos[t * D_ + d];
}

// ---------------- doc ids: exclusive prefix count of EOS ----------------
__global__ void k_docid(const int* __restrict__ idx, int* __restrict__ doc) {
  int b = threadIdx.x;
  if (b >= B_) return;
  int c = 0;
  for (int t = 0; t < T_; ++t) {
    int e = (idx[b*T_ + t] == EOS_) ? 1 : 0;
    doc[b*T_ + t] = c;
    c += e;
  }
}

// ---------------- layernorm: one wave per row, bf16 out ----------------
__global__ void k_ln(const float* __restrict__ x, const float* __restrict__ g,
                     const float* __restrict__ b, __hip_bfloat16* __restrict__ out) {
  int row = blockIdx.x;
  const float* xr = x + (size_t)row * D_;
  int lane = threadIdx.x;
  float vals[D_/64];
  float s = 0.f;
  #pragma unroll
  for (int i = 0; i < D_/64; ++i) { vals[i] = xr[lane + i*64]; s += vals[i]; }
  #pragma unroll
  for (int o = 1; o < 64; o <<= 1) s += __shfl_xor(s, o);
  float mu = s * (1.f/D_);
  float v = 0.f;
  #pragma unroll
  for (int i = 0; i < D_/64; ++i) { float d0 = vals[i]-mu; v += d0*d0; }
  #pragma unroll
  for (int o = 1; o < 64; o <<= 1) v += __shfl_xor(v, o);
  float inv = rsqrtf(v * (1.f/D_) + 1e-5f);
  #pragma unroll
  for (int i = 0; i < D_/64; ++i) {
    int d = lane + i*64;
    out[(size_t)row*D_ + d] = __float2bfloat16((vals[i]-mu)*inv*g[d] + b[d]);
  }
}

// ------- weight transpose+cast: in f32 [K,N] (per layer) -> out bf16 [N,K] -------
__global__ void k_wt(const float* __restrict__ in, __hip_bfloat16* __restrict__ out,
                     int K, int N) {
  __shared__ float tile[32][33];
  int l = blockIdx.z;
  const float* src = in + (size_t)l*K*N;
  __hip_bfloat16* dst = out + (size_t)l*N*K;
  int n0 = blockIdx.x*32, k0 = blockIdx.y*32;
  int tx = threadIdx.x, ty = threadIdx.y;
  #pragma unroll
  for (int i = 0; i < 4; ++i)
    tile[ty + i*8][tx] = src[(size_t)(k0 + ty + i*8)*N + n0 + tx];
  __syncthreads();
  #pragma unroll
  for (int i = 0; i < 4; ++i)
    dst[(size_t)(n0 + ty + i*8)*K + k0 + tx] = __float2bfloat16(tile[tx][ty + i*8]);
}

// ------- MFMA NT GEMM: C[M,N] = A[M,K]bf16 @ Bt[N,K]^T (+bias)(+gelu)(+resid) -------
// Bt is bf16 (Bh) or f32 (Bf, converted during staging). Out f32 or bf16.
// BM=BN=128, BK=64, 256 threads = 4 waves (2x2), wave tile 64x64 = 4x4 frags.
__global__ __launch_bounds__(256) void k_mfma_nt(
    const __hip_bfloat16* __restrict__ A,
    const __hip_bfloat16* __restrict__ Bh,
    const float* __restrict__ Bf,
    const float* __restrict__ bias,
    const float* resid,
    float* outf, __hip_bfloat16* outh,
    int M, int N, int K, int gelu)
{
  __shared__ __align__(16) short lds_a[128*64];
  __shared__ __align__(16) short lds_b[128*64];
  const int t = threadIdx.x;
  const int m0 = blockIdx.y * 128;
  const int n0 = blockIdx.x * 128;
  const int lane = t & 63;
  const int wid = t >> 6;
  const int wm = (wid >> 1) * 64;
  const int wn = (wid & 1) * 64;
  const int lrow = lane & 15;
  const int lkb = (lane >> 4) * 16;   // byte offset of this lane's 8-elem k-group

  f32x4 acc[4][4];
  #pragma unroll
  for (int i = 0; i < 4; ++i)
    #pragma unroll
    for (int j = 0; j < 4; ++j)
      acc[i][j] = (f32x4){0.f, 0.f, 0.f, 0.f};

  for (int k0 = 0; k0 < K; k0 += 64) {
    // ---- stage A tile [128][64] bf16, XOR-swizzled ----
    #pragma unroll
    for (int p = 0; p < 4; ++p) {
      int c = p*256 + t;
      int row = c >> 3;
      int colb = (c & 7) << 4;
      uint4 v = *(const uint4*)((const char*)A + ((size_t)(m0+row)*K + k0)*2 + colb);
      int dst = (row*128 + colb) ^ ((row & 7) << 4);
      *(uint4*)((char*)lds_a + dst) = v;
    }
    // ---- stage B tile [128][64] ----
    if (Bh) {
      #pragma unroll
      for (int p = 0; p < 4; ++p) {
        int c = p*256 + t;
        int row = c >> 3;
        int colb = (c & 7) << 4;
        int gn = n0 + row;
        uint4 v = {0u,0u,0u,0u};
        if (gn < N) v = *(const uint4*)((const char*)Bh + ((size_t)gn*K + k0)*2 + colb);
        int dst = (row*128 + colb) ^ ((row & 7) << 4);
        *(uint4*)((char*)lds_b + dst) = v;
      }
    } else {
      #pragma unroll
      for (int p = 0; p < 4; ++p) {
        int c = p*256 + t;
        int row = c >> 3;
        int colb = (c & 7) << 4;
        int gn = n0 + row;
        s16x8 s = {0,0,0,0,0,0,0,0};
        if (gn < N) {
          const char* src = (const char*)Bf + ((size_t)gn*K + k0)*4 + colb*2;
          float4 v0 = *(const float4*)src;
          float4 v1 = *(const float4*)(src + 16);
          s[0]=f2bf(v0.x); s[1]=f2bf(v0.y); s[2]=f2bf(v0.z); s[3]=f2bf(v0.w);
          s[4]=f2bf(v1.x); s[5]=f2bf(v1.y); s[6]=f2bf(v1.z); s[7]=f2bf(v1.w);
        }
        int dst = (row*128 + colb) ^ ((row & 7) << 4);
        *(s16x8*)((char*)lds_b + dst) = s;
      }
    }
    __syncthreads();
    // ---- 2 k-substeps of 32 ----
    #pragma unroll
    for (int ks = 0; ks < 2; ++ks) {
      s16x8 af[4], bfr[4];
      #pragma unroll
      for (int f = 0; f < 4; ++f) {
        int row = wm + f*16 + lrow;
        int off = (row*128 + ks*64 + lkb) ^ ((row & 7) << 4);
        af[f] = *(const s16x8*)((const char*)lds_a + off);
      }
      #pragma unroll
      for (int f = 0; f < 4; ++f) {
        int row = wn + f*16 + lrow;
        int off = (row*128 + ks*64 + lkb) ^ ((row & 7) << 4);
        bfr[f] = *(const s16x8*)((const char*)lds_b + off);
      }
      #pragma unroll
      for (int fm = 0; fm < 4; ++fm)
        #pragma unroll
        for (int fn = 0; fn < 4; ++fn)
          acc[fm][fn] = __builtin_amdgcn_mfma_f32_16x16x32_bf16(
              af[fm], bfr[fn], acc[fm][fn], 0, 0, 0);
    }
    __syncthreads();
  }
  // ---- epilogue: C/D layout col=lane&15, row=(lane>>4)*4+r ----
  const int crow = (lane >> 4) * 4;
  #pragma unroll
  for (int fm = 0; fm < 4; ++fm) {
    #pragma unroll
    for (int fn = 0; fn < 4; ++fn) {
      int col = n0 + wn + fn*16 + lrow;
      if (col >= N) continue;
      #pragma unroll
      for (int r = 0; r < 4; ++r) {
        int row = m0 + wm + fm*16 + crow + r;
        float v = acc[fm][fn][r];
        if (bias) v += bias[col];
        if (gelu) v = 0.5f * v * (1.f + erff(v * 0.70710678118654752f));
        if (resid) v += resid[(size_t)row*N + col];
        if (outf) outf[(size_t)row*N + col] = v;
        else      outh[(size_t)row*N + col] = __float2bfloat16(v);
      }
    }
  }
}

// ---------------- attention: one wave per (b,h,q) row; y out bf16 ----------------
__global__ void k_attn(const float* __restrict__ qkv, const int* __restrict__ doc,
                       __hip_bfloat16* __restrict__ y) {
  int qi = blockIdx.x, h = blockIdx.y, b = blockIdx.z;
  int lane = threadIdx.x;
  __shared__ float qs[HD_];
  __shared__ float sc[T_];
  int rowq = b*T_ + qi;
  const float* Q = qkv + (size_t)rowq*(3*D_) + h*HD_;
  qs[lane] = Q[lane];
  __syncthreads();
  int mydoc = doc[rowq];
  float lmax = -1e30f;
  for (int k = lane; k <= qi; k += 64) {
    float s = -1e30f;
    if (doc[b*T_ + k] == mydoc) {
      const float* Kp = qkv + (size_t)(b*T_ + k)*(3*D_) + D_ + h*HD_;
      float acc = 0.f;
      #pragma unroll 8
      for (int d = 0; d < HD_; ++d) acc += qs[d]*Kp[d];
      s = acc * 0.125f;
    }
    sc[k] = s;
    lmax = fmaxf(lmax, s);
  }
  #pragma unroll
  for (int o = 1; o < 64; o <<= 1) lmax = fmaxf(lmax, __shfl_xor(lmax, o));
  __syncthreads();
  float lsum = 0.f;
  for (int k = lane; k <= qi; k += 64) {
    float p = (sc[k] > -1e29f) ? __expf(sc[k]-lmax) : 0.f;
    sc[k] = p;
    lsum += p;
  }
  #pragma unroll
  for (int o = 1; o < 64; o <<= 1) lsum += __shfl_xor(lsum, o);
  __syncthreads();
  float inv = 1.f / lsum;
  float acc = 0.f;
  const float* Vb = qkv + (size_t)(b*T_)*(3*D_) + 2*D_ + h*HD_ + lane;
  for (int k = 0; k <= qi; ++k) {
    acc += sc[k] * Vb[(size_t)k*(3*D_)];
  }
  y[(size_t)rowq*D_ + h*HD_ + lane] = __float2bfloat16(acc * inv);
}

// ---------------- per-row log-softmax loss terms ----------------
__global__ void k_rowloss(const float* __restrict__ logits,
                          const int* __restrict__ tgt, float* __restrict__ rl) {
  __shared__ float red[4];
  int row = blockIdx.x;
  const float* lr = logits + (size_t)row * V_;
  int tid = threadIdx.x;
  float m = -1e30f;
  for (int v = tid; v < V_; v += 256) m = fmaxf(m, lr[v]);
  #pragma unroll
  for (int o = 1; o < 64; o <<= 1) m = fmaxf(m, __shfl_xor(m, o));
  if ((tid & 63) == 0) red[tid >> 6] = m;
  __syncthreads();
  m = fmaxf(fmaxf(red[0], red[1]), fmaxf(red[2], red[3]));
  __syncthreads();
  float s = 0.f;
  for (int v = tid; v < V_; v += 256) s += __expf(lr[v] - m);
  #pragma unroll
  for (int o = 1; o < 64; o <<= 1) s += __shfl_xor(s, o);
  if ((tid & 63) == 0) red[tid >> 6] = s;
  __syncthreads();
  if (tid == 0) {
    s = red[0]+red[1]+red[2]+red[3];
    rl[row] = (logf(s) + m) - lr[tgt[row]];
  }
}

// ---------------- final loss = mean(rl) ----------------
__global__ void k_loss(const float* __restrict__ rl, float* __restrict__ out) {
  __shared__ float red[4];
  int tid = threadIdx.x;
  float s = 0.f;
  for (int i = tid; i < NTOK; i += 256) s += rl[i];
  #pragma unroll
  for (int o = 1; o < 64; o <<= 1) s += __shfl_xor(s, o);
  if ((tid & 63) == 0) red[tid >> 6] = s;
  __syncthreads();
  if (tid == 0) {
    s = red[0]+red[1]+red[2]+red[3];
    out[0] = s / (float)NTOK;
  }
}

extern "C" void kernel_launch(void* const* d_in, const int* in_sizes, int n_in,
                              void* d_out, int out_size, void* d_ws, size_t ws_size,
                              hipStream_t stream) {
  const int*   idx   = (const int*)d_in[0];
  const int*   tgt   = (const int*)d_in[1];
  const float* tok   = (const float*)d_in[2];
  const float* pos   = (const float*)d_in[3];
  const float* ln1_g = (const float*)d_in[4];
  const float* ln1_b = (const float*)d_in[5];
  const float* ln2_g = (const float*)d_in[6];
  const float* ln2_b = (const float*)d_in[7];
  const float* W_qkv = (const float*)d_in[8];
  const float* b_qkv = (const float*)d_in[9];
  const float* W_proj= (const float*)d_in[10];
  const float* b_proj= (const float*)d_in[11];
  const float* W_fc1 = (const float*)d_in[12];
  const float* b_fc1 = (const float*)d_in[13];
  const float* W_fc2 = (const float*)d_in[14];
  const float* b_fc2 = (const float*)d_in[15];
  const float* lnf_g = (const float*)d_in[16];
  const float* lnf_b = (const float*)d_in[17];

  float* out = (float*)d_out;   // f32 logits + loss

  // ---- scratch in d_out (411.7 MB; everything here is dead before the
  //      logits GEMM overwrites it) ----
  char* ob = (char*)d_out;
  float*           x    = (float*)(ob + 0);                       //  6,291,456
  float*           qkv  = (float*)(ob + (size_t)6291456);         // 18,874,368
  __hip_bfloat16*  y    = (__hip_bfloat16*)(ob + (size_t)25165824);  // 3,145,728
  __hip_bfloat16*  tff  = (__hip_bfloat16*)(ob + (size_t)28311552);  // 12,582,912
  __hip_bfloat16*  WTq  = (__hip_bfloat16*)(ob + (size_t)40894464);  // 21,233,664
  __hip_bfloat16*  WTp  = (__hip_bfloat16*)(ob + (size_t)62128128);  //  7,077,888
  __hip_bfloat16*  WT1  = (__hip_bfloat16*)(ob + (size_t)69206016);  // 28,311,552
  __hip_bfloat16*  WT2  = (__hip_bfloat16*)(ob + (size_t)97517568);  // 28,311,552 -> ends 125,829,120

  // ---- d_ws: only what is live during/after the logits GEMM ----
  char* wb = (char*)d_ws;
  __hip_bfloat16* h  = (__hip_bfloat16*)(wb + 0);                 // 3,145,728
  int*   doc = (int*)  (wb + (size_t)3145728);
  float* rl  = (float*)(wb + (size_t)3153920);

  // ---- weight transpose+cast (once per launch) ----
  dim3 tb(32, 8);
  k_wt<<<dim3(2304/32, 768/32, L_), tb, 0, stream>>>(W_qkv,  WTq,  768, 2304);
  k_wt<<<dim3( 768/32, 768/32, L_), tb, 0, stream>>>(W_proj, WTp,  768,  768);
  k_wt<<<dim3(3072/32, 768/32, L_), tb, 0, stream>>>(W_fc1,  WT1,  768, 3072);
  k_wt<<<dim3( 768/32,3072/32, L_), tb, 0, stream>>>(W_fc2,  WT2, 3072,  768);

  k_embed<<<(NTOK*D_ + 255)/256, 256, 0, stream>>>(idx, tok, pos, x);
  k_docid<<<1, 64, 0, stream>>>(idx, doc);

  for (int l = 0; l < L_; ++l) {
    k_ln<<<NTOK, 64, 0, stream>>>(x, ln1_g + l*D_, ln1_b + l*D_, h);
    k_mfma_nt<<<dim3(2304/128, NTOK/128), 256, 0, stream>>>(
        h, WTq + (size_t)l*2304*768, nullptr, b_qkv + (size_t)l*2304, nullptr,
        qkv, nullptr, NTOK, 2304, 768, 0);
    k_attn<<<dim3(T_, H_, B_), 64, 0, stream>>>(qkv, doc, y);
    k_mfma_nt<<<dim3(768/128, NTOK/128), 256, 0, stream>>>(
        y, WTp + (size_t)l*768*768, nullptr, b_proj + (size_t)l*768, x,
        x, nullptr, NTOK, 768, 768, 0);
    k_ln<<<NTOK, 64, 0, stream>>>(x, ln2_g + l*D_, ln2_b + l*D_, h);
    k_mfma_nt<<<dim3(3072/128, NTOK/128), 256, 0, stream>>>(
        h, WT1 + (size_t)l*3072*768, nullptr, b_fc1 + (size_t)l*3072, nullptr,
        nullptr, tff, NTOK, 3072, 768, 1);
    k_mfma_nt<<<dim3(768/128, NTOK/128), 256, 0, stream>>>(
        tff, WT2 + (size_t)l*768*3072, nullptr, b_fc2 + (size_t)l*768, x,
        x, nullptr, NTOK, 768, 3072, 0);
  }
  k_ln<<<NTOK, 64, 0, stream>>>(x, lnf_g, lnf_b, h);
  // logits: A=h bf16 (ws), B=tok f32 (input, [V,768] k-major, cvt in staging)
  k_mfma_nt<<<dim3((V_ + 127)/128, NTOK/128), 256, 0, stream>>>(
      h, nullptr, tok, nullptr, nullptr, out, nullptr, NTOK, V_, 768, 0);
  k_rowloss<<<NTOK, 256, 0, stream>>>(out, tgt, rl);
  k_loss<<<1, 256, 0, stream>>>(rl, out + (size_t)NTOK*V_);
}

// Round 6
// 2848.842 us; speedup vs baseline: 5.2406x; 2.0707x over previous
//
#include <hip/hip_runtime.h>
#include <hip/hip_bf16.h>
#include <math.h>

#define V_ 50257
#define L_ 6
#define H_ 12
#define D_ 768
#define HD_ 64
#define FF_ 3072
#define B_ 2
#define T_ 1024
#define NTOK (B_*T_)
#define EOS_ 50256
#define QBLK 64
#define KVB 64

typedef __attribute__((ext_vector_type(8))) short s16x8;
typedef __attribute__((ext_vector_type(4))) float f32x4;

__device__ __forceinline__ short f2bf(float f) {
  __hip_bfloat16 h = __float2bfloat16(f);
  return *reinterpret_cast<short*>(&h);
}

// ---------------- embedding: x = token_emb[idx] + pos_emb ----------------
__global__ void k_embed(const int* __restrict__ idx, const float* __restrict__ tok,
                        const float* __restrict__ pos, float* __restrict__ x) {
  int gid = blockIdx.x * blockDim.x + threadIdx.x;
  const int total = NTOK * D_;
  if (gid >= total) return;
  int row = gid / D_;
  int d = gid - row * D_;
  int t = row & (T_ - 1);
  x[gid] = tok[(size_t)idx[row] * D_ + d] + pos[t * D_ + d];
}

// ---------------- doc ids: exclusive prefix count of EOS ----------------
__global__ void k_docid(const int* __restrict__ idx, int* __restrict__ doc) {
  int b = threadIdx.x;
  if (b >= B_) return;
  int c = 0;
  for (int t = 0; t < T_; ++t) {
    int e = (idx[b*T_ + t] == EOS_) ? 1 : 0;
    doc[b*T_ + t] = c;
    c += e;
  }
}

// ---------------- layernorm: one wave per row, bf16 out ----------------
__global__ void k_ln(const float* __restrict__ x, const float* __restrict__ g,
                     const float* __restrict__ b, __hip_bfloat16* __restrict__ out) {
  int row = blockIdx.x;
  const float* xr = x + (size_t)row * D_;
  int lane = threadIdx.x;
  float vals[D_/64];
  float s = 0.f;
  #pragma unroll
  for (int i = 0; i < D_/64; ++i) { vals[i] = xr[lane + i*64]; s += vals[i]; }
  #pragma unroll
  for (int o = 1; o < 64; o <<= 1) s += __shfl_xor(s, o);
  float mu = s * (1.f/D_);
  float v = 0.f;
  #pragma unroll
  for (int i = 0; i < D_/64; ++i) { float d0 = vals[i]-mu; v += d0*d0; }
  #pragma unroll
  for (int o = 1; o < 64; o <<= 1) v += __shfl_xor(v, o);
  float inv = rsqrtf(v * (1.f/D_) + 1e-5f);
  #pragma unroll
  for (int i = 0; i < D_/64; ++i) {
    int d = lane + i*64;
    out[(size_t)row*D_ + d] = __float2bfloat16((vals[i]-mu)*inv*g[d] + b[d]);
  }
}

// ------- weight transpose+cast: in f32 [K,N] (per layer) -> out bf16 [N,K] -------
__global__ void k_wt(const float* __restrict__ in, __hip_bfloat16* __restrict__ out,
                     int K, int N) {
  __shared__ float tile[32][33];
  int l = blockIdx.z;
  const float* src = in + (size_t)l*K*N;
  __hip_bfloat16* dst = out + (size_t)l*N*K;
  int n0 = blockIdx.x*32, k0 = blockIdx.y*32;
  int tx = threadIdx.x, ty = threadIdx.y;
  #pragma unroll
  for (int i = 0; i < 4; ++i)
    tile[ty + i*8][tx] = src[(size_t)(k0 + ty + i*8)*N + n0 + tx];
  __syncthreads();
  #pragma unroll
  for (int i = 0; i < 4; ++i)
    dst[(size_t)(n0 + ty + i*8)*K + k0 + tx] = __float2bfloat16(tile[tx][ty + i*8]);
}

// ------- MFMA NT GEMM: C[M,N] = A[M,K]bf16 @ Bt[N,K]^T (+bias)(+gelu)(+resid) -------
__global__ __launch_bounds__(256) void k_mfma_nt(
    const __hip_bfloat16* __restrict__ A,
    const __hip_bfloat16* __restrict__ Bh,
    const float* __restrict__ Bf,
    const float* __restrict__ bias,
    const float* resid,
    float* outf, __hip_bfloat16* outh,
    int M, int N, int K, int gelu)
{
  __shared__ __align__(16) short lds_a[128*64];
  __shared__ __align__(16) short lds_b[128*64];
  const int t = threadIdx.x;
  const int m0 = blockIdx.y * 128;
  const int n0 = blockIdx.x * 128;
  const int lane = t & 63;
  const int wid = t >> 6;
  const int wm = (wid >> 1) * 64;
  const int wn = (wid & 1) * 64;
  const int lrow = lane & 15;
  const int lkb = (lane >> 4) * 16;

  f32x4 acc[4][4];
  #pragma unroll
  for (int i = 0; i < 4; ++i)
    #pragma unroll
    for (int j = 0; j < 4; ++j)
      acc[i][j] = (f32x4){0.f, 0.f, 0.f, 0.f};

  for (int k0 = 0; k0 < K; k0 += 64) {
    #pragma unroll
    for (int p = 0; p < 4; ++p) {
      int c = p*256 + t;
      int row = c >> 3;
      int colb = (c & 7) << 4;
      uint4 v = *(const uint4*)((const char*)A + ((size_t)(m0+row)*K + k0)*2 + colb);
      int dst = (row*128 + colb) ^ ((row & 7) << 4);
      *(uint4*)((char*)lds_a + dst) = v;
    }
    if (Bh) {
      #pragma unroll
      for (int p = 0; p < 4; ++p) {
        int c = p*256 + t;
        int row = c >> 3;
        int colb = (c & 7) << 4;
        int gn = n0 + row;
        uint4 v = {0u,0u,0u,0u};
        if (gn < N) v = *(const uint4*)((const char*)Bh + ((size_t)gn*K + k0)*2 + colb);
        int dst = (row*128 + colb) ^ ((row & 7) << 4);
        *(uint4*)((char*)lds_b + dst) = v;
      }
    } else {
      #pragma unroll
      for (int p = 0; p < 4; ++p) {
        int c = p*256 + t;
        int row = c >> 3;
        int colb = (c & 7) << 4;
        int gn = n0 + row;
        s16x8 s = {0,0,0,0,0,0,0,0};
        if (gn < N) {
          const char* src = (const char*)Bf + ((size_t)gn*K + k0)*4 + colb*2;
          float4 v0 = *(const float4*)src;
          float4 v1 = *(const float4*)(src + 16);
          s[0]=f2bf(v0.x); s[1]=f2bf(v0.y); s[2]=f2bf(v0.z); s[3]=f2bf(v0.w);
          s[4]=f2bf(v1.x); s[5]=f2bf(v1.y); s[6]=f2bf(v1.z); s[7]=f2bf(v1.w);
        }
        int dst = (row*128 + colb) ^ ((row & 7) << 4);
        *(s16x8*)((char*)lds_b + dst) = s;
      }
    }
    __syncthreads();
    #pragma unroll
    for (int ks = 0; ks < 2; ++ks) {
      s16x8 af[4], bfr[4];
      #pragma unroll
      for (int f = 0; f < 4; ++f) {
        int row = wm + f*16 + lrow;
        int off = (row*128 + ks*64 + lkb) ^ ((row & 7) << 4);
        af[f] = *(const s16x8*)((const char*)lds_a + off);
      }
      #pragma unroll
      for (int f = 0; f < 4; ++f) {
        int row = wn + f*16 + lrow;
        int off = (row*128 + ks*64 + lkb) ^ ((row & 7) << 4);
        bfr[f] = *(const s16x8*)((const char*)lds_b + off);
      }
      #pragma unroll
      for (int fm = 0; fm < 4; ++fm)
        #pragma unroll
        for (int fn = 0; fn < 4; ++fn)
          acc[fm][fn] = __builtin_amdgcn_mfma_f32_16x16x32_bf16(
              af[fm], bfr[fn], acc[fm][fn], 0, 0, 0);
    }
    __syncthreads();
  }
  const int crow = (lane >> 4) * 4;
  #pragma unroll
  for (int fm = 0; fm < 4; ++fm) {
    #pragma unroll
    for (int fn = 0; fn < 4; ++fn) {
      int col = n0 + wn + fn*16 + lrow;
      if (col >= N) continue;
      #pragma unroll
      for (int r = 0; r < 4; ++r) {
        int row = m0 + wm + fm*16 + crow + r;
        float v = acc[fm][fn][r];
        if (bias) v += bias[col];
        if (gelu) v = 0.5f * v * (1.f + erff(v * 0.70710678118654752f));
        if (resid) v += resid[(size_t)row*N + col];
        if (outf) outf[(size_t)row*N + col] = v;
        else      outh[(size_t)row*N + col] = __float2bfloat16(v);
      }
    }
  }
}

// ------- flash attention: block = (64 q-rows, h, b), 4 waves x 16 rows -------
__global__ __launch_bounds__(256) void k_fattn(
    const float* __restrict__ qkv, const int* __restrict__ doc,
    __hip_bfloat16* __restrict__ y)
{
  __shared__ __align__(16) short q_lds[QBLK*64];
  __shared__ __align__(16) short k_lds[KVB*64];
  __shared__ __align__(16) short vt_lds[64*KVB];
  __shared__ __align__(16) short p_lds[4][16*64];
  __shared__ int doc_k[KVB];
  const int t = threadIdx.x;
  const int lane = t & 63;
  const int w = t >> 6;
  const int q0 = blockIdx.x * QBLK;
  const int h = blockIdx.y, b = blockIdx.z;
  const int lrow = lane & 15;
  const int lgrp = lane >> 4;
  const int crow = lgrp * 4;
  const size_t qs = 3*D_;

  // ---- stage Q (64x64, f32->bf16, swizzled) ----
  const float* qbase = qkv + ((size_t)(b*T_ + q0))*qs + h*HD_;
  #pragma unroll
  for (int p = 0; p < 2; ++p) {
    int c = p*256 + t;
    int row = c >> 3, seg = c & 7;
    const float* src = qbase + (size_t)row*qs + seg*8;
    s16x8 s;
    #pragma unroll
    for (int j = 0; j < 8; ++j) s[j] = f2bf(src[j]);
    int dst = (row*128 + seg*16) ^ ((row & 7) << 4);
    *(s16x8*)((char*)q_lds + dst) = s;
  }
  int docq[4];
  #pragma unroll
  for (int r = 0; r < 4; ++r)
    docq[r] = doc[b*T_ + q0 + w*16 + crow + r];
  __syncthreads();

  float m_r[4], l_r[4];
  #pragma unroll
  for (int r = 0; r < 4; ++r) { m_r[r] = -1e30f; l_r[r] = 0.f; }
  f32x4 o[4];
  #pragma unroll
  for (int fd = 0; fd < 4; ++fd) o[fd] = (f32x4){0.f,0.f,0.f,0.f};

  const int ntiles = q0/KVB + 1;
  for (int kt = 0; kt < ntiles; ++kt) {
    const int kv0 = kt * KVB;
    // ---- stage K tile ----
    const float* kbase = qkv + ((size_t)(b*T_ + kv0))*qs + D_ + h*HD_;
    #pragma unroll
    for (int p = 0; p < 2; ++p) {
      int c = p*256 + t;
      int row = c >> 3, seg = c & 7;
      const float* src = kbase + (size_t)row*qs + seg*8;
      s16x8 s;
      #pragma unroll
      for (int j = 0; j < 8; ++j) s[j] = f2bf(src[j]);
      int dst = (row*128 + seg*16) ^ ((row & 7) << 4);
      *(s16x8*)((char*)k_lds + dst) = s;
    }
    // ---- stage V^T tile (scatter: LDS[d][kv] = V[kv][d]) ----
    const float* vbase = qkv + ((size_t)(b*T_ + kv0))*qs + 2*D_ + h*HD_;
    #pragma unroll
    for (int p = 0; p < 2; ++p) {
      int c = p*256 + t;
      int kvr = c >> 3, d0 = (c & 7)*8;
      const float* src = vbase + (size_t)kvr*qs + d0;
      #pragma unroll
      for (int j = 0; j < 8; ++j) {
        int d = d0 + j;
        int off = (d*128 + kvr*2) ^ ((d & 7) << 4);
        *(short*)((char*)vt_lds + off) = f2bf(src[j]);
      }
    }
    if (t < KVB) doc_k[t] = doc[b*T_ + kv0 + t];
    __syncthreads();

    // ---- S = Q K^T (scale later) ----
    f32x4 sfr[4];
    #pragma unroll
    for (int fn = 0; fn < 4; ++fn) sfr[fn] = (f32x4){0.f,0.f,0.f,0.f};
    #pragma unroll
    for (int ks = 0; ks < 2; ++ks) {
      int arow = w*16 + lrow;
      s16x8 af = *(const s16x8*)((const char*)q_lds +
                 ((arow*128 + lgrp*16 + ks*64) ^ ((arow & 7) << 4)));
      #pragma unroll
      for (int fn = 0; fn < 4; ++fn) {
        int brow = fn*16 + lrow;
        s16x8 bf = *(const s16x8*)((const char*)k_lds +
                   ((brow*128 + lgrp*16 + ks*64) ^ ((brow & 7) << 4)));
        sfr[fn] = __builtin_amdgcn_mfma_f32_16x16x32_bf16(af, bf, sfr[fn], 0, 0, 0);
      }
    }
    // ---- mask + scale ----
    int dk[4];
    #pragma unroll
    for (int fn = 0; fn < 4; ++fn) dk[fn] = doc_k[fn*16 + lrow];
    float rowmax[4] = {-1e30f, -1e30f, -1e30f, -1e30f};
    #pragma unroll
    for (int fn = 0; fn < 4; ++fn) {
      int col = kv0 + fn*16 + lrow;
      #pragma unroll
      for (int r = 0; r < 4; ++r) {
        int qrow = q0 + w*16 + crow + r;
        bool ok = (col <= qrow) && (dk[fn] == docq[r]);
        float v = ok ? sfr[fn][r] * 0.125f : -1e30f;
        sfr[fn][r] = v;
        rowmax[r] = fmaxf(rowmax[r], v);
      }
    }
    #pragma unroll
    for (int r = 0; r < 4; ++r) {
      float v = rowmax[r];
      #pragma unroll
      for (int off = 1; off < 16; off <<= 1) v = fmaxf(v, __shfl_xor(v, off));
      rowmax[r] = v;
    }
    // ---- online softmax update ----
    float alpha[4], psum[4];
    #pragma unroll
    for (int r = 0; r < 4; ++r) {
      float mn = fmaxf(m_r[r], rowmax[r]);
      alpha[r] = __expf(m_r[r] - mn);
      m_r[r] = mn;
      psum[r] = 0.f;
    }
    #pragma unroll
    for (int fn = 0; fn < 4; ++fn) {
      #pragma unroll
      for (int r = 0; r < 4; ++r) {
        float sv = sfr[fn][r];
        float p = (sv < -5e29f) ? 0.f : __expf(sv - m_r[r]);
        psum[r] += p;
        int rl_ = crow + r;
        int off = (rl_*128 + (fn*16 + lrow)*2) ^ ((rl_ & 7) << 4);
        *(short*)((char*)p_lds[w] + off) = f2bf(p);
      }
    }
    #pragma unroll
    for (int r = 0; r < 4; ++r) {
      float v = psum[r];
      #pragma unroll
      for (int off = 1; off < 16; off <<= 1) v += __shfl_xor(v, off);
      l_r[r] = l_r[r]*alpha[r] + v;
    }
    #pragma unroll
    for (int fd = 0; fd < 4; ++fd)
      #pragma unroll
      for (int r = 0; r < 4; ++r)
        o[fd][r] *= alpha[r];
    __syncthreads();   // P visible (and all ds_writes drained)
    // ---- PV ----
    #pragma unroll
    for (int ks = 0; ks < 2; ++ks) {
      s16x8 af = *(const s16x8*)((const char*)p_lds[w] +
                 ((lrow*128 + lgrp*16 + ks*64) ^ ((lrow & 7) << 4)));
      #pragma unroll
      for (int fd = 0; fd < 4; ++fd) {
        int brow = fd*16 + lrow;
        s16x8 bf = *(const s16x8*)((const char*)vt_lds +
                   ((brow*128 + lgrp*16 + ks*64) ^ ((brow & 7) << 4)));
        o[fd] = __builtin_amdgcn_mfma_f32_16x16x32_bf16(af, bf, o[fd], 0, 0, 0);
      }
    }
    __syncthreads();   // PV reads done before next staging overwrites
  }
  // ---- write y ----
  #pragma unroll
  for (int r = 0; r < 4; ++r) {
    float inv = 1.f / l_r[r];
    int rowg = b*T_ + q0 + w*16 + crow + r;
    #pragma unroll
    for (int fd = 0; fd < 4; ++fd) {
      int col = h*HD_ + fd*16 + lrow;
      y[(size_t)rowg*D_ + col] = __float2bfloat16(o[fd][r] * inv);
    }
  }
}

// ---------------- per-row log-softmax loss terms ----------------
__global__ void k_rowloss(const float* __restrict__ logits,
                          const int* __restrict__ tgt, float* __restrict__ rl) {
  __shared__ float red[4];
  int row = blockIdx.x;
  const float* lr = logits + (size_t)row * V_;
  int tid = threadIdx.x;
  float m = -1e30f;
  for (int v = tid; v < V_; v += 256) m = fmaxf(m, lr[v]);
  #pragma unroll
  for (int o = 1; o < 64; o <<= 1) m = fmaxf(m, __shfl_xor(m, o));
  if ((tid & 63) == 0) red[tid >> 6] = m;
  __syncthreads();
  m = fmaxf(fmaxf(red[0], red[1]), fmaxf(red[2], red[3]));
  __syncthreads();
  float s = 0.f;
  for (int v = tid; v < V_; v += 256) s += __expf(lr[v] - m);
  #pragma unroll
  for (int o = 1; o < 64; o <<= 1) s += __shfl_xor(s, o);
  if ((tid & 63) == 0) red[tid >> 6] = s;
  __syncthreads();
  if (tid == 0) {
    s = red[0]+red[1]+red[2]+red[3];
    rl[row] = (logf(s) + m) - lr[tgt[row]];
  }
}

// ---------------- final loss = mean(rl) ----------------
__global__ void k_loss(const float* __restrict__ rl, float* __restrict__ out) {
  __shared__ float red[4];
  int tid = threadIdx.x;
  float s = 0.f;
  for (int i = tid; i < NTOK; i += 256) s += rl[i];
  #pragma unroll
  for (int o = 1; o < 64; o <<= 1) s += __shfl_xor(s, o);
  if ((tid & 63) == 0) red[tid >> 6] = s;
  __syncthreads();
  if (tid == 0) {
    s = red[0]+red[1]+red[2]+red[3];
    out[0] = s / (float)NTOK;
  }
}

extern "C" void kernel_launch(void* const* d_in, const int* in_sizes, int n_in,
                              void* d_out, int out_size, void* d_ws, size_t ws_size,
                              hipStream_t stream) {
  const int*   idx   = (const int*)d_in[0];
  const int*   tgt   = (const int*)d_in[1];
  const float* tok   = (const float*)d_in[2];
  const float* pos   = (const float*)d_in[3];
  const float* ln1_g = (const float*)d_in[4];
  const float* ln1_b = (const float*)d_in[5];
  const float* ln2_g = (const float*)d_in[6];
  const float* ln2_b = (const float*)d_in[7];
  const float* W_qkv = (const float*)d_in[8];
  const float* b_qkv = (const float*)d_in[9];
  const float* W_proj= (const float*)d_in[10];
  const float* b_proj= (const float*)d_in[11];
  const float* W_fc1 = (const float*)d_in[12];
  const float* b_fc1 = (const float*)d_in[13];
  const float* W_fc2 = (const float*)d_in[14];
  const float* b_fc2 = (const float*)d_in[15];
  const float* lnf_g = (const float*)d_in[16];
  const float* lnf_b = (const float*)d_in[17];

  float* out = (float*)d_out;

  char* ob = (char*)d_out;
  float*           x    = (float*)(ob + 0);
  float*           qkv  = (float*)(ob + (size_t)6291456);
  __hip_bfloat16*  y    = (__hip_bfloat16*)(ob + (size_t)25165824);
  __hip_bfloat16*  tff  = (__hip_bfloat16*)(ob + (size_t)28311552);
  __hip_bfloat16*  WTq  = (__hip_bfloat16*)(ob + (size_t)40894464);
  __hip_bfloat16*  WTp  = (__hip_bfloat16*)(ob + (size_t)62128128);
  __hip_bfloat16*  WT1  = (__hip_bfloat16*)(ob + (size_t)69206016);
  __hip_bfloat16*  WT2  = (__hip_bfloat16*)(ob + (size_t)97517568);  // ends 125,829,120

  char* wb = (char*)d_ws;
  __hip_bfloat16* h  = (__hip_bfloat16*)(wb + 0);
  int*   doc = (int*)  (wb + (size_t)3145728);
  float* rl  = (float*)(wb + (size_t)3153920);

  dim3 tb(32, 8);
  k_wt<<<dim3(2304/32, 768/32, L_), tb, 0, stream>>>(W_qkv,  WTq,  768, 2304);
  k_wt<<<dim3( 768/32, 768/32, L_), tb, 0, stream>>>(W_proj, WTp,  768,  768);
  k_wt<<<dim3(3072/32, 768/32, L_), tb, 0, stream>>>(W_fc1,  WT1,  768, 3072);
  k_wt<<<dim3( 768/32,3072/32, L_), tb, 0, stream>>>(W_fc2,  WT2, 3072,  768);

  k_embed<<<(NTOK*D_ + 255)/256, 256, 0, stream>>>(idx, tok, pos, x);
  k_docid<<<1, 64, 0, stream>>>(idx, doc);

  for (int l = 0; l < L_; ++l) {
    k_ln<<<NTOK, 64, 0, stream>>>(x, ln1_g + l*D_, ln1_b + l*D_, h);
    k_mfma_nt<<<dim3(2304/128, NTOK/128), 256, 0, stream>>>(
        h, WTq + (size_t)l*2304*768, nullptr, b_qkv + (size_t)l*2304, nullptr,
        qkv, nullptr, NTOK, 2304, 768, 0);
    k_fattn<<<dim3(T_/QBLK, H_, B_), 256, 0, stream>>>(qkv, doc, y);
    k_mfma_nt<<<dim3(768/128, NTOK/128), 256, 0, stream>>>(
        y, WTp + (size_t)l*768*768, nullptr, b_proj + (size_t)l*768, x,
        x, nullptr, NTOK, 768, 768, 0);
    k_ln<<<NTOK, 64, 0, stream>>>(x, ln2_g + l*D_, ln2_b + l*D_, h);
    k_mfma_nt<<<dim3(3072/128, NTOK/128), 256, 0, stream>>>(
        h, WT1 + (size_t)l*3072*768, nullptr, b_fc1 + (size_t)l*3072, nullptr,
        nullptr, tff, NTOK, 3072, 768, 1);
    k_mfma_nt<<<dim3(768/128, NTOK/128), 256, 0, stream>>>(
        tff, WT2 + (size_t)l*768*3072, nullptr, b_fc2 + (size_t)l*768, x,
        x, nullptr, NTOK, 768, 3072, 0);
  }
  k_ln<<<NTOK, 64, 0, stream>>>(x, lnf_g, lnf_b, h);
  k_mfma_nt<<<dim3((V_ + 127)/128, NTOK/128), 256, 0, stream>>>(
      h, nullptr, tok, nullptr, nullptr, out, nullptr, NTOK, V_, 768, 0);
  k_rowloss<<<NTOK, 256, 0, stream>>>(out, tgt, rl);
  k_loss<<<1, 256, 0, stream>>>(rl, out + (size_t)NTOK*V_);
}

// Round 7
// 2578.260 us; speedup vs baseline: 5.7906x; 1.1049x over previous
//
#include <hip/hip_runtime.h>
#include <hip/hip_bf16.h>
#include <math.h>

#define V_ 50257
#define L_ 6
#define H_ 12
#define D_ 768
#define HD_ 64
#define FF_ 3072
#define B_ 2
#define T_ 1024
#define NTOK (B_*T_)
#define EOS_ 50256
#define QBLK 64
#define KVB 64
#define LBN 64
#define NSTRIP ((V_ + LBN - 1)/LBN)   // 786

typedef __attribute__((ext_vector_type(8))) short s16x8;
typedef __attribute__((ext_vector_type(4))) float f32x4;

__device__ __forceinline__ short f2bf(float f) {
  __hip_bfloat16 h = __float2bfloat16(f);
  return *reinterpret_cast<short*>(&h);
}

// async global->LDS, 16B per lane; l must be the WAVE-uniform base (HW adds lane*16)
__device__ __forceinline__ void gl_lds16(const void* g, void* l) {
  __builtin_amdgcn_global_load_lds(
      (const __attribute__((address_space(1))) unsigned int*)g,
      (__attribute__((address_space(3))) unsigned int*)l, 16, 0, 0);
}

// ---------------- embedding ----------------
__global__ void k_embed(const int* __restrict__ idx, const float* __restrict__ tok,
                        const float* __restrict__ pos, float* __restrict__ x) {
  int gid = blockIdx.x * blockDim.x + threadIdx.x;
  const int total = NTOK * D_;
  if (gid >= total) return;
  int row = gid / D_;
  int d = gid - row * D_;
  int t = row & (T_ - 1);
  x[gid] = tok[(size_t)idx[row] * D_ + d] + pos[t * D_ + d];
}

// ---------------- doc ids ----------------
__global__ void k_docid(const int* __restrict__ idx, int* __restrict__ doc) {
  int b = threadIdx.x;
  if (b >= B_) return;
  int c = 0;
  for (int t = 0; t < T_; ++t) {
    int e = (idx[b*T_ + t] == EOS_) ? 1 : 0;
    doc[b*T_ + t] = c;
    c += e;
  }
}

// ---------------- layernorm ----------------
__global__ void k_ln(const float* __restrict__ x, const float* __restrict__ g,
                     const float* __restrict__ b, __hip_bfloat16* __restrict__ out) {
  int row = blockIdx.x;
  const float* xr = x + (size_t)row * D_;
  int lane = threadIdx.x;
  float vals[D_/64];
  float s = 0.f;
  #pragma unroll
  for (int i = 0; i < D_/64; ++i) { vals[i] = xr[lane + i*64]; s += vals[i]; }
  #pragma unroll
  for (int o = 1; o < 64; o <<= 1) s += __shfl_xor(s, o);
  float mu = s * (1.f/D_);
  float v = 0.f;
  #pragma unroll
  for (int i = 0; i < D_/64; ++i) { float d0 = vals[i]-mu; v += d0*d0; }
  #pragma unroll
  for (int o = 1; o < 64; o <<= 1) v += __shfl_xor(v, o);
  float inv = rsqrtf(v * (1.f/D_) + 1e-5f);
  #pragma unroll
  for (int i = 0; i < D_/64; ++i) {
    int d = lane + i*64;
    out[(size_t)row*D_ + d] = __float2bfloat16((vals[i]-mu)*inv*g[d] + b[d]);
  }
}

// ------- weight transpose+cast -------
__global__ void k_wt(const float* __restrict__ in, __hip_bfloat16* __restrict__ out,
                     int K, int N) {
  __shared__ float tile[32][33];
  int l = blockIdx.z;
  const float* src = in + (size_t)l*K*N;
  __hip_bfloat16* dst = out + (size_t)l*N*K;
  int n0 = blockIdx.x*32, k0 = blockIdx.y*32;
  int tx = threadIdx.x, ty = threadIdx.y;
  #pragma unroll
  for (int i = 0; i < 4; ++i)
    tile[ty + i*8][tx] = src[(size_t)(k0 + ty + i*8)*N + n0 + tx];
  __syncthreads();
  #pragma unroll
  for (int i = 0; i < 4; ++i)
    dst[(size_t)(n0 + ty + i*8)*K + k0 + tx] = __float2bfloat16(tile[tx][ty + i*8]);
}

// ------- MFMA NT GEMM (128x128x64), gload_lds staging -------
__global__ __launch_bounds__(256) void k_mfma_nt(
    const __hip_bfloat16* __restrict__ A,
    const __hip_bfloat16* __restrict__ Bh,
    const float* __restrict__ Bf,
    const float* __restrict__ bias,
    const float* resid,
    float* outf, __hip_bfloat16* outh,
    int M, int N, int K, int gelu)
{
  __shared__ __align__(16) short lds_a[128*64];
  __shared__ __align__(16) short lds_b[128*64];
  const int t = threadIdx.x;
  const int m0 = blockIdx.y * 128;
  const int n0 = blockIdx.x * 128;
  const int lane = t & 63;
  const int wid = t >> 6;
  const int wm = (wid >> 1) * 64;
  const int wn = (wid & 1) * 64;
  const int lrow = lane & 15;
  const int lkb = (lane >> 4) * 16;
  const int wbase = (t & 192) * 16;    // wave-uniform chunk base (bytes)

  f32x4 acc[4][4];
  #pragma unroll
  for (int i = 0; i < 4; ++i)
    #pragma unroll
    for (int j = 0; j < 4; ++j)
      acc[i][j] = (f32x4){0.f, 0.f, 0.f, 0.f};

  for (int k0 = 0; k0 < K; k0 += 64) {
    // A: linear LDS dest + inverse-swizzled per-lane source
    #pragma unroll
    for (int p = 0; p < 4; ++p) {
      int c = p*256 + t;
      int row = c >> 3;
      int colb = (c & 7) << 4;
      const char* src = (const char*)A + ((size_t)(m0+row)*K + k0)*2 + (colb ^ ((row & 7) << 4));
      gl_lds16(src, (char*)lds_a + p*4096 + wbase);
    }
    if (Bh) {
      #pragma unroll
      for (int p = 0; p < 4; ++p) {
        int c = p*256 + t;
        int row = c >> 3;
        int colb = (c & 7) << 4;
        const char* src = (const char*)Bh + ((size_t)(n0+row)*K + k0)*2 + (colb ^ ((row & 7) << 4));
        gl_lds16(src, (char*)lds_b + p*4096 + wbase);
      }
    } else {
      #pragma unroll
      for (int p = 0; p < 4; ++p) {
        int c = p*256 + t;
        int row = c >> 3;
        int colb = (c & 7) << 4;
        int gn = n0 + row;
        s16x8 s = {0,0,0,0,0,0,0,0};
        if (gn < N) {
          const char* src = (const char*)Bf + ((size_t)gn*K + k0)*4 + colb*2;
          float4 v0 = *(const float4*)src;
          float4 v1 = *(const float4*)(src + 16);
          s[0]=f2bf(v0.x); s[1]=f2bf(v0.y); s[2]=f2bf(v0.z); s[3]=f2bf(v0.w);
          s[4]=f2bf(v1.x); s[5]=f2bf(v1.y); s[6]=f2bf(v1.z); s[7]=f2bf(v1.w);
        }
        int dst = (row*128 + colb) ^ ((row & 7) << 4);
        *(s16x8*)((char*)lds_b + dst) = s;
      }
    }
    __syncthreads();
    #pragma unroll
    for (int ks = 0; ks < 2; ++ks) {
      s16x8 af[4], bfr[4];
      #pragma unroll
      for (int f = 0; f < 4; ++f) {
        int row = wm + f*16 + lrow;
        int off = (row*128 + ks*64 + lkb) ^ ((row & 7) << 4);
        af[f] = *(const s16x8*)((const char*)lds_a + off);
      }
      #pragma unroll
      for (int f = 0; f < 4; ++f) {
        int row = wn + f*16 + lrow;
        int off = (row*128 + ks*64 + lkb) ^ ((row & 7) << 4);
        bfr[f] = *(const s16x8*)((const char*)lds_b + off);
      }
      #pragma unroll
      for (int fm = 0; fm < 4; ++fm)
        #pragma unroll
        for (int fn = 0; fn < 4; ++fn)
          acc[fm][fn] = __builtin_amdgcn_mfma_f32_16x16x32_bf16(
              af[fm], bfr[fn], acc[fm][fn], 0, 0, 0);
    }
    __syncthreads();
  }
  const int crow = (lane >> 4) * 4;
  #pragma unroll
  for (int fm = 0; fm < 4; ++fm) {
    #pragma unroll
    for (int fn = 0; fn < 4; ++fn) {
      int col = n0 + wn + fn*16 + lrow;
      if (col >= N) continue;
      #pragma unroll
      for (int r = 0; r < 4; ++r) {
        int row = m0 + wm + fm*16 + crow + r;
        float v = acc[fm][fn][r];
        if (bias) v += bias[col];
        if (gelu) v = 0.5f * v * (1.f + erff(v * 0.70710678118654752f));
        if (resid) v += resid[(size_t)row*N + col];
        if (outf) outf[(size_t)row*N + col] = v;
        else      outh[(size_t)row*N + col] = __float2bfloat16(v);
      }
    }
  }
}

// ------- logits: one block per 64-col strip of V, persistent B in LDS,
//         loops all 16 M-tiles, emits per-row (max,sumexp) partials -------
__global__ __launch_bounds__(256) void k_logits(
    const __hip_bfloat16* __restrict__ A,   // h [2048][768] bf16
    const float* __restrict__ Bt,           // tok [V][768] f32
    float* __restrict__ C,                  // logits [2048][V] f32
    float2* __restrict__ part)              // [2048][NSTRIP]
{
  __shared__ __align__(16) short b_lds[LBN*768];   // 96 KB
  __shared__ __align__(16) short a_lds[128*64];    // 16 KB
  const int t = threadIdx.x;
  const int lane = t & 63;
  const int wid = t >> 6;
  const int strip = blockIdx.x;
  const int n0 = strip * LBN;
  const int wm = (wid >> 1) * 64;
  const int wn = (wid & 1) * 32;
  const int lrow = lane & 15;
  const int lgrp = lane >> 4;
  const int crow = lgrp * 4;

  // ---- stage B strip once: [64 rows][768 k] bf16, XOR-swizzled ----
  for (int c = t; c < LBN*96; c += 256) {
    int row = c / 96;
    int seg = c - row*96;
    int gn = n0 + row;
    s16x8 s = {0,0,0,0,0,0,0,0};
    if (gn < V_) {
      const float* src = Bt + (size_t)gn*768 + seg*8;
      float4 v0 = *(const float4*)src;
      float4 v1 = *(const float4*)(src + 4);
      s[0]=f2bf(v0.x); s[1]=f2bf(v0.y); s[2]=f2bf(v0.z); s[3]=f2bf(v0.w);
      s[4]=f2bf(v1.x); s[5]=f2bf(v1.y); s[6]=f2bf(v1.z); s[7]=f2bf(v1.w);
    }
    int bo = (seg*16) ^ ((row & 7) << 4);
    *(s16x8*)((char*)b_lds + row*1536 + bo) = s;
  }

  for (int mt = 0; mt < 16; ++mt) {
    const int m0 = mt * 128;
    f32x4 acc[4][2];
    #pragma unroll
    for (int i = 0; i < 4; ++i) { acc[i][0] = (f32x4){0,0,0,0}; acc[i][1] = (f32x4){0,0,0,0}; }

    for (int k0 = 0; k0 < 768; k0 += 64) {
      #pragma unroll
      for (int p = 0; p < 4; ++p) {
        int c = p*256 + t;
        int row = c >> 3;
        int colb = (c & 7) << 4;
        uint4 v = *(const uint4*)((const char*)A + ((size_t)(m0+row)*768 + k0)*2 + colb);
        int dst = (row*128 + colb) ^ ((row & 7) << 4);
        *(uint4*)((char*)a_lds + dst) = v;
      }
      __syncthreads();
      #pragma unroll
      for (int ks = 0; ks < 2; ++ks) {
        s16x8 af[4], bf2[2];
        #pragma unroll
        for (int f = 0; f < 4; ++f) {
          int row = wm + f*16 + lrow;
          int off = (row*128 + ks*64 + lgrp*16) ^ ((row & 7) << 4);
          af[f] = *(const s16x8*)((const char*)a_lds + off);
        }
        #pragma unroll
        for (int f = 0; f < 2; ++f) {
          int brow = wn + f*16 + lrow;
          int bo = (k0 + ks*32)*2 + lgrp*16;
          int off = brow*1536 + (bo ^ ((brow & 7) << 4));
          bf2[f] = *(const s16x8*)((const char*)b_lds + off);
        }
        #pragma unroll
        for (int fm = 0; fm < 4; ++fm)
          #pragma unroll
          for (int fn = 0; fn < 2; ++fn)
            acc[fm][fn] = __builtin_amdgcn_mfma_f32_16x16x32_bf16(
                af[fm], bf2[fn], acc[fm][fn], 0, 0, 0);
      }
      __syncthreads();
    }

    // ---- epilogue: write C + per-row partials over this strip ----
    bool val0 = (n0 + wn + lrow) < V_;
    bool val1 = (n0 + wn + 16 + lrow) < V_;
    float* red = (float*)a_lds;   // reuse (post-barrier): [128 rows][4]
    #pragma unroll
    for (int fm = 0; fm < 4; ++fm) {
      #pragma unroll
      for (int r = 0; r < 4; ++r) {
        int rit = wm + fm*16 + crow + r;
        int row = m0 + rit;
        float v0 = acc[fm][0][r], v1 = acc[fm][1][r];
        if (val0) C[(size_t)row*V_ + n0 + wn + lrow] = v0;
        if (val1) C[(size_t)row*V_ + n0 + wn + 16 + lrow] = v1;
        float m = fmaxf(val0 ? v0 : -1e30f, val1 ? v1 : -1e30f);
        #pragma unroll
        for (int o = 1; o < 16; o <<= 1) m = fmaxf(m, __shfl_xor(m, o));
        float s = (val0 ? __expf(v0 - m) : 0.f) + (val1 ? __expf(v1 - m) : 0.f);
        #pragma unroll
        for (int o = 1; o < 16; o <<= 1) s += __shfl_xor(s, o);
        if (lrow == 0) { red[rit*4 + (wid&1)*2] = m; red[rit*4 + (wid&1)*2 + 1] = s; }
      }
    }
    __syncthreads();
    if (t < 128) {
      float ma = red[t*4], sa = red[t*4+1], mb = red[t*4+2], sb = red[t*4+3];
      float mn = fmaxf(ma, mb);
      float S = sa*__expf(ma - mn) + sb*__expf(mb - mn);
      part[(size_t)(m0 + t)*NSTRIP + strip] = make_float2(mn, S);
    }
    __syncthreads();
  }
}

// ------- combine per-strip partials -> per-row loss -------
__global__ void k_rowloss2(const float2* __restrict__ part,
                           const float* __restrict__ logits,
                           const int* __restrict__ tgt, float* __restrict__ rl) {
  int row = blockIdx.x;
  int lane = threadIdx.x;
  float M = -1e30f, S = 0.f;
  for (int i = lane; i < NSTRIP; i += 64) {
    float2 p = part[(size_t)row*NSTRIP + i];
    float mn = fmaxf(M, p.x);
    S = S*__expf(M - mn) + p.y*__expf(p.x - mn);
    M = mn;
  }
  #pragma unroll
  for (int o = 1; o < 64; o <<= 1) {
    float Mo = __shfl_xor(M, o);
    float So = __shfl_xor(S, o);
    float mn = fmaxf(M, Mo);
    S = S*__expf(M - mn) + So*__expf(Mo - mn);
    M = mn;
  }
  if (lane == 0)
    rl[row] = (logf(S) + M) - logits[(size_t)row*V_ + tgt[row]];
}

// ------- flash attention -------
__global__ __launch_bounds__(256) void k_fattn(
    const float* __restrict__ qkv, const int* __restrict__ doc,
    __hip_bfloat16* __restrict__ y)
{
  __shared__ __align__(16) short q_lds[QBLK*64];
  __shared__ __align__(16) short k_lds[KVB*64];
  __shared__ __align__(16) short vt_lds[64*KVB];
  __shared__ __align__(16) short p_lds[4][16*64];
  __shared__ int doc_k[KVB];
  const int t = threadIdx.x;
  const int lane = t & 63;
  const int w = t >> 6;
  const int q0 = blockIdx.x * QBLK;
  const int h = blockIdx.y, b = blockIdx.z;
  const int lrow = lane & 15;
  const int lgrp = lane >> 4;
  const int crow = lgrp * 4;
  const size_t qs = 3*D_;

  const float* qbase = qkv + ((size_t)(b*T_ + q0))*qs + h*HD_;
  #pragma unroll
  for (int p = 0; p < 2; ++p) {
    int c = p*256 + t;
    int row = c >> 3, seg = c & 7;
    const float* src = qbase + (size_t)row*qs + seg*8;
    s16x8 s;
    #pragma unroll
    for (int j = 0; j < 8; ++j) s[j] = f2bf(src[j]);
    int dst = (row*128 + seg*16) ^ ((row & 7) << 4);
    *(s16x8*)((char*)q_lds + dst) = s;
  }
  int docq[4];
  #pragma unroll
  for (int r = 0; r < 4; ++r)
    docq[r] = doc[b*T_ + q0 + w*16 + crow + r];
  __syncthreads();

  float m_r[4], l_r[4];
  #pragma unroll
  for (int r = 0; r < 4; ++r) { m_r[r] = -1e30f; l_r[r] = 0.f; }
  f32x4 o[4];
  #pragma unroll
  for (int fd = 0; fd < 4; ++fd) o[fd] = (f32x4){0.f,0.f,0.f,0.f};

  const int ntiles = q0/KVB + 1;
  for (int kt = 0; kt < ntiles; ++kt) {
    const int kv0 = kt * KVB;
    const float* kbase = qkv + ((size_t)(b*T_ + kv0))*qs + D_ + h*HD_;
    #pragma unroll
    for (int p = 0; p < 2; ++p) {
      int c = p*256 + t;
      int row = c >> 3, seg = c & 7;
      const float* src = kbase + (size_t)row*qs + seg*8;
      s16x8 s;
      #pragma unroll
      for (int j = 0; j < 8; ++j) s[j] = f2bf(src[j]);
      int dst = (row*128 + seg*16) ^ ((row & 7) << 4);
      *(s16x8*)((char*)k_lds + dst) = s;
    }
    const float* vbase = qkv + ((size_t)(b*T_ + kv0))*qs + 2*D_ + h*HD_;
    #pragma unroll
    for (int p = 0; p < 2; ++p) {
      int c = p*256 + t;
      int kvr = c >> 3, d0 = (c & 7)*8;
      const float* src = vbase + (size_t)kvr*qs + d0;
      #pragma unroll
      for (int j = 0; j < 8; ++j) {
        int d = d0 + j;
        int off = (d*128 + kvr*2) ^ ((d & 7) << 4);
        *(short*)((char*)vt_lds + off) = f2bf(src[j]);
      }
    }
    if (t < KVB) doc_k[t] = doc[b*T_ + kv0 + t];
    __syncthreads();

    f32x4 sfr[4];
    #pragma unroll
    for (int fn = 0; fn < 4; ++fn) sfr[fn] = (f32x4){0.f,0.f,0.f,0.f};
    #pragma unroll
    for (int ks = 0; ks < 2; ++ks) {
      int arow = w*16 + lrow;
      s16x8 af = *(const s16x8*)((const char*)q_lds +
                 ((arow*128 + lgrp*16 + ks*64) ^ ((arow & 7) << 4)));
      #pragma unroll
      for (int fn = 0; fn < 4; ++fn) {
        int brow = fn*16 + lrow;
        s16x8 bf = *(const s16x8*)((const char*)k_lds +
                   ((brow*128 + lgrp*16 + ks*64) ^ ((brow & 7) << 4)));
        sfr[fn] = __builtin_amdgcn_mfma_f32_16x16x32_bf16(af, bf, sfr[fn], 0, 0, 0);
      }
    }
    int dk[4];
    #pragma unroll
    for (int fn = 0; fn < 4; ++fn) dk[fn] = doc_k[fn*16 + lrow];
    float rowmax[4] = {-1e30f, -1e30f, -1e30f, -1e30f};
    #pragma unroll
    for (int fn = 0; fn < 4; ++fn) {
      int col = kv0 + fn*16 + lrow;
      #pragma unroll
      for (int r = 0; r < 4; ++r) {
        int qrow = q0 + w*16 + crow + r;
        bool ok = (col <= qrow) && (dk[fn] == docq[r]);
        float v = ok ? sfr[fn][r] * 0.125f : -1e30f;
        sfr[fn][r] = v;
        rowmax[r] = fmaxf(rowmax[r], v);
      }
    }
    #pragma unroll
    for (int r = 0; r < 4; ++r) {
      float v = rowmax[r];
      #pragma unroll
      for (int off = 1; off < 16; off <<= 1) v = fmaxf(v, __shfl_xor(v, off));
      rowmax[r] = v;
    }
    float alpha[4], psum[4];
    #pragma unroll
    for (int r = 0; r < 4; ++r) {
      float mn = fmaxf(m_r[r], rowmax[r]);
      alpha[r] = __expf(m_r[r] - mn);
      m_r[r] = mn;
      psum[r] = 0.f;
    }
    #pragma unroll
    for (int fn = 0; fn < 4; ++fn) {
      #pragma unroll
      for (int r = 0; r < 4; ++r) {
        float sv = sfr[fn][r];
        float p = (sv < -5e29f) ? 0.f : __expf(sv - m_r[r]);
        psum[r] += p;
        int rl_ = crow + r;
        int off = (rl_*128 + (fn*16 + lrow)*2) ^ ((rl_ & 7) << 4);
        *(short*)((char*)p_lds[w] + off) = f2bf(p);
      }
    }
    #pragma unroll
    for (int r = 0; r < 4; ++r) {
      float v = psum[r];
      #pragma unroll
      for (int off = 1; off < 16; off <<= 1) v += __shfl_xor(v, off);
      l_r[r] = l_r[r]*alpha[r] + v;
    }
    #pragma unroll
    for (int fd = 0; fd < 4; ++fd)
      #pragma unroll
      for (int r = 0; r < 4; ++r)
        o[fd][r] *= alpha[r];
    __syncthreads();
    #pragma unroll
    for (int ks = 0; ks < 2; ++ks) {
      s16x8 af = *(const s16x8*)((const char*)p_lds[w] +
                 ((lrow*128 + lgrp*16 + ks*64) ^ ((lrow & 7) << 4)));
      #pragma unroll
      for (int fd = 0; fd < 4; ++fd) {
        int brow = fd*16 + lrow;
        s16x8 bf = *(const s16x8*)((const char*)vt_lds +
                   ((brow*128 + lgrp*16 + ks*64) ^ ((brow & 7) << 4)));
        o[fd] = __builtin_amdgcn_mfma_f32_16x16x32_bf16(af, bf, o[fd], 0, 0, 0);
      }
    }
    __syncthreads();
  }
  #pragma unroll
  for (int r = 0; r < 4; ++r) {
    float inv = 1.f / l_r[r];
    int rowg = b*T_ + q0 + w*16 + crow + r;
    #pragma unroll
    for (int fd = 0; fd < 4; ++fd) {
      int col = h*HD_ + fd*16 + lrow;
      y[(size_t)rowg*D_ + col] = __float2bfloat16(o[fd][r] * inv);
    }
  }
}

// ---------------- fallback per-row log-softmax ----------------
__global__ void k_rowloss(const float* __restrict__ logits,
                          const int* __restrict__ tgt, float* __restrict__ rl) {
  __shared__ float red[4];
  int row = blockIdx.x;
  const float* lr = logits + (size_t)row * V_;
  int tid = threadIdx.x;
  float m = -1e30f;
  for (int v = tid; v < V_; v += 256) m = fmaxf(m, lr[v]);
  #pragma unroll
  for (int o = 1; o < 64; o <<= 1) m = fmaxf(m, __shfl_xor(m, o));
  if ((tid & 63) == 0) red[tid >> 6] = m;
  __syncthreads();
  m = fmaxf(fmaxf(red[0], red[1]), fmaxf(red[2], red[3]));
  __syncthreads();
  float s = 0.f;
  for (int v = tid; v < V_; v += 256) s += __expf(lr[v] - m);
  #pragma unroll
  for (int o = 1; o < 64; o <<= 1) s += __shfl_xor(s, o);
  if ((tid & 63) == 0) red[tid >> 6] = s;
  __syncthreads();
  if (tid == 0) {
    s = red[0]+red[1]+red[2]+red[3];
    rl[row] = (logf(s) + m) - lr[tgt[row]];
  }
}

// ---------------- final loss = mean(rl) ----------------
__global__ void k_loss(const float* __restrict__ rl, float* __restrict__ out) {
  __shared__ float red[4];
  int tid = threadIdx.x;
  float s = 0.f;
  for (int i = tid; i < NTOK; i += 256) s += rl[i];
  #pragma unroll
  for (int o = 1; o < 64; o <<= 1) s += __shfl_xor(s, o);
  if ((tid & 63) == 0) red[tid >> 6] = s;
  __syncthreads();
  if (tid == 0) {
    s = red[0]+red[1]+red[2]+red[3];
    out[0] = s / (float)NTOK;
  }
}

extern "C" void kernel_launch(void* const* d_in, const int* in_sizes, int n_in,
                              void* d_out, int out_size, void* d_ws, size_t ws_size,
                              hipStream_t stream) {
  const int*   idx   = (const int*)d_in[0];
  const int*   tgt   = (const int*)d_in[1];
  const float* tok   = (const float*)d_in[2];
  const float* pos   = (const float*)d_in[3];
  const float* ln1_g = (const float*)d_in[4];
  const float* ln1_b = (const float*)d_in[5];
  const float* ln2_g = (const float*)d_in[6];
  const float* ln2_b = (const float*)d_in[7];
  const float* W_qkv = (const float*)d_in[8];
  const float* b_qkv = (const float*)d_in[9];
  const float* W_proj= (const float*)d_in[10];
  const float* b_proj= (const float*)d_in[11];
  const float* W_fc1 = (const float*)d_in[12];
  const float* b_fc1 = (const float*)d_in[13];
  const float* W_fc2 = (const float*)d_in[14];
  const float* b_fc2 = (const float*)d_in[15];
  const float* lnf_g = (const float*)d_in[16];
  const float* lnf_b = (const float*)d_in[17];

  float* out = (float*)d_out;

  char* ob = (char*)d_out;
  float*           x    = (float*)(ob + 0);
  float*           qkv  = (float*)(ob + (size_t)6291456);
  __hip_bfloat16*  y    = (__hip_bfloat16*)(ob + (size_t)25165824);
  __hip_bfloat16*  tff  = (__hip_bfloat16*)(ob + (size_t)28311552);
  __hip_bfloat16*  WTq  = (__hip_bfloat16*)(ob + (size_t)40894464);
  __hip_bfloat16*  WTp  = (__hip_bfloat16*)(ob + (size_t)62128128);
  __hip_bfloat16*  WT1  = (__hip_bfloat16*)(ob + (size_t)69206016);
  __hip_bfloat16*  WT2  = (__hip_bfloat16*)(ob + (size_t)97517568);  // ends 125,829,120

  char* wb = (char*)d_ws;
  __hip_bfloat16* h  = (__hip_bfloat16*)(wb + 0);                  // 3,145,728
  int*    doc  = (int*)  (wb + (size_t)3145728);                   // 8,192
  float*  rl   = (float*)(wb + (size_t)3153920);                   // 8,192
  float2* part = (float2*)(wb + (size_t)3162112);                  // 12,877,824
  const size_t ws_need = (size_t)3162112 + (size_t)NTOK*NSTRIP*8;  // 16,039,936
  const bool fused_loss = (ws_size >= ws_need);

  dim3 tb(32, 8);
  k_wt<<<dim3(2304/32, 768/32, L_), tb, 0, stream>>>(W_qkv,  WTq,  768, 2304);
  k_wt<<<dim3( 768/32, 768/32, L_), tb, 0, stream>>>(W_proj, WTp,  768,  768);
  k_wt<<<dim3(3072/32, 768/32, L_), tb, 0, stream>>>(W_fc1,  WT1,  768, 3072);
  k_wt<<<dim3( 768/32,3072/32, L_), tb, 0, stream>>>(W_fc2,  WT2, 3072,  768);

  k_embed<<<(NTOK*D_ + 255)/256, 256, 0, stream>>>(idx, tok, pos, x);
  k_docid<<<1, 64, 0, stream>>>(idx, doc);

  for (int l = 0; l < L_; ++l) {
    k_ln<<<NTOK, 64, 0, stream>>>(x, ln1_g + l*D_, ln1_b + l*D_, h);
    k_mfma_nt<<<dim3(2304/128, NTOK/128), 256, 0, stream>>>(
        h, WTq + (size_t)l*2304*768, nullptr, b_qkv + (size_t)l*2304, nullptr,
        qkv, nullptr, NTOK, 2304, 768, 0);
    k_fattn<<<dim3(T_/QBLK, H_, B_), 256, 0, stream>>>(qkv, doc, y);
    k_mfma_nt<<<dim3(768/128, NTOK/128), 256, 0, stream>>>(
        y, WTp + (size_t)l*768*768, nullptr, b_proj + (size_t)l*768, x,
        x, nullptr, NTOK, 768, 768, 0);
    k_ln<<<NTOK, 64, 0, stream>>>(x, ln2_g + l*D_, ln2_b + l*D_, h);
    k_mfma_nt<<<dim3(3072/128, NTOK/128), 256, 0, stream>>>(
        h, WT1 + (size_t)l*3072*768, nullptr, b_fc1 + (size_t)l*3072, nullptr,
        nullptr, tff, NTOK, 3072, 768, 1);
    k_mfma_nt<<<dim3(768/128, NTOK/128), 256, 0, stream>>>(
        tff, WT2 + (size_t)l*768*3072, nullptr, b_fc2 + (size_t)l*768, x,
        x, nullptr, NTOK, 768, 3072, 0);
  }
  k_ln<<<NTOK, 64, 0, stream>>>(x, lnf_g, lnf_b, h);

  if (fused_loss) {
    k_logits<<<NSTRIP, 256, 0, stream>>>(h, tok, out, part);
    k_rowloss2<<<NTOK, 64, 0, stream>>>(part, out, tgt, rl);
  } else {
    k_mfma_nt<<<dim3((V_ + 127)/128, NTOK/128), 256, 0, stream>>>(
        h, nullptr, tok, nullptr, nullptr, out, nullptr, NTOK, V_, 768, 0);
    k_rowloss<<<NTOK, 256, 0, stream>>>(out, tgt, rl);
  }
  k_loss<<<1, 256, 0, stream>>>(rl, out + (size_t)NTOK*V_);
}

// Round 8
// 2194.949 us; speedup vs baseline: 6.8019x; 1.1746x over previous
//
#include <hip/hip_runtime.h>
#include <hip/hip_bf16.h>
#include <math.h>

#define V_ 50257
#define L_ 6
#define H_ 12
#define D_ 768
#define HD_ 64
#define FF_ 3072
#define B_ 2
#define T_ 1024
#define NTOK (B_*T_)
#define EOS_ 50256
#define QBLK 64
#define KVB 64
#define NS2 393            // number of 128-col logit tiles

typedef __attribute__((ext_vector_type(8))) short s16x8;
typedef __attribute__((ext_vector_type(4))) float f32x4;

__device__ __forceinline__ short f2bf(float f) {
  __hip_bfloat16 h = __float2bfloat16(f);
  return *reinterpret_cast<short*>(&h);
}

// async global->LDS, 16B per lane; l must be the WAVE-uniform base (HW adds lane*16)
__device__ __forceinline__ void gl_lds16(const void* g, void* l) {
  __builtin_amdgcn_global_load_lds(
      (const __attribute__((address_space(1))) unsigned int*)g,
      (__attribute__((address_space(3))) unsigned int*)l, 16, 0, 0);
}

// ---------------- embedding ----------------
__global__ void k_embed(const int* __restrict__ idx, const float* __restrict__ tok,
                        const float* __restrict__ pos, float* __restrict__ x) {
  int gid = blockIdx.x * blockDim.x + threadIdx.x;
  const int total = NTOK * D_;
  if (gid >= total) return;
  int row = gid / D_;
  int d = gid - row * D_;
  int t = row & (T_ - 1);
  x[gid] = tok[(size_t)idx[row] * D_ + d] + pos[t * D_ + d];
}

// ---------------- doc ids ----------------
__global__ void k_docid(const int* __restrict__ idx, int* __restrict__ doc) {
  int b = threadIdx.x;
  if (b >= B_) return;
  int c = 0;
  for (int t = 0; t < T_; ++t) {
    int e = (idx[b*T_ + t] == EOS_) ? 1 : 0;
    doc[b*T_ + t] = c;
    c += e;
  }
}

// ---------------- layernorm ----------------
__global__ void k_ln(const float* __restrict__ x, const float* __restrict__ g,
                     const float* __restrict__ b, __hip_bfloat16* __restrict__ out) {
  int row = blockIdx.x;
  const float* xr = x + (size_t)row * D_;
  int lane = threadIdx.x;
  float vals[D_/64];
  float s = 0.f;
  #pragma unroll
  for (int i = 0; i < D_/64; ++i) { vals[i] = xr[lane + i*64]; s += vals[i]; }
  #pragma unroll
  for (int o = 1; o < 64; o <<= 1) s += __shfl_xor(s, o);
  float mu = s * (1.f/D_);
  float v = 0.f;
  #pragma unroll
  for (int i = 0; i < D_/64; ++i) { float d0 = vals[i]-mu; v += d0*d0; }
  #pragma unroll
  for (int o = 1; o < 64; o <<= 1) v += __shfl_xor(v, o);
  float inv = rsqrtf(v * (1.f/D_) + 1e-5f);
  #pragma unroll
  for (int i = 0; i < D_/64; ++i) {
    int d = lane + i*64;
    out[(size_t)row*D_ + d] = __float2bfloat16((vals[i]-mu)*inv*g[d] + b[d]);
  }
}

// ------- weight transpose+cast -------
__global__ void k_wt(const float* __restrict__ in, __hip_bfloat16* __restrict__ out,
                     int K, int N) {
  __shared__ float tile[32][33];
  int l = blockIdx.z;
  const float* src = in + (size_t)l*K*N;
  __hip_bfloat16* dst = out + (size_t)l*N*K;
  int n0 = blockIdx.x*32, k0 = blockIdx.y*32;
  int tx = threadIdx.x, ty = threadIdx.y;
  #pragma unroll
  for (int i = 0; i < 4; ++i)
    tile[ty + i*8][tx] = src[(size_t)(k0 + ty + i*8)*N + n0 + tx];
  __syncthreads();
  #pragma unroll
  for (int i = 0; i < 4; ++i)
    dst[(size_t)(n0 + ty + i*8)*K + k0 + tx] = __float2bfloat16(tile[tx][ty + i*8]);
}

// ------- MFMA NT GEMM (128x128x64), gload_lds staging -------
__global__ __launch_bounds__(256) void k_mfma_nt(
    const __hip_bfloat16* __restrict__ A,
    const __hip_bfloat16* __restrict__ Bh,
    const float* __restrict__ Bf,
    const float* __restrict__ bias,
    const float* resid,
    float* outf, __hip_bfloat16* outh,
    int M, int N, int K, int gelu)
{
  __shared__ __align__(16) short lds_a[128*64];
  __shared__ __align__(16) short lds_b[128*64];
  const int t = threadIdx.x;
  const int m0 = blockIdx.y * 128;
  const int n0 = blockIdx.x * 128;
  const int lane = t & 63;
  const int wid = t >> 6;
  const int wm = (wid >> 1) * 64;
  const int wn = (wid & 1) * 64;
  const int lrow = lane & 15;
  const int lkb = (lane >> 4) * 16;
  const int wbase = (t & 192) * 16;

  f32x4 acc[4][4];
  #pragma unroll
  for (int i = 0; i < 4; ++i)
    #pragma unroll
    for (int j = 0; j < 4; ++j)
      acc[i][j] = (f32x4){0.f, 0.f, 0.f, 0.f};

  for (int k0 = 0; k0 < K; k0 += 64) {
    #pragma unroll
    for (int p = 0; p < 4; ++p) {
      int c = p*256 + t;
      int row = c >> 3;
      int colb = (c & 7) << 4;
      const char* src = (const char*)A + ((size_t)(m0+row)*K + k0)*2 + (colb ^ ((row & 7) << 4));
      gl_lds16(src, (char*)lds_a + p*4096 + wbase);
    }
    if (Bh) {
      #pragma unroll
      for (int p = 0; p < 4; ++p) {
        int c = p*256 + t;
        int row = c >> 3;
        int colb = (c & 7) << 4;
        const char* src = (const char*)Bh + ((size_t)(n0+row)*K + k0)*2 + (colb ^ ((row & 7) << 4));
        gl_lds16(src, (char*)lds_b + p*4096 + wbase);
      }
    } else {
      #pragma unroll
      for (int p = 0; p < 4; ++p) {
        int c = p*256 + t;
        int row = c >> 3;
        int colb = (c & 7) << 4;
        int gn = n0 + row;
        s16x8 s = {0,0,0,0,0,0,0,0};
        if (gn < N) {
          const char* src = (const char*)Bf + ((size_t)gn*K + k0)*4 + colb*2;
          float4 v0 = *(const float4*)src;
          float4 v1 = *(const float4*)(src + 16);
          s[0]=f2bf(v0.x); s[1]=f2bf(v0.y); s[2]=f2bf(v0.z); s[3]=f2bf(v0.w);
          s[4]=f2bf(v1.x); s[5]=f2bf(v1.y); s[6]=f2bf(v1.z); s[7]=f2bf(v1.w);
        }
        int dst = (row*128 + colb) ^ ((row & 7) << 4);
        *(s16x8*)((char*)lds_b + dst) = s;
      }
    }
    __syncthreads();
    #pragma unroll
    for (int ks = 0; ks < 2; ++ks) {
      s16x8 af[4], bfr[4];
      #pragma unroll
      for (int f = 0; f < 4; ++f) {
        int row = wm + f*16 + lrow;
        int off = (row*128 + ks*64 + lkb) ^ ((row & 7) << 4);
        af[f] = *(const s16x8*)((const char*)lds_a + off);
      }
      #pragma unroll
      for (int f = 0; f < 4; ++f) {
        int row = wn + f*16 + lrow;
        int off = (row*128 + ks*64 + lkb) ^ ((row & 7) << 4);
        bfr[f] = *(const s16x8*)((const char*)lds_b + off);
      }
      #pragma unroll
      for (int fm = 0; fm < 4; ++fm)
        #pragma unroll
        for (int fn = 0; fn < 4; ++fn)
          acc[fm][fn] = __builtin_amdgcn_mfma_f32_16x16x32_bf16(
              af[fm], bfr[fn], acc[fm][fn], 0, 0, 0);
    }
    __syncthreads();
  }
  const int crow = (lane >> 4) * 4;
  #pragma unroll
  for (int fm = 0; fm < 4; ++fm) {
    #pragma unroll
    for (int fn = 0; fn < 4; ++fn) {
      int col = n0 + wn + fn*16 + lrow;
      if (col >= N) continue;
      #pragma unroll
      for (int r = 0; r < 4; ++r) {
        int row = m0 + wm + fm*16 + crow + r;
        float v = acc[fm][fn][r];
        if (bias) v += bias[col];
        if (gelu) v = 0.5f * v * (1.f + erff(v * 0.70710678118654752f));
        if (resid) v += resid[(size_t)row*N + col];
        if (outf) outf[(size_t)row*N + col] = v;
        else      outh[(size_t)row*N + col] = __float2bfloat16(v);
      }
    }
  }
}

// ------- logits GEMM + fused per-tile softmax partials -------
// grid (16 m-tiles, 393 n-tiles), x fastest -> 16 blocks sharing a tok panel
// dispatch consecutively (L2/L3 reuse). part[row][nt] = (max, sumexp) of tile.
__global__ __launch_bounds__(256) void k_logits(
    const __hip_bfloat16* __restrict__ A,   // h [2048][768] bf16
    const float* __restrict__ Bf,           // tok [V][768] f32
    float* __restrict__ C,                  // logits [2048][V_] f32
    float2* __restrict__ part)              // [2048][NS2]
{
  __shared__ __align__(16) short lds_a[128*64];
  __shared__ __align__(16) short lds_b[128*64];
  const int t = threadIdx.x;
  const int m0 = blockIdx.x * 128;
  const int nt = blockIdx.y;
  const int n0 = nt * 128;
  const int lane = t & 63;
  const int wid = t >> 6;
  const int wm = (wid >> 1) * 64;
  const int wn = (wid & 1) * 64;
  const int lrow = lane & 15;
  const int lkb = (lane >> 4) * 16;
  const int wbase = (t & 192) * 16;

  f32x4 acc[4][4];
  #pragma unroll
  for (int i = 0; i < 4; ++i)
    #pragma unroll
    for (int j = 0; j < 4; ++j)
      acc[i][j] = (f32x4){0.f, 0.f, 0.f, 0.f};

  for (int k0 = 0; k0 < 768; k0 += 64) {
    #pragma unroll
    for (int p = 0; p < 4; ++p) {
      int c = p*256 + t;
      int row = c >> 3;
      int colb = (c & 7) << 4;
      const char* src = (const char*)A + ((size_t)(m0+row)*768 + k0)*2 + (colb ^ ((row & 7) << 4));
      gl_lds16(src, (char*)lds_a + p*4096 + wbase);
    }
    #pragma unroll
    for (int p = 0; p < 4; ++p) {
      int c = p*256 + t;
      int row = c >> 3;
      int colb = (c & 7) << 4;
      int gn = n0 + row;
      s16x8 s = {0,0,0,0,0,0,0,0};
      if (gn < V_) {
        const char* src = (const char*)Bf + ((size_t)gn*768 + k0)*4 + colb*2;
        float4 v0 = *(const float4*)src;
        float4 v1 = *(const float4*)(src + 16);
        s[0]=f2bf(v0.x); s[1]=f2bf(v0.y); s[2]=f2bf(v0.z); s[3]=f2bf(v0.w);
        s[4]=f2bf(v1.x); s[5]=f2bf(v1.y); s[6]=f2bf(v1.z); s[7]=f2bf(v1.w);
      }
      int dst = (row*128 + colb) ^ ((row & 7) << 4);
      *(s16x8*)((char*)lds_b + dst) = s;
    }
    __syncthreads();
    #pragma unroll
    for (int ks = 0; ks < 2; ++ks) {
      s16x8 af[4], bfr[4];
      #pragma unroll
      for (int f = 0; f < 4; ++f) {
        int row = wm + f*16 + lrow;
        int off = (row*128 + ks*64 + lkb) ^ ((row & 7) << 4);
        af[f] = *(const s16x8*)((const char*)lds_a + off);
      }
      #pragma unroll
      for (int f = 0; f < 4; ++f) {
        int row = wn + f*16 + lrow;
        int off = (row*128 + ks*64 + lkb) ^ ((row & 7) << 4);
        bfr[f] = *(const s16x8*)((const char*)lds_b + off);
      }
      #pragma unroll
      for (int fm = 0; fm < 4; ++fm)
        #pragma unroll
        for (int fn = 0; fn < 4; ++fn)
          acc[fm][fn] = __builtin_amdgcn_mfma_f32_16x16x32_bf16(
              af[fm], bfr[fn], acc[fm][fn], 0, 0, 0);
    }
    __syncthreads();
  }
  // ---- epilogue: write C + per-row (max,sumexp) partials over this 128-tile ----
  const int crow = (lane >> 4) * 4;
  bool valid[4];
  #pragma unroll
  for (int fn = 0; fn < 4; ++fn) valid[fn] = (n0 + wn + fn*16 + lrow) < V_;
  float2* red = (float2*)lds_a;   // [128 rows][2 wave-cols], safe after final barrier
  #pragma unroll
  for (int fm = 0; fm < 4; ++fm) {
    #pragma unroll
    for (int r = 0; r < 4; ++r) {
      int rit = wm + fm*16 + crow + r;
      int row = m0 + rit;
      float m = -1e30f;
      #pragma unroll
      for (int fn = 0; fn < 4; ++fn) {
        if (valid[fn]) {
          float v = acc[fm][fn][r];
          C[(size_t)row*V_ + n0 + wn + fn*16 + lrow] = v;
          m = fmaxf(m, v);
        }
      }
      #pragma unroll
      for (int o = 1; o < 16; o <<= 1) m = fmaxf(m, __shfl_xor(m, o));
      float s = 0.f;
      #pragma unroll
      for (int fn = 0; fn < 4; ++fn)
        if (valid[fn]) s += __expf(acc[fm][fn][r] - m);
      #pragma unroll
      for (int o = 1; o < 16; o <<= 1) s += __shfl_xor(s, o);
      if (lrow == 0) red[rit*2 + (wid & 1)] = make_float2(m, s);
    }
  }
  __syncthreads();
  if (t < 128) {
    float2 a = red[t*2], b = red[t*2 + 1];
    float mn = fmaxf(a.x, b.x);
    float S = a.y*__expf(a.x - mn) + b.y*__expf(b.x - mn);
    part[(size_t)(m0 + t)*NS2 + nt] = make_float2(mn, S);
  }
}

// ------- combine per-tile partials -> per-row loss -------
__global__ void k_rowloss2(const float2* __restrict__ part,
                           const float* __restrict__ logits,
                           const int* __restrict__ tgt, float* __restrict__ rl) {
  int row = blockIdx.x;
  int lane = threadIdx.x;
  float M = -1e30f, S = 0.f;
  for (int i = lane; i < NS2; i += 64) {
    float2 p = part[(size_t)row*NS2 + i];
    float mn = fmaxf(M, p.x);
    S = S*__expf(M - mn) + p.y*__expf(p.x - mn);
    M = mn;
  }
  #pragma unroll
  for (int o = 1; o < 64; o <<= 1) {
    float Mo = __shfl_xor(M, o);
    float So = __shfl_xor(S, o);
    float mn = fmaxf(M, Mo);
    S = S*__expf(M - mn) + So*__expf(Mo - mn);
    M = mn;
  }
  if (lane == 0)
    rl[row] = (logf(S) + M) - logits[(size_t)row*V_ + tgt[row]];
}

// ------- flash attention -------
__global__ __launch_bounds__(256) void k_fattn(
    const float* __restrict__ qkv, const int* __restrict__ doc,
    __hip_bfloat16* __restrict__ y)
{
  __shared__ __align__(16) short q_lds[QBLK*64];
  __shared__ __align__(16) short k_lds[KVB*64];
  __shared__ __align__(16) short vt_lds[64*KVB];
  __shared__ __align__(16) short p_lds[4][16*64];
  __shared__ int doc_k[KVB];
  const int t = threadIdx.x;
  const int lane = t & 63;
  const int w = t >> 6;
  const int q0 = blockIdx.x * QBLK;
  const int h = blockIdx.y, b = blockIdx.z;
  const int lrow = lane & 15;
  const int lgrp = lane >> 4;
  const int crow = lgrp * 4;
  const size_t qs = 3*D_;

  const float* qbase = qkv + ((size_t)(b*T_ + q0))*qs + h*HD_;
  #pragma unroll
  for (int p = 0; p < 2; ++p) {
    int c = p*256 + t;
    int row = c >> 3, seg = c & 7;
    const float* src = qbase + (size_t)row*qs + seg*8;
    s16x8 s;
    #pragma unroll
    for (int j = 0; j < 8; ++j) s[j] = f2bf(src[j]);
    int dst = (row*128 + seg*16) ^ ((row & 7) << 4);
    *(s16x8*)((char*)q_lds + dst) = s;
  }
  int docq[4];
  #pragma unroll
  for (int r = 0; r < 4; ++r)
    docq[r] = doc[b*T_ + q0 + w*16 + crow + r];
  __syncthreads();

  float m_r[4], l_r[4];
  #pragma unroll
  for (int r = 0; r < 4; ++r) { m_r[r] = -1e30f; l_r[r] = 0.f; }
  f32x4 o[4];
  #pragma unroll
  for (int fd = 0; fd < 4; ++fd) o[fd] = (f32x4){0.f,0.f,0.f,0.f};

  const int ntiles = q0/KVB + 1;
  for (int kt = 0; kt < ntiles; ++kt) {
    const int kv0 = kt * KVB;
    const float* kbase = qkv + ((size_t)(b*T_ + kv0))*qs + D_ + h*HD_;
    #pragma unroll
    for (int p = 0; p < 2; ++p) {
      int c = p*256 + t;
      int row = c >> 3, seg = c & 7;
      const float* src = kbase + (size_t)row*qs + seg*8;
      s16x8 s;
      #pragma unroll
      for (int j = 0; j < 8; ++j) s[j] = f2bf(src[j]);
      int dst = (row*128 + seg*16) ^ ((row & 7) << 4);
      *(s16x8*)((char*)k_lds + dst) = s;
    }
    const float* vbase = qkv + ((size_t)(b*T_ + kv0))*qs + 2*D_ + h*HD_;
    #pragma unroll
    for (int p = 0; p < 2; ++p) {
      int c = p*256 + t;
      int kvr = c >> 3, d0 = (c & 7)*8;
      const float* src = vbase + (size_t)kvr*qs + d0;
      #pragma unroll
      for (int j = 0; j < 8; ++j) {
        int d = d0 + j;
        int off = (d*128 + kvr*2) ^ ((d & 7) << 4);
        *(short*)((char*)vt_lds + off) = f2bf(src[j]);
      }
    }
    if (t < KVB) doc_k[t] = doc[b*T_ + kv0 + t];
    __syncthreads();

    f32x4 sfr[4];
    #pragma unroll
    for (int fn = 0; fn < 4; ++fn) sfr[fn] = (f32x4){0.f,0.f,0.f,0.f};
    #pragma unroll
    for (int ks = 0; ks < 2; ++ks) {
      int arow = w*16 + lrow;
      s16x8 af = *(const s16x8*)((const char*)q_lds +
                 ((arow*128 + lgrp*16 + ks*64) ^ ((arow & 7) << 4)));
      #pragma unroll
      for (int fn = 0; fn < 4; ++fn) {
        int brow = fn*16 + lrow;
        s16x8 bf = *(const s16x8*)((const char*)k_lds +
                   ((brow*128 + lgrp*16 + ks*64) ^ ((brow & 7) << 4)));
        sfr[fn] = __builtin_amdgcn_mfma_f32_16x16x32_bf16(af, bf, sfr[fn], 0, 0, 0);
      }
    }
    int dk[4];
    #pragma unroll
    for (int fn = 0; fn < 4; ++fn) dk[fn] = doc_k[fn*16 + lrow];
    float rowmax[4] = {-1e30f, -1e30f, -1e30f, -1e30f};
    #pragma unroll
    for (int fn = 0; fn < 4; ++fn) {
      int col = kv0 + fn*16 + lrow;
      #pragma unroll
      for (int r = 0; r < 4; ++r) {
        int qrow = q0 + w*16 + crow + r;
        bool ok = (col <= qrow) && (dk[fn] == docq[r]);
        float v = ok ? sfr[fn][r] * 0.125f : -1e30f;
        sfr[fn][r] = v;
        rowmax[r] = fmaxf(rowmax[r], v);
      }
    }
    #pragma unroll
    for (int r = 0; r < 4; ++r) {
      float v = rowmax[r];
      #pragma unroll
      for (int off = 1; off < 16; off <<= 1) v = fmaxf(v, __shfl_xor(v, off));
      rowmax[r] = v;
    }
    float alpha[4], psum[4];
    #pragma unroll
    for (int r = 0; r < 4; ++r) {
      float mn = fmaxf(m_r[r], rowmax[r]);
      alpha[r] = __expf(m_r[r] - mn);
      m_r[r] = mn;
      psum[r] = 0.f;
    }
    #pragma unroll
    for (int fn = 0; fn < 4; ++fn) {
      #pragma unroll
      for (int r = 0; r < 4; ++r) {
        float sv = sfr[fn][r];
        float p = (sv < -5e29f) ? 0.f : __expf(sv - m_r[r]);
        psum[r] += p;
        int rl_ = crow + r;
        int off = (rl_*128 + (fn*16 + lrow)*2) ^ ((rl_ & 7) << 4);
        *(short*)((char*)p_lds[w] + off) = f2bf(p);
      }
    }
    #pragma unroll
    for (int r = 0; r < 4; ++r) {
      float v = psum[r];
      #pragma unroll
      for (int off = 1; off < 16; off <<= 1) v += __shfl_xor(v, off);
      l_r[r] = l_r[r]*alpha[r] + v;
    }
    #pragma unroll
    for (int fd = 0; fd < 4; ++fd)
      #pragma unroll
      for (int r = 0; r < 4; ++r)
        o[fd][r] *= alpha[r];
    __syncthreads();
    #pragma unroll
    for (int ks = 0; ks < 2; ++ks) {
      s16x8 af = *(const s16x8*)((const char*)p_lds[w] +
                 ((lrow*128 + lgrp*16 + ks*64) ^ ((lrow & 7) << 4)));
      #pragma unroll
      for (int fd = 0; fd < 4; ++fd) {
        int brow = fd*16 + lrow;
        s16x8 bf = *(const s16x8*)((const char*)vt_lds +
                   ((brow*128 + lgrp*16 + ks*64) ^ ((brow & 7) << 4)));
        o[fd] = __builtin_amdgcn_mfma_f32_16x16x32_bf16(af, bf, o[fd], 0, 0, 0);
      }
    }
    __syncthreads();
  }
  #pragma unroll
  for (int r = 0; r < 4; ++r) {
    float inv = 1.f / l_r[r];
    int rowg = b*T_ + q0 + w*16 + crow + r;
    #pragma unroll
    for (int fd = 0; fd < 4; ++fd) {
      int col = h*HD_ + fd*16 + lrow;
      y[(size_t)rowg*D_ + col] = __float2bfloat16(o[fd][r] * inv);
    }
  }
}

// ---------------- fallback per-row log-softmax ----------------
__global__ void k_rowloss(const float* __restrict__ logits,
                          const int* __restrict__ tgt, float* __restrict__ rl) {
  __shared__ float red[4];
  int row = blockIdx.x;
  const float* lr = logits + (size_t)row * V_;
  int tid = threadIdx.x;
  float m = -1e30f;
  for (int v = tid; v < V_; v += 256) m = fmaxf(m, lr[v]);
  #pragma unroll
  for (int o = 1; o < 64; o <<= 1) m = fmaxf(m, __shfl_xor(m, o));
  if ((tid & 63) == 0) red[tid >> 6] = m;
  __syncthreads();
  m = fmaxf(fmaxf(red[0], red[1]), fmaxf(red[2], red[3]));
  __syncthreads();
  float s = 0.f;
  for (int v = tid; v < V_; v += 256) s += __expf(lr[v] - m);
  #pragma unroll
  for (int o = 1; o < 64; o <<= 1) s += __shfl_xor(s, o);
  if ((tid & 63) == 0) red[tid >> 6] = s;
  __syncthreads();
  if (tid == 0) {
    s = red[0]+red[1]+red[2]+red[3];
    rl[row] = (logf(s) + m) - lr[tgt[row]];
  }
}

// ---------------- final loss = mean(rl) ----------------
__global__ void k_loss(const float* __restrict__ rl, float* __restrict__ out) {
  __shared__ float red[4];
  int tid = threadIdx.x;
  float s = 0.f;
  for (int i = tid; i < NTOK; i += 256) s += rl[i];
  #pragma unroll
  for (int o = 1; o < 64; o <<= 1) s += __shfl_xor(s, o);
  if ((tid & 63) == 0) red[tid >> 6] = s;
  __syncthreads();
  if (tid == 0) {
    s = red[0]+red[1]+red[2]+red[3];
    out[0] = s / (float)NTOK;
  }
}

extern "C" void kernel_launch(void* const* d_in, const int* in_sizes, int n_in,
                              void* d_out, int out_size, void* d_ws, size_t ws_size,
                              hipStream_t stream) {
  const int*   idx   = (const int*)d_in[0];
  const int*   tgt   = (const int*)d_in[1];
  const float* tok   = (const float*)d_in[2];
  const float* pos   = (const float*)d_in[3];
  const float* ln1_g = (const float*)d_in[4];
  const float* ln1_b = (const float*)d_in[5];
  const float* ln2_g = (const float*)d_in[6];
  const float* ln2_b = (const float*)d_in[7];
  const float* W_qkv = (const float*)d_in[8];
  const float* b_qkv = (const float*)d_in[9];
  const float* W_proj= (const float*)d_in[10];
  const float* b_proj= (const float*)d_in[11];
  const float* W_fc1 = (const float*)d_in[12];
  const float* b_fc1 = (const float*)d_in[13];
  const float* W_fc2 = (const float*)d_in[14];
  const float* b_fc2 = (const float*)d_in[15];
  const float* lnf_g = (const float*)d_in[16];
  const float* lnf_b = (const float*)d_in[17];

  float* out = (float*)d_out;

  char* ob = (char*)d_out;
  float*           x    = (float*)(ob + 0);
  float*           qkv  = (float*)(ob + (size_t)6291456);
  __hip_bfloat16*  y    = (__hip_bfloat16*)(ob + (size_t)25165824);
  __hip_bfloat16*  tff  = (__hip_bfloat16*)(ob + (size_t)28311552);
  __hip_bfloat16*  WTq  = (__hip_bfloat16*)(ob + (size_t)40894464);
  __hip_bfloat16*  WTp  = (__hip_bfloat16*)(ob + (size_t)62128128);
  __hip_bfloat16*  WT1  = (__hip_bfloat16*)(ob + (size_t)69206016);
  __hip_bfloat16*  WT2  = (__hip_bfloat16*)(ob + (size_t)97517568);  // ends 125,829,120

  char* wb = (char*)d_ws;
  __hip_bfloat16* h  = (__hip_bfloat16*)(wb + 0);                  // 3,145,728
  int*    doc  = (int*)  (wb + (size_t)3145728);                   // 8,192
  float*  rl   = (float*)(wb + (size_t)3153920);                   // 8,192
  float2* part = (float2*)(wb + (size_t)3162112);                  // 6,438,912
  const size_t ws_need = (size_t)3162112 + (size_t)NTOK*NS2*8;     // 9,601,024
  const bool fused_loss = (ws_size >= ws_need);

  dim3 tb(32, 8);
  k_wt<<<dim3(2304/32, 768/32, L_), tb, 0, stream>>>(W_qkv,  WTq,  768, 2304);
  k_wt<<<dim3( 768/32, 768/32, L_), tb, 0, stream>>>(W_proj, WTp,  768,  768);
  k_wt<<<dim3(3072/32, 768/32, L_), tb, 0, stream>>>(W_fc1,  WT1,  768, 3072);
  k_wt<<<dim3( 768/32,3072/32, L_), tb, 0, stream>>>(W_fc2,  WT2, 3072,  768);

  k_embed<<<(NTOK*D_ + 255)/256, 256, 0, stream>>>(idx, tok, pos, x);
  k_docid<<<1, 64, 0, stream>>>(idx, doc);

  for (int l = 0; l < L_; ++l) {
    k_ln<<<NTOK, 64, 0, stream>>>(x, ln1_g + l*D_, ln1_b + l*D_, h);
    k_mfma_nt<<<dim3(2304/128, NTOK/128), 256, 0, stream>>>(
        h, WTq + (size_t)l*2304*768, nullptr, b_qkv + (size_t)l*2304, nullptr,
        qkv, nullptr, NTOK, 2304, 768, 0);
    k_fattn<<<dim3(T_/QBLK, H_, B_), 256, 0, stream>>>(qkv, doc, y);
    k_mfma_nt<<<dim3(768/128, NTOK/128), 256, 0, stream>>>(
        y, WTp + (size_t)l*768*768, nullptr, b_proj + (size_t)l*768, x,
        x, nullptr, NTOK, 768, 768, 0);
    k_ln<<<NTOK, 64, 0, stream>>>(x, ln2_g + l*D_, ln2_b + l*D_, h);
    k_mfma_nt<<<dim3(3072/128, NTOK/128), 256, 0, stream>>>(
        h, WT1 + (size_t)l*3072*768, nullptr, b_fc1 + (size_t)l*3072, nullptr,
        nullptr, tff, NTOK, 3072, 768, 1);
    k_mfma_nt<<<dim3(768/128, NTOK/128), 256, 0, stream>>>(
        tff, WT2 + (size_t)l*768*3072, nullptr, b_fc2 + (size_t)l*768, x,
        x, nullptr, NTOK, 768, 3072, 0);
  }
  k_ln<<<NTOK, 64, 0, stream>>>(x, lnf_g, lnf_b, h);

  if (fused_loss) {
    // m-major grid: 16 consecutive blocks share one tok panel
    k_logits<<<dim3(NTOK/128, NS2), 256, 0, stream>>>(h, tok, out, part);
    k_rowloss2<<<NTOK, 64, 0, stream>>>(part, out, tgt, rl);
  } else {
    k_mfma_nt<<<dim3((V_ + 127)/128, NTOK/128), 256, 0, stream>>>(
        h, nullptr, tok, nullptr, nullptr, out, nullptr, NTOK, V_, 768, 0);
    k_rowloss<<<NTOK, 256, 0, stream>>>(out, tgt, rl);
  }
  k_loss<<<1, 256, 0, stream>>>(rl, out + (size_t)NTOK*V_);
}

// Round 9
// 2075.868 us; speedup vs baseline: 7.1921x; 1.0574x over previous
//
#include <hip/hip_runtime.h>
#include <hip/hip_bf16.h>
#include <math.h>

#define V_ 50257
#define L_ 6
#define H_ 12
#define D_ 768
#define HD_ 64
#define FF_ 3072
#define B_ 2
#define T_ 1024
#define NTOK (B_*T_)
#define EOS_ 50256
#define QBLK 64
#define KVB 64
#define NS2 393            // number of 128-col logit tiles

typedef __attribute__((ext_vector_type(8))) short s16x8;
typedef __attribute__((ext_vector_type(4))) float f32x4;

__device__ __forceinline__ short f2bf(float f) {
  __hip_bfloat16 h = __float2bfloat16(f);
  return *reinterpret_cast<short*>(&h);
}

// async global->LDS, 16B per lane; l must be the WAVE-uniform base (HW adds lane*16)
__device__ __forceinline__ void gl_lds16(const void* g, void* l) {
  __builtin_amdgcn_global_load_lds(
      (const __attribute__((address_space(1))) unsigned int*)g,
      (__attribute__((address_space(3))) unsigned int*)l, 16, 0, 0);
}

// ---------------- embedding ----------------
__global__ void k_embed(const int* __restrict__ idx, const float* __restrict__ tok,
                        const float* __restrict__ pos, float* __restrict__ x) {
  int gid = blockIdx.x * blockDim.x + threadIdx.x;
  const int total = NTOK * D_;
  if (gid >= total) return;
  int row = gid / D_;
  int d = gid - row * D_;
  int t = row & (T_ - 1);
  x[gid] = tok[(size_t)idx[row] * D_ + d] + pos[t * D_ + d];
}

// ---------------- doc ids ----------------
__global__ void k_docid(const int* __restrict__ idx, int* __restrict__ doc) {
  int b = threadIdx.x;
  if (b >= B_) return;
  int c = 0;
  for (int t = 0; t < T_; ++t) {
    int e = (idx[b*T_ + t] == EOS_) ? 1 : 0;
    doc[b*T_ + t] = c;
    c += e;
  }
}

// ---------------- tok f32 -> bf16 cast (no transpose; [V][768] k-major) --------
__global__ void k_cast_tok(const float* __restrict__ in,
                           __hip_bfloat16* __restrict__ out, long n8) {
  long i = (long)blockIdx.x*blockDim.x + threadIdx.x;
  long stride = (long)gridDim.x*blockDim.x;
  for (; i < n8; i += stride) {
    const float4* src = (const float4*)(in + i*8);
    float4 v0 = src[0], v1 = src[1];
    s16x8 s;
    s[0]=f2bf(v0.x); s[1]=f2bf(v0.y); s[2]=f2bf(v0.z); s[3]=f2bf(v0.w);
    s[4]=f2bf(v1.x); s[5]=f2bf(v1.y); s[6]=f2bf(v1.z); s[7]=f2bf(v1.w);
    *(s16x8*)((short*)out + i*8) = s;
  }
}

// ---------------- layernorm ----------------
__global__ void k_ln(const float* __restrict__ x, const float* __restrict__ g,
                     const float* __restrict__ b, __hip_bfloat16* __restrict__ out) {
  int row = blockIdx.x;
  const float* xr = x + (size_t)row * D_;
  int lane = threadIdx.x;
  float vals[D_/64];
  float s = 0.f;
  #pragma unroll
  for (int i = 0; i < D_/64; ++i) { vals[i] = xr[lane + i*64]; s += vals[i]; }
  #pragma unroll
  for (int o = 1; o < 64; o <<= 1) s += __shfl_xor(s, o);
  float mu = s * (1.f/D_);
  float v = 0.f;
  #pragma unroll
  for (int i = 0; i < D_/64; ++i) { float d0 = vals[i]-mu; v += d0*d0; }
  #pragma unroll
  for (int o = 1; o < 64; o <<= 1) v += __shfl_xor(v, o);
  float inv = rsqrtf(v * (1.f/D_) + 1e-5f);
  #pragma unroll
  for (int i = 0; i < D_/64; ++i) {
    int d = lane + i*64;
    out[(size_t)row*D_ + d] = __float2bfloat16((vals[i]-mu)*inv*g[d] + b[d]);
  }
}

// ------- weight transpose+cast -------
__global__ void k_wt(const float* __restrict__ in, __hip_bfloat16* __restrict__ out,
                     int K, int N) {
  __shared__ float tile[32][33];
  int l = blockIdx.z;
  const float* src = in + (size_t)l*K*N;
  __hip_bfloat16* dst = out + (size_t)l*N*K;
  int n0 = blockIdx.x*32, k0 = blockIdx.y*32;
  int tx = threadIdx.x, ty = threadIdx.y;
  #pragma unroll
  for (int i = 0; i < 4; ++i)
    tile[ty + i*8][tx] = src[(size_t)(k0 + ty + i*8)*N + n0 + tx];
  __syncthreads();
  #pragma unroll
  for (int i = 0; i < 4; ++i)
    dst[(size_t)(n0 + ty + i*8)*K + k0 + tx] = __float2bfloat16(tile[tx][ty + i*8]);
}

// ------- MFMA NT GEMM (128x128x64), gload_lds staging -------
__global__ __launch_bounds__(256) void k_mfma_nt(
    const __hip_bfloat16* __restrict__ A,
    const __hip_bfloat16* __restrict__ Bh,
    const float* __restrict__ Bf,
    const float* __restrict__ bias,
    const float* resid,
    float* outf, __hip_bfloat16* outh,
    int M, int N, int K, int gelu)
{
  __shared__ __align__(16) short lds_a[128*64];
  __shared__ __align__(16) short lds_b[128*64];
  const int t = threadIdx.x;
  const int m0 = blockIdx.y * 128;
  const int n0 = blockIdx.x * 128;
  const int lane = t & 63;
  const int wid = t >> 6;
  const int wm = (wid >> 1) * 64;
  const int wn = (wid & 1) * 64;
  const int lrow = lane & 15;
  const int lkb = (lane >> 4) * 16;
  const int wbase = (t & 192) * 16;

  f32x4 acc[4][4];
  #pragma unroll
  for (int i = 0; i < 4; ++i)
    #pragma unroll
    for (int j = 0; j < 4; ++j)
      acc[i][j] = (f32x4){0.f, 0.f, 0.f, 0.f};

  for (int k0 = 0; k0 < K; k0 += 64) {
    #pragma unroll
    for (int p = 0; p < 4; ++p) {
      int c = p*256 + t;
      int row = c >> 3;
      int colb = (c & 7) << 4;
      const char* src = (const char*)A + ((size_t)(m0+row)*K + k0)*2 + (colb ^ ((row & 7) << 4));
      gl_lds16(src, (char*)lds_a + p*4096 + wbase);
    }
    if (Bh) {
      #pragma unroll
      for (int p = 0; p < 4; ++p) {
        int c = p*256 + t;
        int row = c >> 3;
        int colb = (c & 7) << 4;
        const char* src = (const char*)Bh + ((size_t)(n0+row)*K + k0)*2 + (colb ^ ((row & 7) << 4));
        gl_lds16(src, (char*)lds_b + p*4096 + wbase);
      }
    } else {
      #pragma unroll
      for (int p = 0; p < 4; ++p) {
        int c = p*256 + t;
        int row = c >> 3;
        int colb = (c & 7) << 4;
        int gn = n0 + row;
        s16x8 s = {0,0,0,0,0,0,0,0};
        if (gn < N) {
          const char* src = (const char*)Bf + ((size_t)gn*K + k0)*4 + colb*2;
          float4 v0 = *(const float4*)src;
          float4 v1 = *(const float4*)(src + 16);
          s[0]=f2bf(v0.x); s[1]=f2bf(v0.y); s[2]=f2bf(v0.z); s[3]=f2bf(v0.w);
          s[4]=f2bf(v1.x); s[5]=f2bf(v1.y); s[6]=f2bf(v1.z); s[7]=f2bf(v1.w);
        }
        int dst = (row*128 + colb) ^ ((row & 7) << 4);
        *(s16x8*)((char*)lds_b + dst) = s;
      }
    }
    __syncthreads();
    #pragma unroll
    for (int ks = 0; ks < 2; ++ks) {
      s16x8 af[4], bfr[4];
      #pragma unroll
      for (int f = 0; f < 4; ++f) {
        int row = wm + f*16 + lrow;
        int off = (row*128 + ks*64 + lkb) ^ ((row & 7) << 4);
        af[f] = *(const s16x8*)((const char*)lds_a + off);
      }
      #pragma unroll
      for (int f = 0; f < 4; ++f) {
        int row = wn + f*16 + lrow;
        int off = (row*128 + ks*64 + lkb) ^ ((row & 7) << 4);
        bfr[f] = *(const s16x8*)((const char*)lds_b + off);
      }
      #pragma unroll
      for (int fm = 0; fm < 4; ++fm)
        #pragma unroll
        for (int fn = 0; fn < 4; ++fn)
          acc[fm][fn] = __builtin_amdgcn_mfma_f32_16x16x32_bf16(
              af[fm], bfr[fn], acc[fm][fn], 0, 0, 0);
    }
    __syncthreads();
  }
  const int crow = (lane >> 4) * 4;
  #pragma unroll
  for (int fm = 0; fm < 4; ++fm) {
    #pragma unroll
    for (int fn = 0; fn < 4; ++fn) {
      int col = n0 + wn + fn*16 + lrow;
      if (col >= N) continue;
      #pragma unroll
      for (int r = 0; r < 4; ++r) {
        int row = m0 + wm + fm*16 + crow + r;
        float v = acc[fm][fn][r];
        if (bias) v += bias[col];
        if (gelu) v = 0.5f * v * (1.f + erff(v * 0.70710678118654752f));
        if (resid) v += resid[(size_t)row*N + col];
        if (outf) outf[(size_t)row*N + col] = v;
        else      outh[(size_t)row*N + col] = __float2bfloat16(v);
      }
    }
  }
}

// ------- logits GEMM + fused per-tile softmax partials -------
// grid (16 m-tiles, 393 n-tiles), x fastest. Bh (bf16, gl_lds) preferred;
// Bf (f32, cvt staging) fallback. part[row][nt] = (max, sumexp) of tile.
__global__ __launch_bounds__(256) void k_logits(
    const __hip_bfloat16* __restrict__ A,   // h [2048][768] bf16
    const __hip_bfloat16* __restrict__ Bh,  // tokh [V][768] bf16 (or null)
    const float* __restrict__ Bf,           // tok [V][768] f32
    float* __restrict__ C,                  // logits [2048][V_] f32
    float2* __restrict__ part)              // [2048][NS2]
{
  __shared__ __align__(16) short lds_a[128*64];
  __shared__ __align__(16) short lds_b[128*64];
  const int t = threadIdx.x;
  const int m0 = blockIdx.x * 128;
  const int nt = blockIdx.y;
  const int n0 = nt * 128;
  const int lane = t & 63;
  const int wid = t >> 6;
  const int wm = (wid >> 1) * 64;
  const int wn = (wid & 1) * 64;
  const int lrow = lane & 15;
  const int lkb = (lane >> 4) * 16;
  const int wbase = (t & 192) * 16;

  f32x4 acc[4][4];
  #pragma unroll
  for (int i = 0; i < 4; ++i)
    #pragma unroll
    for (int j = 0; j < 4; ++j)
      acc[i][j] = (f32x4){0.f, 0.f, 0.f, 0.f};

  for (int k0 = 0; k0 < 768; k0 += 64) {
    #pragma unroll
    for (int p = 0; p < 4; ++p) {
      int c = p*256 + t;
      int row = c >> 3;
      int colb = (c & 7) << 4;
      const char* src = (const char*)A + ((size_t)(m0+row)*768 + k0)*2 + (colb ^ ((row & 7) << 4));
      gl_lds16(src, (char*)lds_a + p*4096 + wbase);
    }
    if (Bh) {
      // OOB rows of the ragged last tile read into the 128KB slack after tokh;
      // garbage columns are masked in the epilogue.
      #pragma unroll
      for (int p = 0; p < 4; ++p) {
        int c = p*256 + t;
        int row = c >> 3;
        int colb = (c & 7) << 4;
        const char* src = (const char*)Bh + ((size_t)(n0+row)*768 + k0)*2 + (colb ^ ((row & 7) << 4));
        gl_lds16(src, (char*)lds_b + p*4096 + wbase);
      }
    } else {
      #pragma unroll
      for (int p = 0; p < 4; ++p) {
        int c = p*256 + t;
        int row = c >> 3;
        int colb = (c & 7) << 4;
        int gn = n0 + row;
        s16x8 s = {0,0,0,0,0,0,0,0};
        if (gn < V_) {
          const char* src = (const char*)Bf + ((size_t)gn*768 + k0)*4 + colb*2;
          float4 v0 = *(const float4*)src;
          float4 v1 = *(const float4*)(src + 16);
          s[0]=f2bf(v0.x); s[1]=f2bf(v0.y); s[2]=f2bf(v0.z); s[3]=f2bf(v0.w);
          s[4]=f2bf(v1.x); s[5]=f2bf(v1.y); s[6]=f2bf(v1.z); s[7]=f2bf(v1.w);
        }
        int dst = (row*128 + colb) ^ ((row & 7) << 4);
        *(s16x8*)((char*)lds_b + dst) = s;
      }
    }
    __syncthreads();
    #pragma unroll
    for (int ks = 0; ks < 2; ++ks) {
      s16x8 af[4], bfr[4];
      #pragma unroll
      for (int f = 0; f < 4; ++f) {
        int row = wm + f*16 + lrow;
        int off = (row*128 + ks*64 + lkb) ^ ((row & 7) << 4);
        af[f] = *(const s16x8*)((const char*)lds_a + off);
      }
      #pragma unroll
      for (int f = 0; f < 4; ++f) {
        int row = wn + f*16 + lrow;
        int off = (row*128 + ks*64 + lkb) ^ ((row & 7) << 4);
        bfr[f] = *(const s16x8*)((const char*)lds_b + off);
      }
      #pragma unroll
      for (int fm = 0; fm < 4; ++fm)
        #pragma unroll
        for (int fn = 0; fn < 4; ++fn)
          acc[fm][fn] = __builtin_amdgcn_mfma_f32_16x16x32_bf16(
              af[fm], bfr[fn], acc[fm][fn], 0, 0, 0);
    }
    __syncthreads();
  }
  // ---- epilogue: write C + per-row (max,sumexp) partials over this 128-tile ----
  const int crow = (lane >> 4) * 4;
  bool valid[4];
  #pragma unroll
  for (int fn = 0; fn < 4; ++fn) valid[fn] = (n0 + wn + fn*16 + lrow) < V_;
  float2* red = (float2*)lds_a;   // [128 rows][2 wave-cols], safe after final barrier
  #pragma unroll
  for (int fm = 0; fm < 4; ++fm) {
    #pragma unroll
    for (int r = 0; r < 4; ++r) {
      int rit = wm + fm*16 + crow + r;
      int row = m0 + rit;
      float m = -1e30f;
      #pragma unroll
      for (int fn = 0; fn < 4; ++fn) {
        if (valid[fn]) {
          float v = acc[fm][fn][r];
          C[(size_t)row*V_ + n0 + wn + fn*16 + lrow] = v;
          m = fmaxf(m, v);
        }
      }
      #pragma unroll
      for (int o = 1; o < 16; o <<= 1) m = fmaxf(m, __shfl_xor(m, o));
      float s = 0.f;
      #pragma unroll
      for (int fn = 0; fn < 4; ++fn)
        if (valid[fn]) s += __expf(acc[fm][fn][r] - m);
      #pragma unroll
      for (int o = 1; o < 16; o <<= 1) s += __shfl_xor(s, o);
      if (lrow == 0) red[rit*2 + (wid & 1)] = make_float2(m, s);
    }
  }
  __syncthreads();
  if (t < 128) {
    float2 a = red[t*2], b = red[t*2 + 1];
    float mn = fmaxf(a.x, b.x);
    float S = a.y*__expf(a.x - mn) + b.y*__expf(b.x - mn);
    part[(size_t)(m0 + t)*NS2 + nt] = make_float2(mn, S);
  }
}

// ------- combine per-tile partials -> per-row loss -------
__global__ void k_rowloss2(const float2* __restrict__ part,
                           const float* __restrict__ logits,
                           const int* __restrict__ tgt, float* __restrict__ rl) {
  int row = blockIdx.x;
  int lane = threadIdx.x;
  float M = -1e30f, S = 0.f;
  for (int i = lane; i < NS2; i += 64) {
    float2 p = part[(size_t)row*NS2 + i];
    float mn = fmaxf(M, p.x);
    S = S*__expf(M - mn) + p.y*__expf(p.x - mn);
    M = mn;
  }
  #pragma unroll
  for (int o = 1; o < 64; o <<= 1) {
    float Mo = __shfl_xor(M, o);
    float So = __shfl_xor(S, o);
    float mn = fmaxf(M, Mo);
    S = S*__expf(M - mn) + So*__expf(Mo - mn);
    M = mn;
  }
  if (lane == 0)
    rl[row] = (logf(S) + M) - logits[(size_t)row*V_ + tgt[row]];
}

// ------- flash attention -------
__global__ __launch_bounds__(256) void k_fattn(
    const float* __restrict__ qkv, const int* __restrict__ doc,
    __hip_bfloat16* __restrict__ y)
{
  __shared__ __align__(16) short q_lds[QBLK*64];
  __shared__ __align__(16) short k_lds[KVB*64];
  __shared__ __align__(16) short vt_lds[64*KVB];
  __shared__ __align__(16) short p_lds[4][16*64];
  __shared__ int doc_k[KVB];
  const int t = threadIdx.x;
  const int lane = t & 63;
  const int w = t >> 6;
  const int q0 = blockIdx.x * QBLK;
  const int h = blockIdx.y, b = blockIdx.z;
  const int lrow = lane & 15;
  const int lgrp = lane >> 4;
  const int crow = lgrp * 4;
  const size_t qs = 3*D_;

  const float* qbase = qkv + ((size_t)(b*T_ + q0))*qs + h*HD_;
  #pragma unroll
  for (int p = 0; p < 2; ++p) {
    int c = p*256 + t;
    int row = c >> 3, seg = c & 7;
    const float* src = qbase + (size_t)row*qs + seg*8;
    s16x8 s;
    #pragma unroll
    for (int j = 0; j < 8; ++j) s[j] = f2bf(src[j]);
    int dst = (row*128 + seg*16) ^ ((row & 7) << 4);
    *(s16x8*)((char*)q_lds + dst) = s;
  }
  int docq[4];
  #pragma unroll
  for (int r = 0; r < 4; ++r)
    docq[r] = doc[b*T_ + q0 + w*16 + crow + r];
  __syncthreads();

  float m_r[4], l_r[4];
  #pragma unroll
  for (int r = 0; r < 4; ++r) { m_r[r] = -1e30f; l_r[r] = 0.f; }
  f32x4 o[4];
  #pragma unroll
  for (int fd = 0; fd < 4; ++fd) o[fd] = (f32x4){0.f,0.f,0.f,0.f};

  const int ntiles = q0/KVB + 1;
  for (int kt = 0; kt < ntiles; ++kt) {
    const int kv0 = kt * KVB;
    const float* kbase = qkv + ((size_t)(b*T_ + kv0))*qs + D_ + h*HD_;
    #pragma unroll
    for (int p = 0; p < 2; ++p) {
      int c = p*256 + t;
      int row = c >> 3, seg = c & 7;
      const float* src = kbase + (size_t)row*qs + seg*8;
      s16x8 s;
      #pragma unroll
      for (int j = 0; j < 8; ++j) s[j] = f2bf(src[j]);
      int dst = (row*128 + seg*16) ^ ((row & 7) << 4);
      *(s16x8*)((char*)k_lds + dst) = s;
    }
    const float* vbase = qkv + ((size_t)(b*T_ + kv0))*qs + 2*D_ + h*HD_;
    #pragma unroll
    for (int p = 0; p < 2; ++p) {
      int c = p*256 + t;
      int kvr = c >> 3, d0 = (c & 7)*8;
      const float* src = vbase + (size_t)kvr*qs + d0;
      #pragma unroll
      for (int j = 0; j < 8; ++j) {
        int d = d0 + j;
        int off = (d*128 + kvr*2) ^ ((d & 7) << 4);
        *(short*)((char*)vt_lds + off) = f2bf(src[j]);
      }
    }
    if (t < KVB) doc_k[t] = doc[b*T_ + kv0 + t];
    __syncthreads();

    f32x4 sfr[4];
    #pragma unroll
    for (int fn = 0; fn < 4; ++fn) sfr[fn] = (f32x4){0.f,0.f,0.f,0.f};
    #pragma unroll
    for (int ks = 0; ks < 2; ++ks) {
      int arow = w*16 + lrow;
      s16x8 af = *(const s16x8*)((const char*)q_lds +
                 ((arow*128 + lgrp*16 + ks*64) ^ ((arow & 7) << 4)));
      #pragma unroll
      for (int fn = 0; fn < 4; ++fn) {
        int brow = fn*16 + lrow;
        s16x8 bf = *(const s16x8*)((const char*)k_lds +
                   ((brow*128 + lgrp*16 + ks*64) ^ ((brow & 7) << 4)));
        sfr[fn] = __builtin_amdgcn_mfma_f32_16x16x32_bf16(af, bf, sfr[fn], 0, 0, 0);
      }
    }
    int dk[4];
    #pragma unroll
    for (int fn = 0; fn < 4; ++fn) dk[fn] = doc_k[fn*16 + lrow];
    float rowmax[4] = {-1e30f, -1e30f, -1e30f, -1e30f};
    #pragma unroll
    for (int fn = 0; fn < 4; ++fn) {
      int col = kv0 + fn*16 + lrow;
      #pragma unroll
      for (int r = 0; r < 4; ++r) {
        int qrow = q0 + w*16 + crow + r;
        bool ok = (col <= qrow) && (dk[fn] == docq[r]);
        float v = ok ? sfr[fn][r] * 0.125f : -1e30f;
        sfr[fn][r] = v;
        rowmax[r] = fmaxf(rowmax[r], v);
      }
    }
    #pragma unroll
    for (int r = 0; r < 4; ++r) {
      float v = rowmax[r];
      #pragma unroll
      for (int off = 1; off < 16; off <<= 1) v = fmaxf(v, __shfl_xor(v, off));
      rowmax[r] = v;
    }
    float alpha[4], psum[4];
    #pragma unroll
    for (int r = 0; r < 4; ++r) {
      float mn = fmaxf(m_r[r], rowmax[r]);
      alpha[r] = __expf(m_r[r] - mn);
      m_r[r] = mn;
      psum[r] = 0.f;
    }
    #pragma unroll
    for (int fn = 0; fn < 4; ++fn) {
      #pragma unroll
      for (int r = 0; r < 4; ++r) {
        float sv = sfr[fn][r];
        float p = (sv < -5e29f) ? 0.f : __expf(sv - m_r[r]);
        psum[r] += p;
        int rl_ = crow + r;
        int off = (rl_*128 + (fn*16 + lrow)*2) ^ ((rl_ & 7) << 4);
        *(short*)((char*)p_lds[w] + off) = f2bf(p);
      }
    }
    #pragma unroll
    for (int r = 0; r < 4; ++r) {
      float v = psum[r];
      #pragma unroll
      for (int off = 1; off < 16; off <<= 1) v += __shfl_xor(v, off);
      l_r[r] = l_r[r]*alpha[r] + v;
    }
    #pragma unroll
    for (int fd = 0; fd < 4; ++fd)
      #pragma unroll
      for (int r = 0; r < 4; ++r)
        o[fd][r] *= alpha[r];
    __syncthreads();
    #pragma unroll
    for (int ks = 0; ks < 2; ++ks) {
      s16x8 af = *(const s16x8*)((const char*)p_lds[w] +
                 ((lrow*128 + lgrp*16 + ks*64) ^ ((lrow & 7) << 4)));
      #pragma unroll
      for (int fd = 0; fd < 4; ++fd) {
        int brow = fd*16 + lrow;
        s16x8 bf = *(const s16x8*)((const char*)vt_lds +
                   ((brow*128 + lgrp*16 + ks*64) ^ ((brow & 7) << 4)));
        o[fd] = __builtin_amdgcn_mfma_f32_16x16x32_bf16(af, bf, o[fd], 0, 0, 0);
      }
    }
    __syncthreads();
  }
  #pragma unroll
  for (int r = 0; r < 4; ++r) {
    float inv = 1.f / l_r[r];
    int rowg = b*T_ + q0 + w*16 + crow + r;
    #pragma unroll
    for (int fd = 0; fd < 4; ++fd) {
      int col = h*HD_ + fd*16 + lrow;
      y[(size_t)rowg*D_ + col] = __float2bfloat16(o[fd][r] * inv);
    }
  }
}

// ---------------- fallback per-row log-softmax ----------------
__global__ void k_rowloss(const float* __restrict__ logits,
                          const int* __restrict__ tgt, float* __restrict__ rl) {
  __shared__ float red[4];
  int row = blockIdx.x;
  const float* lr = logits + (size_t)row * V_;
  int tid = threadIdx.x;
  float m = -1e30f;
  for (int v = tid; v < V_; v += 256) m = fmaxf(m, lr[v]);
  #pragma unroll
  for (int o = 1; o < 64; o <<= 1) m = fmaxf(m, __shfl_xor(m, o));
  if ((tid & 63) == 0) red[tid >> 6] = m;
  __syncthreads();
  m = fmaxf(fmaxf(red[0], red[1]), fmaxf(red[2], red[3]));
  __syncthreads();
  float s = 0.f;
  for (int v = tid; v < V_; v += 256) s += __expf(lr[v] - m);
  #pragma unroll
  for (int o = 1; o < 64; o <<= 1) s += __shfl_xor(s, o);
  if ((tid & 63) == 0) red[tid >> 6] = s;
  __syncthreads();
  if (tid == 0) {
    s = red[0]+red[1]+red[2]+red[3];
    rl[row] = (logf(s) + m) - lr[tgt[row]];
  }
}

// ---------------- final loss = mean(rl) ----------------
__global__ void k_loss(const float* __restrict__ rl, float* __restrict__ out) {
  __shared__ float red[4];
  int tid = threadIdx.x;
  float s = 0.f;
  for (int i = tid; i < NTOK; i += 256) s += rl[i];
  #pragma unroll
  for (int o = 1; o < 64; o <<= 1) s += __shfl_xor(s, o);
  if ((tid & 63) == 0) red[tid >> 6] = s;
  __syncthreads();
  if (tid == 0) {
    s = red[0]+red[1]+red[2]+red[3];
    out[0] = s / (float)NTOK;
  }
}

extern "C" void kernel_launch(void* const* d_in, const int* in_sizes, int n_in,
                              void* d_out, int out_size, void* d_ws, size_t ws_size,
                              hipStream_t stream) {
  const int*   idx   = (const int*)d_in[0];
  const int*   tgt   = (const int*)d_in[1];
  const float* tok   = (const float*)d_in[2];
  const float* pos   = (const float*)d_in[3];
  const float* ln1_g = (const float*)d_in[4];
  const float* ln1_b = (const float*)d_in[5];
  const float* ln2_g = (const float*)d_in[6];
  const float* ln2_b = (const float*)d_in[7];
  const float* W_qkv = (const float*)d_in[8];
  const float* b_qkv = (const float*)d_in[9];
  const float* W_proj= (const float*)d_in[10];
  const float* b_proj= (const float*)d_in[11];
  const float* W_fc1 = (const float*)d_in[12];
  const float* b_fc1 = (const float*)d_in[13];
  const float* W_fc2 = (const float*)d_in[14];
  const float* b_fc2 = (const float*)d_in[15];
  const float* lnf_g = (const float*)d_in[16];
  const float* lnf_b = (const float*)d_in[17];

  float* out = (float*)d_out;

  char* ob = (char*)d_out;
  float*           x    = (float*)(ob + 0);
  float*           qkv  = (float*)(ob + (size_t)6291456);
  __hip_bfloat16*  y    = (__hip_bfloat16*)(ob + (size_t)25165824);
  __hip_bfloat16*  tff  = (__hip_bfloat16*)(ob + (size_t)28311552);
  __hip_bfloat16*  WTq  = (__hip_bfloat16*)(ob + (size_t)40894464);
  __hip_bfloat16*  WTp  = (__hip_bfloat16*)(ob + (size_t)62128128);
  __hip_bfloat16*  WT1  = (__hip_bfloat16*)(ob + (size_t)69206016);
  __hip_bfloat16*  WT2  = (__hip_bfloat16*)(ob + (size_t)97517568);  // ends 125,829,120

  char* wb = (char*)d_ws;
  __hip_bfloat16* h    = (__hip_bfloat16*)(wb + 0);                  // 3,145,728
  int*    doc  = (int*)  (wb + (size_t)3145728);                     // 8,192
  float*  rl   = (float*)(wb + (size_t)3153920);                     // 8,192
  float2* part = (float2*)(wb + (size_t)3162112);                    // 6,438,912
  __hip_bfloat16* tokh = (__hip_bfloat16*)(wb + (size_t)9601024);    // 77,194,752 (+128K slack)
  const size_t ws_need_part = (size_t)9601024;                       // fused loss
  const size_t ws_need_tokh = (size_t)9601024 + 77194752 + 131072;   // 86,926,848
  const bool fused_loss = (ws_size >= ws_need_part);
  const bool use_tokh   = (ws_size >= ws_need_tokh);

  dim3 tb(32, 8);
  k_wt<<<dim3(2304/32, 768/32, L_), tb, 0, stream>>>(W_qkv,  WTq,  768, 2304);
  k_wt<<<dim3( 768/32, 768/32, L_), tb, 0, stream>>>(W_proj, WTp,  768,  768);
  k_wt<<<dim3(3072/32, 768/32, L_), tb, 0, stream>>>(W_fc1,  WT1,  768, 3072);
  k_wt<<<dim3( 768/32,3072/32, L_), tb, 0, stream>>>(W_fc2,  WT2, 3072,  768);
  if (use_tokh)
    k_cast_tok<<<2048, 256, 0, stream>>>(tok, tokh, (long)V_*768/8);

  k_embed<<<(NTOK*D_ + 255)/256, 256, 0, stream>>>(idx, tok, pos, x);
  k_docid<<<1, 64, 0, stream>>>(idx, doc);

  for (int l = 0; l < L_; ++l) {
    k_ln<<<NTOK, 64, 0, stream>>>(x, ln1_g + l*D_, ln1_b + l*D_, h);
    k_mfma_nt<<<dim3(2304/128, NTOK/128), 256, 0, stream>>>(
        h, WTq + (size_t)l*2304*768, nullptr, b_qkv + (size_t)l*2304, nullptr,
        qkv, nullptr, NTOK, 2304, 768, 0);
    k_fattn<<<dim3(T_/QBLK, H_, B_), 256, 0, stream>>>(qkv, doc, y);
    k_mfma_nt<<<dim3(768/128, NTOK/128), 256, 0, stream>>>(
        y, WTp + (size_t)l*768*768, nullptr, b_proj + (size_t)l*768, x,
        x, nullptr, NTOK, 768, 768, 0);
    k_ln<<<NTOK, 64, 0, stream>>>(x, ln2_g + l*D_, ln2_b + l*D_, h);
    k_mfma_nt<<<dim3(3072/128, NTOK/128), 256, 0, stream>>>(
        h, WT1 + (size_t)l*3072*768, nullptr, b_fc1 + (size_t)l*3072, nullptr,
        nullptr, tff, NTOK, 3072, 768, 1);
    k_mfma_nt<<<dim3(768/128, NTOK/128), 256, 0, stream>>>(
        tff, WT2 + (size_t)l*768*3072, nullptr, b_fc2 + (size_t)l*768, x,
        x, nullptr, NTOK, 768, 3072, 0);
  }
  k_ln<<<NTOK, 64, 0, stream>>>(x, lnf_g, lnf_b, h);

  if (fused_loss) {
    k_logits<<<dim3(NTOK/128, NS2), 256, 0, stream>>>(
        h, use_tokh ? tokh : nullptr, tok, out, part);
    k_rowloss2<<<NTOK, 64, 0, stream>>>(part, out, tgt, rl);
  } else {
    k_mfma_nt<<<dim3((V_ + 127)/128, NTOK/128), 256, 0, stream>>>(
        h, nullptr, tok, nullptr, nullptr, out, nullptr, NTOK, V_, 768, 0);
    k_rowloss<<<NTOK, 256, 0, stream>>>(out, tgt, rl);
  }
  k_loss<<<1, 256, 0, stream>>>(rl, out + (size_t)NTOK*V_);
}

// Round 10
// 1638.199 us; speedup vs baseline: 9.1135x; 1.2672x over previous
//
#include <hip/hip_runtime.h>
#include <hip/hip_bf16.h>
#include <math.h>

#define V_ 50257
#define L_ 6
#define H_ 12
#define D_ 768
#define HD_ 64
#define FF_ 3072
#define B_ 2
#define T_ 1024
#define NTOK (B_*T_)
#define EOS_ 50256
#define QBLK 64
#define KVB 64
#define NS2 393            // number of 128-col logit tiles

typedef __attribute__((ext_vector_type(8))) short s16x8;
typedef __attribute__((ext_vector_type(4))) float f32x4;

__device__ __forceinline__ short f2bf(float f) {
  __hip_bfloat16 h = __float2bfloat16(f);
  return *reinterpret_cast<short*>(&h);
}

// async global->LDS, 16B per lane; l must be the WAVE-uniform base (HW adds lane*16)
__device__ __forceinline__ void gl_lds16(const void* g, void* l) {
  __builtin_amdgcn_global_load_lds(
      (const __attribute__((address_space(1))) unsigned int*)g,
      (__attribute__((address_space(3))) unsigned int*)l, 16, 0, 0);
}

// ---------------- embedding ----------------
__global__ void k_embed(const int* __restrict__ idx, const float* __restrict__ tok,
                        const float* __restrict__ pos, float* __restrict__ x) {
  int gid = blockIdx.x * blockDim.x + threadIdx.x;
  const int total = NTOK * D_;
  if (gid >= total) return;
  int row = gid / D_;
  int d = gid - row * D_;
  int t = row & (T_ - 1);
  x[gid] = tok[(size_t)idx[row] * D_ + d] + pos[t * D_ + d];
}

// ---------------- doc ids ----------------
__global__ void k_docid(const int* __restrict__ idx, int* __restrict__ doc) {
  int b = threadIdx.x;
  if (b >= B_) return;
  int c = 0;
  for (int t = 0; t < T_; ++t) {
    int e = (idx[b*T_ + t] == EOS_) ? 1 : 0;
    doc[b*T_ + t] = c;
    c += e;
  }
}

// ---------------- tok f32 -> bf16 cast (no transpose; [V][768] k-major) --------
__global__ void k_cast_tok(const float* __restrict__ in,
                           __hip_bfloat16* __restrict__ out, long n8) {
  long i = (long)blockIdx.x*blockDim.x + threadIdx.x;
  long stride = (long)gridDim.x*blockDim.x;
  for (; i < n8; i += stride) {
    const float4* src = (const float4*)(in + i*8);
    float4 v0 = src[0], v1 = src[1];
    s16x8 s;
    s[0]=f2bf(v0.x); s[1]=f2bf(v0.y); s[2]=f2bf(v0.z); s[3]=f2bf(v0.w);
    s[4]=f2bf(v1.x); s[5]=f2bf(v1.y); s[6]=f2bf(v1.z); s[7]=f2bf(v1.w);
    *(s16x8*)((short*)out + i*8) = s;
  }
}

// ---------------- layernorm ----------------
__global__ void k_ln(const float* __restrict__ x, const float* __restrict__ g,
                     const float* __restrict__ b, __hip_bfloat16* __restrict__ out) {
  int row = blockIdx.x;
  const float* xr = x + (size_t)row * D_;
  int lane = threadIdx.x;
  float vals[D_/64];
  float s = 0.f;
  #pragma unroll
  for (int i = 0; i < D_/64; ++i) { vals[i] = xr[lane + i*64]; s += vals[i]; }
  #pragma unroll
  for (int o = 1; o < 64; o <<= 1) s += __shfl_xor(s, o);
  float mu = s * (1.f/D_);
  float v = 0.f;
  #pragma unroll
  for (int i = 0; i < D_/64; ++i) { float d0 = vals[i]-mu; v += d0*d0; }
  #pragma unroll
  for (int o = 1; o < 64; o <<= 1) v += __shfl_xor(v, o);
  float inv = rsqrtf(v * (1.f/D_) + 1e-5f);
  #pragma unroll
  for (int i = 0; i < D_/64; ++i) {
    int d = lane + i*64;
    out[(size_t)row*D_ + d] = __float2bfloat16((vals[i]-mu)*inv*g[d] + b[d]);
  }
}

// ------- weight transpose+cast -------
__global__ void k_wt(const float* __restrict__ in, __hip_bfloat16* __restrict__ out,
                     int K, int N) {
  __shared__ float tile[32][33];
  int l = blockIdx.z;
  const float* src = in + (size_t)l*K*N;
  __hip_bfloat16* dst = out + (size_t)l*N*K;
  int n0 = blockIdx.x*32, k0 = blockIdx.y*32;
  int tx = threadIdx.x, ty = threadIdx.y;
  #pragma unroll
  for (int i = 0; i < 4; ++i)
    tile[ty + i*8][tx] = src[(size_t)(k0 + ty + i*8)*N + n0 + tx];
  __syncthreads();
  #pragma unroll
  for (int i = 0; i < 4; ++i)
    dst[(size_t)(n0 + ty + i*8)*K + k0 + tx] = __float2bfloat16(tile[tx][ty + i*8]);
}

// ------- MFMA NT GEMM (128x128x64), gload_lds staging -------
__global__ __launch_bounds__(256) void k_mfma_nt(
    const __hip_bfloat16* __restrict__ A,
    const __hip_bfloat16* __restrict__ Bh,
    const float* __restrict__ Bf,
    const float* __restrict__ bias,
    const float* resid,
    float* outf, __hip_bfloat16* outh,
    int M, int N, int K, int gelu)
{
  __shared__ __align__(16) short lds_a[128*64];
  __shared__ __align__(16) short lds_b[128*64];
  const int t = threadIdx.x;
  const int m0 = blockIdx.y * 128;
  const int n0 = blockIdx.x * 128;
  const int lane = t & 63;
  const int wid = t >> 6;
  const int wm = (wid >> 1) * 64;
  const int wn = (wid & 1) * 64;
  const int lrow = lane & 15;
  const int lkb = (lane >> 4) * 16;
  const int wbase = (t & 192) * 16;

  f32x4 acc[4][4];
  #pragma unroll
  for (int i = 0; i < 4; ++i)
    #pragma unroll
    for (int j = 0; j < 4; ++j)
      acc[i][j] = (f32x4){0.f, 0.f, 0.f, 0.f};

  for (int k0 = 0; k0 < K; k0 += 64) {
    #pragma unroll
    for (int p = 0; p < 4; ++p) {
      int c = p*256 + t;
      int row = c >> 3;
      int colb = (c & 7) << 4;
      const char* src = (const char*)A + ((size_t)(m0+row)*K + k0)*2 + (colb ^ ((row & 7) << 4));
      gl_lds16(src, (char*)lds_a + p*4096 + wbase);
    }
    if (Bh) {
      #pragma unroll
      for (int p = 0; p < 4; ++p) {
        int c = p*256 + t;
        int row = c >> 3;
        int colb = (c & 7) << 4;
        const char* src = (const char*)Bh + ((size_t)(n0+row)*K + k0)*2 + (colb ^ ((row & 7) << 4));
        gl_lds16(src, (char*)lds_b + p*4096 + wbase);
      }
    } else {
      #pragma unroll
      for (int p = 0; p < 4; ++p) {
        int c = p*256 + t;
        int row = c >> 3;
        int colb = (c & 7) << 4;
        int gn = n0 + row;
        s16x8 s = {0,0,0,0,0,0,0,0};
        if (gn < N) {
          const char* src = (const char*)Bf + ((size_t)gn*K + k0)*4 + colb*2;
          float4 v0 = *(const float4*)src;
          float4 v1 = *(const float4*)(src + 16);
          s[0]=f2bf(v0.x); s[1]=f2bf(v0.y); s[2]=f2bf(v0.z); s[3]=f2bf(v0.w);
          s[4]=f2bf(v1.x); s[5]=f2bf(v1.y); s[6]=f2bf(v1.z); s[7]=f2bf(v1.w);
        }
        int dst = (row*128 + colb) ^ ((row & 7) << 4);
        *(s16x8*)((char*)lds_b + dst) = s;
      }
    }
    __syncthreads();
    #pragma unroll
    for (int ks = 0; ks < 2; ++ks) {
      s16x8 af[4], bfr[4];
      #pragma unroll
      for (int f = 0; f < 4; ++f) {
        int row = wm + f*16 + lrow;
        int off = (row*128 + ks*64 + lkb) ^ ((row & 7) << 4);
        af[f] = *(const s16x8*)((const char*)lds_a + off);
      }
      #pragma unroll
      for (int f = 0; f < 4; ++f) {
        int row = wn + f*16 + lrow;
        int off = (row*128 + ks*64 + lkb) ^ ((row & 7) << 4);
        bfr[f] = *(const s16x8*)((const char*)lds_b + off);
      }
      #pragma unroll
      for (int fm = 0; fm < 4; ++fm)
        #pragma unroll
        for (int fn = 0; fn < 4; ++fn)
          acc[fm][fn] = __builtin_amdgcn_mfma_f32_16x16x32_bf16(
              af[fm], bfr[fn], acc[fm][fn], 0, 0, 0);
    }
    __syncthreads();
  }
  const int crow = (lane >> 4) * 4;
  #pragma unroll
  for (int fm = 0; fm < 4; ++fm) {
    #pragma unroll
    for (int fn = 0; fn < 4; ++fn) {
      int col = n0 + wn + fn*16 + lrow;
      if (col >= N) continue;
      #pragma unroll
      for (int r = 0; r < 4; ++r) {
        int row = m0 + wm + fm*16 + crow + r;
        float v = acc[fm][fn][r];
        if (bias) v += bias[col];
        if (gelu) v = 0.5f * v * (1.f + erff(v * 0.70710678118654752f));
        if (resid) v += resid[(size_t)row*N + col];
        if (outf) outf[(size_t)row*N + col] = v;
        else      outh[(size_t)row*N + col] = __float2bfloat16(v);
      }
    }
  }
}

// ------- small-N MFMA NT GEMM (64x64x64): for N=768 layers (proj, fc2) -------
// 4 waves (2x2), wave-tile 32x32, 16KB LDS -> many blocks/CU, 384-block grids.
__global__ __launch_bounds__(256) void k_mfma_nt64(
    const __hip_bfloat16* __restrict__ A,
    const __hip_bfloat16* __restrict__ Bh,
    const float* __restrict__ bias,
    const float* resid,
    float* outf,
    int M, int N, int K)
{
  __shared__ __align__(16) short lds_a[64*64];
  __shared__ __align__(16) short lds_b[64*64];
  const int t = threadIdx.x;
  const int m0 = blockIdx.y * 64;
  const int n0 = blockIdx.x * 64;
  const int lane = t & 63;
  const int wid = t >> 6;
  const int wm = (wid >> 1) * 32;
  const int wn = (wid & 1) * 32;
  const int lrow = lane & 15;
  const int lkb = (lane >> 4) * 16;
  const int wbase = (t & 192) * 16;

  f32x4 acc[2][2];
  #pragma unroll
  for (int i = 0; i < 2; ++i)
    #pragma unroll
    for (int j = 0; j < 2; ++j)
      acc[i][j] = (f32x4){0.f, 0.f, 0.f, 0.f};

  for (int k0 = 0; k0 < K; k0 += 64) {
    #pragma unroll
    for (int p = 0; p < 2; ++p) {
      int c = p*256 + t;
      int row = c >> 3;
      int colb = (c & 7) << 4;
      const char* srcA = (const char*)A + ((size_t)(m0+row)*K + k0)*2 + (colb ^ ((row & 7) << 4));
      gl_lds16(srcA, (char*)lds_a + p*4096 + wbase);
    }
    #pragma unroll
    for (int p = 0; p < 2; ++p) {
      int c = p*256 + t;
      int row = c >> 3;
      int colb = (c & 7) << 4;
      const char* srcB = (const char*)Bh + ((size_t)(n0+row)*K + k0)*2 + (colb ^ ((row & 7) << 4));
      gl_lds16(srcB, (char*)lds_b + p*4096 + wbase);
    }
    __syncthreads();
    #pragma unroll
    for (int ks = 0; ks < 2; ++ks) {
      s16x8 af[2], bfr[2];
      #pragma unroll
      for (int f = 0; f < 2; ++f) {
        int row = wm + f*16 + lrow;
        int off = (row*128 + ks*64 + lkb) ^ ((row & 7) << 4);
        af[f] = *(const s16x8*)((const char*)lds_a + off);
      }
      #pragma unroll
      for (int f = 0; f < 2; ++f) {
        int row = wn + f*16 + lrow;
        int off = (row*128 + ks*64 + lkb) ^ ((row & 7) << 4);
        bfr[f] = *(const s16x8*)((const char*)lds_b + off);
      }
      #pragma unroll
      for (int fm = 0; fm < 2; ++fm)
        #pragma unroll
        for (int fn = 0; fn < 2; ++fn)
          acc[fm][fn] = __builtin_amdgcn_mfma_f32_16x16x32_bf16(
              af[fm], bfr[fn], acc[fm][fn], 0, 0, 0);
    }
    __syncthreads();
  }
  const int crow = (lane >> 4) * 4;
  #pragma unroll
  for (int fm = 0; fm < 2; ++fm) {
    #pragma unroll
    for (int fn = 0; fn < 2; ++fn) {
      int col = n0 + wn + fn*16 + lrow;
      #pragma unroll
      for (int r = 0; r < 4; ++r) {
        int row = m0 + wm + fm*16 + crow + r;
        float v = acc[fm][fn][r] + bias[col];
        if (resid) v += resid[(size_t)row*N + col];
        outf[(size_t)row*N + col] = v;
      }
    }
  }
}

// ------- logits GEMM + fused per-tile softmax partials (nt-stores) -------
__global__ __launch_bounds__(256) void k_logits(
    const __hip_bfloat16* __restrict__ A,   // h [2048][768] bf16
    const __hip_bfloat16* __restrict__ Bh,  // tokh [V][768] bf16 (or null)
    const float* __restrict__ Bf,           // tok [V][768] f32
    float* __restrict__ C,                  // logits [2048][V_] f32
    float2* __restrict__ part)              // [2048][NS2]
{
  __shared__ __align__(16) short lds_a[128*64];
  __shared__ __align__(16) short lds_b[128*64];
  const int t = threadIdx.x;
  const int m0 = blockIdx.x * 128;
  const int nt = blockIdx.y;
  const int n0 = nt * 128;
  const int lane = t & 63;
  const int wid = t >> 6;
  const int wm = (wid >> 1) * 64;
  const int wn = (wid & 1) * 64;
  const int lrow = lane & 15;
  const int lkb = (lane >> 4) * 16;
  const int wbase = (t & 192) * 16;

  f32x4 acc[4][4];
  #pragma unroll
  for (int i = 0; i < 4; ++i)
    #pragma unroll
    for (int j = 0; j < 4; ++j)
      acc[i][j] = (f32x4){0.f, 0.f, 0.f, 0.f};

  for (int k0 = 0; k0 < 768; k0 += 64) {
    #pragma unroll
    for (int p = 0; p < 4; ++p) {
      int c = p*256 + t;
      int row = c >> 3;
      int colb = (c & 7) << 4;
      const char* src = (const char*)A + ((size_t)(m0+row)*768 + k0)*2 + (colb ^ ((row & 7) << 4));
      gl_lds16(src, (char*)lds_a + p*4096 + wbase);
    }
    if (Bh) {
      // OOB rows of the ragged last tile read into the 128KB slack after tokh;
      // garbage columns are masked in the epilogue.
      #pragma unroll
      for (int p = 0; p < 4; ++p) {
        int c = p*256 + t;
        int row = c >> 3;
        int colb = (c & 7) << 4;
        const char* src = (const char*)Bh + ((size_t)(n0+row)*768 + k0)*2 + (colb ^ ((row & 7) << 4));
        gl_lds16(src, (char*)lds_b + p*4096 + wbase);
      }
    } else {
      #pragma unroll
      for (int p = 0; p < 4; ++p) {
        int c = p*256 + t;
        int row = c >> 3;
        int colb = (c & 7) << 4;
        int gn = n0 + row;
        s16x8 s = {0,0,0,0,0,0,0,0};
        if (gn < V_) {
          const char* src = (const char*)Bf + ((size_t)gn*768 + k0)*4 + colb*2;
          float4 v0 = *(const float4*)src;
          float4 v1 = *(const float4*)(src + 16);
          s[0]=f2bf(v0.x); s[1]=f2bf(v0.y); s[2]=f2bf(v0.z); s[3]=f2bf(v0.w);
          s[4]=f2bf(v1.x); s[5]=f2bf(v1.y); s[6]=f2bf(v1.z); s[7]=f2bf(v1.w);
        }
        int dst = (row*128 + colb) ^ ((row & 7) << 4);
        *(s16x8*)((char*)lds_b + dst) = s;
      }
    }
    __syncthreads();
    #pragma unroll
    for (int ks = 0; ks < 2; ++ks) {
      s16x8 af[4], bfr[4];
      #pragma unroll
      for (int f = 0; f < 4; ++f) {
        int row = wm + f*16 + lrow;
        int off = (row*128 + ks*64 + lkb) ^ ((row & 7) << 4);
        af[f] = *(const s16x8*)((const char*)lds_a + off);
      }
      #pragma unroll
      for (int f = 0; f < 4; ++f) {
        int row = wn + f*16 + lrow;
        int off = (row*128 + ks*64 + lkb) ^ ((row & 7) << 4);
        bfr[f] = *(const s16x8*)((const char*)lds_b + off);
      }
      #pragma unroll
      for (int fm = 0; fm < 4; ++fm)
        #pragma unroll
        for (int fn = 0; fn < 4; ++fn)
          acc[fm][fn] = __builtin_amdgcn_mfma_f32_16x16x32_bf16(
              af[fm], bfr[fn], acc[fm][fn], 0, 0, 0);
    }
    __syncthreads();
  }
  // ---- epilogue: nt-store C + per-row (max,sumexp) partials ----
  const int crow = (lane >> 4) * 4;
  bool valid[4];
  #pragma unroll
  for (int fn = 0; fn < 4; ++fn) valid[fn] = (n0 + wn + fn*16 + lrow) < V_;
  float2* red = (float2*)lds_a;   // [128 rows][2 wave-cols], safe after final barrier
  #pragma unroll
  for (int fm = 0; fm < 4; ++fm) {
    #pragma unroll
    for (int r = 0; r < 4; ++r) {
      int rit = wm + fm*16 + crow + r;
      int row = m0 + rit;
      float m = -1e30f;
      #pragma unroll
      for (int fn = 0; fn < 4; ++fn) {
        if (valid[fn]) {
          float v = acc[fm][fn][r];
          __builtin_nontemporal_store(v, &C[(size_t)row*V_ + n0 + wn + fn*16 + lrow]);
          m = fmaxf(m, v);
        }
      }
      #pragma unroll
      for (int o = 1; o < 16; o <<= 1) m = fmaxf(m, __shfl_xor(m, o));
      float s = 0.f;
      #pragma unroll
      for (int fn = 0; fn < 4; ++fn)
        if (valid[fn]) s += __expf(acc[fm][fn][r] - m);
      #pragma unroll
      for (int o = 1; o < 16; o <<= 1) s += __shfl_xor(s, o);
      if (lrow == 0) red[rit*2 + (wid & 1)] = make_float2(m, s);
    }
  }
  __syncthreads();
  if (t < 128) {
    float2 a = red[t*2], b = red[t*2 + 1];
    float mn = fmaxf(a.x, b.x);
    float S = a.y*__expf(a.x - mn) + b.y*__expf(b.x - mn);
    part[(size_t)(m0 + t)*NS2 + nt] = make_float2(mn, S);
  }
}

// ------- combine per-tile partials -> per-row loss -------
__global__ void k_rowloss2(const float2* __restrict__ part,
                           const float* __restrict__ logits,
                           const int* __restrict__ tgt, float* __restrict__ rl) {
  int row = blockIdx.x;
  int lane = threadIdx.x;
  float M = -1e30f, S = 0.f;
  for (int i = lane; i < NS2; i += 64) {
    float2 p = part[(size_t)row*NS2 + i];
    float mn = fmaxf(M, p.x);
    S = S*__expf(M - mn) + p.y*__expf(p.x - mn);
    M = mn;
  }
  #pragma unroll
  for (int o = 1; o < 64; o <<= 1) {
    float Mo = __shfl_xor(M, o);
    float So = __shfl_xor(S, o);
    float mn = fmaxf(M, Mo);
    S = S*__expf(M - mn) + So*__expf(Mo - mn);
    M = mn;
  }
  if (lane == 0)
    rl[row] = (logf(S) + M) - logits[(size_t)row*V_ + tgt[row]];
}

// ------- flash attention -------
__global__ __launch_bounds__(256) void k_fattn(
    const float* __restrict__ qkv, const int* __restrict__ doc,
    __hip_bfloat16* __restrict__ y)
{
  __shared__ __align__(16) short q_lds[QBLK*64];
  __shared__ __align__(16) short k_lds[KVB*64];
  __shared__ __align__(16) short vt_lds[64*KVB];
  __shared__ __align__(16) short p_lds[4][16*64];
  __shared__ int doc_k[KVB];
  const int t = threadIdx.x;
  const int lane = t & 63;
  const int w = t >> 6;
  const int q0 = blockIdx.x * QBLK;
  const int h = blockIdx.y, b = blockIdx.z;
  const int lrow = lane & 15;
  const int lgrp = lane >> 4;
  const int crow = lgrp * 4;
  const size_t qs = 3*D_;

  const float* qbase = qkv + ((size_t)(b*T_ + q0))*qs + h*HD_;
  #pragma unroll
  for (int p = 0; p < 2; ++p) {
    int c = p*256 + t;
    int row = c >> 3, seg = c & 7;
    const float* src = qbase + (size_t)row*qs + seg*8;
    s16x8 s;
    #pragma unroll
    for (int j = 0; j < 8; ++j) s[j] = f2bf(src[j]);
    int dst = (row*128 + seg*16) ^ ((row & 7) << 4);
    *(s16x8*)((char*)q_lds + dst) = s;
  }
  int docq[4];
  #pragma unroll
  for (int r = 0; r < 4; ++r)
    docq[r] = doc[b*T_ + q0 + w*16 + crow + r];
  __syncthreads();

  float m_r[4], l_r[4];
  #pragma unroll
  for (int r = 0; r < 4; ++r) { m_r[r] = -1e30f; l_r[r] = 0.f; }
  f32x4 o[4];
  #pragma unroll
  for (int fd = 0; fd < 4; ++fd) o[fd] = (f32x4){0.f,0.f,0.f,0.f};

  const int ntiles = q0/KVB + 1;
  for (int kt = 0; kt < ntiles; ++kt) {
    const int kv0 = kt * KVB;
    const float* kbase = qkv + ((size_t)(b*T_ + kv0))*qs + D_ + h*HD_;
    #pragma unroll
    for (int p = 0; p < 2; ++p) {
      int c = p*256 + t;
      int row = c >> 3, seg = c & 7;
      const float* src = kbase + (size_t)row*qs + seg*8;
      s16x8 s;
      #pragma unroll
      for (int j = 0; j < 8; ++j) s[j] = f2bf(src[j]);
      int dst = (row*128 + seg*16) ^ ((row & 7) << 4);
      *(s16x8*)((char*)k_lds + dst) = s;
    }
    const float* vbase = qkv + ((size_t)(b*T_ + kv0))*qs + 2*D_ + h*HD_;
    #pragma unroll
    for (int p = 0; p < 2; ++p) {
      int c = p*256 + t;
      int kvr = c >> 3, d0 = (c & 7)*8;
      const float* src = vbase + (size_t)kvr*qs + d0;
      #pragma unroll
      for (int j = 0; j < 8; ++j) {
        int d = d0 + j;
        int off = (d*128 + kvr*2) ^ ((d & 7) << 4);
        *(short*)((char*)vt_lds + off) = f2bf(src[j]);
      }
    }
    if (t < KVB) doc_k[t] = doc[b*T_ + kv0 + t];
    __syncthreads();

    f32x4 sfr[4];
    #pragma unroll
    for (int fn = 0; fn < 4; ++fn) sfr[fn] = (f32x4){0.f,0.f,0.f,0.f};
    #pragma unroll
    for (int ks = 0; ks < 2; ++ks) {
      int arow = w*16 + lrow;
      s16x8 af = *(const s16x8*)((const char*)q_lds +
                 ((arow*128 + lgrp*16 + ks*64) ^ ((arow & 7) << 4)));
      #pragma unroll
      for (int fn = 0; fn < 4; ++fn) {
        int brow = fn*16 + lrow;
        s16x8 bf = *(const s16x8*)((const char*)k_lds +
                   ((brow*128 + lgrp*16 + ks*64) ^ ((brow & 7) << 4)));
        sfr[fn] = __builtin_amdgcn_mfma_f32_16x16x32_bf16(af, bf, sfr[fn], 0, 0, 0);
      }
    }
    int dk[4];
    #pragma unroll
    for (int fn = 0; fn < 4; ++fn) dk[fn] = doc_k[fn*16 + lrow];
    float rowmax[4] = {-1e30f, -1e30f, -1e30f, -1e30f};
    #pragma unroll
    for (int fn = 0; fn < 4; ++fn) {
      int col = kv0 + fn*16 + lrow;
      #pragma unroll
      for (int r = 0; r < 4; ++r) {
        int qrow = q0 + w*16 + crow + r;
        bool ok = (col <= qrow) && (dk[fn] == docq[r]);
        float v = ok ? sfr[fn][r] * 0.125f : -1e30f;
        sfr[fn][r] = v;
        rowmax[r] = fmaxf(rowmax[r], v);
      }
    }
    #pragma unroll
    for (int r = 0; r < 4; ++r) {
      float v = rowmax[r];
      #pragma unroll
      for (int off = 1; off < 16; off <<= 1) v = fmaxf(v, __shfl_xor(v, off));
      rowmax[r] = v;
    }
    float alpha[4], psum[4];
    #pragma unroll
    for (int r = 0; r < 4; ++r) {
      float mn = fmaxf(m_r[r], rowmax[r]);
      alpha[r] = __expf(m_r[r] - mn);
      m_r[r] = mn;
      psum[r] = 0.f;
    }
    #pragma unroll
    for (int fn = 0; fn < 4; ++fn) {
      #pragma unroll
      for (int r = 0; r < 4; ++r) {
        float sv = sfr[fn][r];
        float p = (sv < -5e29f) ? 0.f : __expf(sv - m_r[r]);
        psum[r] += p;
        int rl_ = crow + r;
        int off = (rl_*128 + (fn*16 + lrow)*2) ^ ((rl_ & 7) << 4);
        *(short*)((char*)p_lds[w] + off) = f2bf(p);
      }
    }
    #pragma unroll
    for (int r = 0; r < 4; ++r) {
      float v = psum[r];
      #pragma unroll
      for (int off = 1; off < 16; off <<= 1) v += __shfl_xor(v, off);
      l_r[r] = l_r[r]*alpha[r] + v;
    }
    #pragma unroll
    for (int fd = 0; fd < 4; ++fd)
      #pragma unroll
      for (int r = 0; r < 4; ++r)
        o[fd][r] *= alpha[r];
    __syncthreads();
    #pragma unroll
    for (int ks = 0; ks < 2; ++ks) {
      s16x8 af = *(const s16x8*)((const char*)p_lds[w] +
                 ((lrow*128 + lgrp*16 + ks*64) ^ ((lrow & 7) << 4)));
      #pragma unroll
      for (int fd = 0; fd < 4; ++fd) {
        int brow = fd*16 + lrow;
        s16x8 bf = *(const s16x8*)((const char*)vt_lds +
                   ((brow*128 + lgrp*16 + ks*64) ^ ((brow & 7) << 4)));
        o[fd] = __builtin_amdgcn_mfma_f32_16x16x32_bf16(af, bf, o[fd], 0, 0, 0);
      }
    }
    __syncthreads();
  }
  #pragma unroll
  for (int r = 0; r < 4; ++r) {
    float inv = 1.f / l_r[r];
    int rowg = b*T_ + q0 + w*16 + crow + r;
    #pragma unroll
    for (int fd = 0; fd < 4; ++fd) {
      int col = h*HD_ + fd*16 + lrow;
      y[(size_t)rowg*D_ + col] = __float2bfloat16(o[fd][r] * inv);
    }
  }
}

// ---------------- fallback per-row log-softmax ----------------
__global__ void k_rowloss(const float* __restrict__ logits,
                          const int* __restrict__ tgt, float* __restrict__ rl) {
  __shared__ float red[4];
  int row = blockIdx.x;
  const float* lr = logits + (size_t)row * V_;
  int tid = threadIdx.x;
  float m = -1e30f;
  for (int v = tid; v < V_; v += 256) m = fmaxf(m, lr[v]);
  #pragma unroll
  for (int o = 1; o < 64; o <<= 1) m = fmaxf(m, __shfl_xor(m, o));
  if ((tid & 63) == 0) red[tid >> 6] = m;
  __syncthreads();
  m = fmaxf(fmaxf(red[0], red[1]), fmaxf(red[2], red[3]));
  __syncthreads();
  float s = 0.f;
  for (int v = tid; v < V_; v += 256) s += __expf(lr[v] - m);
  #pragma unroll
  for (int o = 1; o < 64; o <<= 1) s += __shfl_xor(s, o);
  if ((tid & 63) == 0) red[tid >> 6] = s;
  __syncthreads();
  if (tid == 0) {
    s = red[0]+red[1]+red[2]+red[3];
    rl[row] = (logf(s) + m) - lr[tgt[row]];
  }
}

// ---------------- final loss = mean(rl) ----------------
__global__ void k_loss(const float* __restrict__ rl, float* __restrict__ out) {
  __shared__ float red[4];
  int tid = threadIdx.x;
  float s = 0.f;
  for (int i = tid; i < NTOK; i += 256) s += rl[i];
  #pragma unroll
  for (int o = 1; o < 64; o <<= 1) s += __shfl_xor(s, o);
  if ((tid & 63) == 0) red[tid >> 6] = s;
  __syncthreads();
  if (tid == 0) {
    s = red[0]+red[1]+red[2]+red[3];
    out[0] = s / (float)NTOK;
  }
}

extern "C" void kernel_launch(void* const* d_in, const int* in_sizes, int n_in,
                              void* d_out, int out_size, void* d_ws, size_t ws_size,
                              hipStream_t stream) {
  const int*   idx   = (const int*)d_in[0];
  const int*   tgt   = (const int*)d_in[1];
  const float* tok   = (const float*)d_in[2];
  const float* pos   = (const float*)d_in[3];
  const float* ln1_g = (const float*)d_in[4];
  const float* ln1_b = (const float*)d_in[5];
  const float* ln2_g = (const float*)d_in[6];
  const float* ln2_b = (const float*)d_in[7];
  const float* W_qkv = (const float*)d_in[8];
  const float* b_qkv = (const float*)d_in[9];
  const float* W_proj= (const float*)d_in[10];
  const float* b_proj= (const float*)d_in[11];
  const float* W_fc1 = (const float*)d_in[12];
  const float* b_fc1 = (const float*)d_in[13];
  const float* W_fc2 = (const float*)d_in[14];
  const float* b_fc2 = (const float*)d_in[15];
  const float* lnf_g = (const float*)d_in[16];
  const float* lnf_b = (const float*)d_in[17];

  float* out = (float*)d_out;

  char* ob = (char*)d_out;
  float*           x    = (float*)(ob + 0);
  float*           qkv  = (float*)(ob + (size_t)6291456);
  __hip_bfloat16*  y    = (__hip_bfloat16*)(ob + (size_t)25165824);
  __hip_bfloat16*  tff  = (__hip_bfloat16*)(ob + (size_t)28311552);
  __hip_bfloat16*  WTq  = (__hip_bfloat16*)(ob + (size_t)40894464);
  __hip_bfloat16*  WTp  = (__hip_bfloat16*)(ob + (size_t)62128128);
  __hip_bfloat16*  WT1  = (__hip_bfloat16*)(ob + (size_t)69206016);
  __hip_bfloat16*  WT2  = (__hip_bfloat16*)(ob + (size_t)97517568);  // ends 125,829,120

  char* wb = (char*)d_ws;
  __hip_bfloat16* h    = (__hip_bfloat16*)(wb + 0);                  // 3,145,728
  int*    doc  = (int*)  (wb + (size_t)3145728);                     // 8,192
  float*  rl   = (float*)(wb + (size_t)3153920);                     // 8,192
  float2* part = (float2*)(wb + (size_t)3162112);                    // 6,438,912
  __hip_bfloat16* tokh = (__hip_bfloat16*)(wb + (size_t)9601024);    // 77,194,752 (+128K slack)
  const size_t ws_need_part = (size_t)9601024;                       // fused loss
  const size_t ws_need_tokh = (size_t)9601024 + 77194752 + 131072;   // 86,926,848
  const bool fused_loss = (ws_size >= ws_need_part);
  const bool use_tokh   = (ws_size >= ws_need_tokh);

  dim3 tb(32, 8);
  k_wt<<<dim3(2304/32, 768/32, L_), tb, 0, stream>>>(W_qkv,  WTq,  768, 2304);
  k_wt<<<dim3( 768/32, 768/32, L_), tb, 0, stream>>>(W_proj, WTp,  768,  768);
  k_wt<<<dim3(3072/32, 768/32, L_), tb, 0, stream>>>(W_fc1,  WT1,  768, 3072);
  k_wt<<<dim3( 768/32,3072/32, L_), tb, 0, stream>>>(W_fc2,  WT2, 3072,  768);
  if (use_tokh)
    k_cast_tok<<<2048, 256, 0, stream>>>(tok, tokh, (long)V_*768/8);

  k_embed<<<(NTOK*D_ + 255)/256, 256, 0, stream>>>(idx, tok, pos, x);
  k_docid<<<1, 64, 0, stream>>>(idx, doc);

  for (int l = 0; l < L_; ++l) {
    k_ln<<<NTOK, 64, 0, stream>>>(x, ln1_g + l*D_, ln1_b + l*D_, h);
    k_mfma_nt<<<dim3(2304/128, NTOK/128), 256, 0, stream>>>(
        h, WTq + (size_t)l*2304*768, nullptr, b_qkv + (size_t)l*2304, nullptr,
        qkv, nullptr, NTOK, 2304, 768, 0);
    k_fattn<<<dim3(T_/QBLK, H_, B_), 256, 0, stream>>>(qkv, doc, y);
    k_mfma_nt64<<<dim3(768/64, NTOK/64), 256, 0, stream>>>(
        y, WTp + (size_t)l*768*768, b_proj + (size_t)l*768, x, x,
        NTOK, 768, 768);
    k_ln<<<NTOK, 64, 0, stream>>>(x, ln2_g + l*D_, ln2_b + l*D_, h);
    k_mfma_nt<<<dim3(3072/128, NTOK/128), 256, 0, stream>>>(
        h, WT1 + (size_t)l*3072*768, nullptr, b_fc1 + (size_t)l*3072, nullptr,
        nullptr, tff, NTOK, 3072, 768, 1);
    k_mfma_nt64<<<dim3(768/64, NTOK/64), 256, 0, stream>>>(
        tff, WT2 + (size_t)l*768*3072, b_fc2 + (size_t)l*768, x, x,
        NTOK, 768, 3072);
  }
  k_ln<<<NTOK, 64, 0, stream>>>(x, lnf_g, lnf_b, h);

  if (fused_loss) {
    k_logits<<<dim3(NTOK/128, NS2), 256, 0, stream>>>(
        h, use_tokh ? tokh : nullptr, tok, out, part);
    k_rowloss2<<<NTOK, 64, 0, stream>>>(part, out, tgt, rl);
  } else {
    k_mfma_nt<<<dim3((V_ + 127)/128, NTOK/128), 256, 0, stream>>>(
        h, nullptr, tok, nullptr, nullptr, out, nullptr, NTOK, V_, 768, 0);
    k_rowloss<<<NTOK, 256, 0, stream>>>(out, tgt, rl);
  }
  k_loss<<<1, 256, 0, stream>>>(rl, out + (size_t)NTOK*V_);
}

// Round 11
// 1599.078 us; speedup vs baseline: 9.3365x; 1.0245x over previous
//
#include <hip/hip_runtime.h>
#include <hip/hip_bf16.h>
#include <math.h>

#define V_ 50257
#define L_ 6
#define H_ 12
#define D_ 768
#define HD_ 64
#define FF_ 3072
#define B_ 2
#define T_ 1024
#define NTOK (B_*T_)
#define EOS_ 50256
#define QBLK 64
#define KVB 64
#define NS2 393            // number of 128-col logit tiles
#define QS3 (3*D_)         // qkv row stride in elements

typedef __attribute__((ext_vector_type(8))) short s16x8;
typedef __attribute__((ext_vector_type(4))) float f32x4;

__device__ __forceinline__ short f2bf(float f) {
  __hip_bfloat16 h = __float2bfloat16(f);
  return *reinterpret_cast<short*>(&h);
}

// async global->LDS, 16B per lane; l must be the WAVE-uniform base (HW adds lane*16)
__device__ __forceinline__ void gl_lds16(const void* g, void* l) {
  __builtin_amdgcn_global_load_lds(
      (const __attribute__((address_space(1))) unsigned int*)g,
      (__attribute__((address_space(3))) unsigned int*)l, 16, 0, 0);
}

// ---------------- embedding ----------------
__global__ void k_embed(const int* __restrict__ idx, const float* __restrict__ tok,
                        const float* __restrict__ pos, float* __restrict__ x) {
  int gid = blockIdx.x * blockDim.x + threadIdx.x;
  const int total = NTOK * D_;
  if (gid >= total) return;
  int row = gid / D_;
  int d = gid - row * D_;
  int t = row & (T_ - 1);
  x[gid] = tok[(size_t)idx[row] * D_ + d] + pos[t * D_ + d];
}

// ---------------- doc ids ----------------
__global__ void k_docid(const int* __restrict__ idx, int* __restrict__ doc) {
  int b = threadIdx.x;
  if (b >= B_) return;
  int c = 0;
  for (int t = 0; t < T_; ++t) {
    int e = (idx[b*T_ + t] == EOS_) ? 1 : 0;
    doc[b*T_ + t] = c;
    c += e;
  }
}

// ---------------- tok f32 -> bf16 cast --------
__global__ void k_cast_tok(const float* __restrict__ in,
                           __hip_bfloat16* __restrict__ out, long n8) {
  long i = (long)blockIdx.x*blockDim.x + threadIdx.x;
  long stride = (long)gridDim.x*blockDim.x;
  for (; i < n8; i += stride) {
    const float4* src = (const float4*)(in + i*8);
    float4 v0 = src[0], v1 = src[1];
    s16x8 s;
    s[0]=f2bf(v0.x); s[1]=f2bf(v0.y); s[2]=f2bf(v0.z); s[3]=f2bf(v0.w);
    s[4]=f2bf(v1.x); s[5]=f2bf(v1.y); s[6]=f2bf(v1.z); s[7]=f2bf(v1.w);
    *(s16x8*)((short*)out + i*8) = s;
  }
}

// ---------------- layernorm ----------------
__global__ void k_ln(const float* __restrict__ x, const float* __restrict__ g,
                     const float* __restrict__ b, __hip_bfloat16* __restrict__ out) {
  int row = blockIdx.x;
  const float* xr = x + (size_t)row * D_;
  int lane = threadIdx.x;
  float vals[D_/64];
  float s = 0.f;
  #pragma unroll
  for (int i = 0; i < D_/64; ++i) { vals[i] = xr[lane + i*64]; s += vals[i]; }
  #pragma unroll
  for (int o = 1; o < 64; o <<= 1) s += __shfl_xor(s, o);
  float mu = s * (1.f/D_);
  float v = 0.f;
  #pragma unroll
  for (int i = 0; i < D_/64; ++i) { float d0 = vals[i]-mu; v += d0*d0; }
  #pragma unroll
  for (int o = 1; o < 64; o <<= 1) v += __shfl_xor(v, o);
  float inv = rsqrtf(v * (1.f/D_) + 1e-5f);
  #pragma unroll
  for (int i = 0; i < D_/64; ++i) {
    int d = lane + i*64;
    out[(size_t)row*D_ + d] = __float2bfloat16((vals[i]-mu)*inv*g[d] + b[d]);
  }
}

// ------- weight transpose+cast -------
__global__ void k_wt(const float* __restrict__ in, __hip_bfloat16* __restrict__ out,
                     int K, int N) {
  __shared__ float tile[32][33];
  int l = blockIdx.z;
  const float* src = in + (size_t)l*K*N;
  __hip_bfloat16* dst = out + (size_t)l*N*K;
  int n0 = blockIdx.x*32, k0 = blockIdx.y*32;
  int tx = threadIdx.x, ty = threadIdx.y;
  #pragma unroll
  for (int i = 0; i < 4; ++i)
    tile[ty + i*8][tx] = src[(size_t)(k0 + ty + i*8)*N + n0 + tx];
  __syncthreads();
  #pragma unroll
  for (int i = 0; i < 4; ++i)
    dst[(size_t)(n0 + ty + i*8)*K + k0 + tx] = __float2bfloat16(tile[tx][ty + i*8]);
}

// ------- MFMA NT GEMM (128x128x64), gload_lds staging -------
__global__ __launch_bounds__(256) void k_mfma_nt(
    const __hip_bfloat16* __restrict__ A,
    const __hip_bfloat16* __restrict__ Bh,
    const float* __restrict__ Bf,
    const float* __restrict__ bias,
    const float* resid,
    float* outf, __hip_bfloat16* outh,
    int M, int N, int K, int gelu)
{
  __shared__ __align__(16) short lds_a[128*64];
  __shared__ __align__(16) short lds_b[128*64];
  const int t = threadIdx.x;
  const int m0 = blockIdx.y * 128;
  const int n0 = blockIdx.x * 128;
  const int lane = t & 63;
  const int wid = t >> 6;
  const int wm = (wid >> 1) * 64;
  const int wn = (wid & 1) * 64;
  const int lrow = lane & 15;
  const int lkb = (lane >> 4) * 16;
  const int wbase = (t & 192) * 16;

  f32x4 acc[4][4];
  #pragma unroll
  for (int i = 0; i < 4; ++i)
    #pragma unroll
    for (int j = 0; j < 4; ++j)
      acc[i][j] = (f32x4){0.f, 0.f, 0.f, 0.f};

  for (int k0 = 0; k0 < K; k0 += 64) {
    #pragma unroll
    for (int p = 0; p < 4; ++p) {
      int c = p*256 + t;
      int row = c >> 3;
      int colb = (c & 7) << 4;
      const char* src = (const char*)A + ((size_t)(m0+row)*K + k0)*2 + (colb ^ ((row & 7) << 4));
      gl_lds16(src, (char*)lds_a + p*4096 + wbase);
    }
    if (Bh) {
      #pragma unroll
      for (int p = 0; p < 4; ++p) {
        int c = p*256 + t;
        int row = c >> 3;
        int colb = (c & 7) << 4;
        const char* src = (const char*)Bh + ((size_t)(n0+row)*K + k0)*2 + (colb ^ ((row & 7) << 4));
        gl_lds16(src, (char*)lds_b + p*4096 + wbase);
      }
    } else {
      #pragma unroll
      for (int p = 0; p < 4; ++p) {
        int c = p*256 + t;
        int row = c >> 3;
        int colb = (c & 7) << 4;
        int gn = n0 + row;
        s16x8 s = {0,0,0,0,0,0,0,0};
        if (gn < N) {
          const char* src = (const char*)Bf + ((size_t)gn*K + k0)*4 + colb*2;
          float4 v0 = *(const float4*)src;
          float4 v1 = *(const float4*)(src + 16);
          s[0]=f2bf(v0.x); s[1]=f2bf(v0.y); s[2]=f2bf(v0.z); s[3]=f2bf(v0.w);
          s[4]=f2bf(v1.x); s[5]=f2bf(v1.y); s[6]=f2bf(v1.z); s[7]=f2bf(v1.w);
        }
        int dst = (row*128 + colb) ^ ((row & 7) << 4);
        *(s16x8*)((char*)lds_b + dst) = s;
      }
    }
    __syncthreads();
    #pragma unroll
    for (int ks = 0; ks < 2; ++ks) {
      s16x8 af[4], bfr[4];
      #pragma unroll
      for (int f = 0; f < 4; ++f) {
        int row = wm + f*16 + lrow;
        int off = (row*128 + ks*64 + lkb) ^ ((row & 7) << 4);
        af[f] = *(const s16x8*)((const char*)lds_a + off);
      }
      #pragma unroll
      for (int f = 0; f < 4; ++f) {
        int row = wn + f*16 + lrow;
        int off = (row*128 + ks*64 + lkb) ^ ((row & 7) << 4);
        bfr[f] = *(const s16x8*)((const char*)lds_b + off);
      }
      #pragma unroll
      for (int fm = 0; fm < 4; ++fm)
        #pragma unroll
        for (int fn = 0; fn < 4; ++fn)
          acc[fm][fn] = __builtin_amdgcn_mfma_f32_16x16x32_bf16(
              af[fm], bfr[fn], acc[fm][fn], 0, 0, 0);
    }
    __syncthreads();
  }
  const int crow = (lane >> 4) * 4;
  #pragma unroll
  for (int fm = 0; fm < 4; ++fm) {
    #pragma unroll
    for (int fn = 0; fn < 4; ++fn) {
      int col = n0 + wn + fn*16 + lrow;
      if (col >= N) continue;
      #pragma unroll
      for (int r = 0; r < 4; ++r) {
        int row = m0 + wm + fm*16 + crow + r;
        float v = acc[fm][fn][r];
        if (bias) v += bias[col];
        if (gelu) v = 0.5f * v * (1.f + erff(v * 0.70710678118654752f));
        if (resid) v += resid[(size_t)row*N + col];
        if (outf) outf[(size_t)row*N + col] = v;
        else      outh[(size_t)row*N + col] = __float2bfloat16(v);
      }
    }
  }
}

// ------- small-N MFMA NT GEMM (64x64x64): proj, fc2 -------
__global__ __launch_bounds__(256) void k_mfma_nt64(
    const __hip_bfloat16* __restrict__ A,
    const __hip_bfloat16* __restrict__ Bh,
    const float* __restrict__ bias,
    const float* resid,
    float* outf,
    int M, int N, int K)
{
  __shared__ __align__(16) short lds_a[64*64];
  __shared__ __align__(16) short lds_b[64*64];
  const int t = threadIdx.x;
  const int m0 = blockIdx.y * 64;
  const int n0 = blockIdx.x * 64;
  const int lane = t & 63;
  const int wid = t >> 6;
  const int wm = (wid >> 1) * 32;
  const int wn = (wid & 1) * 32;
  const int lrow = lane & 15;
  const int lkb = (lane >> 4) * 16;
  const int wbase = (t & 192) * 16;

  f32x4 acc[2][2];
  #pragma unroll
  for (int i = 0; i < 2; ++i)
    #pragma unroll
    for (int j = 0; j < 2; ++j)
      acc[i][j] = (f32x4){0.f, 0.f, 0.f, 0.f};

  for (int k0 = 0; k0 < K; k0 += 64) {
    #pragma unroll
    for (int p = 0; p < 2; ++p) {
      int c = p*256 + t;
      int row = c >> 3;
      int colb = (c & 7) << 4;
      const char* srcA = (const char*)A + ((size_t)(m0+row)*K + k0)*2 + (colb ^ ((row & 7) << 4));
      gl_lds16(srcA, (char*)lds_a + p*4096 + wbase);
    }
    #pragma unroll
    for (int p = 0; p < 2; ++p) {
      int c = p*256 + t;
      int row = c >> 3;
      int colb = (c & 7) << 4;
      const char* srcB = (const char*)Bh + ((size_t)(n0+row)*K + k0)*2 + (colb ^ ((row & 7) << 4));
      gl_lds16(srcB, (char*)lds_b + p*4096 + wbase);
    }
    __syncthreads();
    #pragma unroll
    for (int ks = 0; ks < 2; ++ks) {
      s16x8 af[2], bfr[2];
      #pragma unroll
      for (int f = 0; f < 2; ++f) {
        int row = wm + f*16 + lrow;
        int off = (row*128 + ks*64 + lkb) ^ ((row & 7) << 4);
        af[f] = *(const s16x8*)((const char*)lds_a + off);
      }
      #pragma unroll
      for (int f = 0; f < 2; ++f) {
        int row = wn + f*16 + lrow;
        int off = (row*128 + ks*64 + lkb) ^ ((row & 7) << 4);
        bfr[f] = *(const s16x8*)((const char*)lds_b + off);
      }
      #pragma unroll
      for (int fm = 0; fm < 2; ++fm)
        #pragma unroll
        for (int fn = 0; fn < 2; ++fn)
          acc[fm][fn] = __builtin_amdgcn_mfma_f32_16x16x32_bf16(
              af[fm], bfr[fn], acc[fm][fn], 0, 0, 0);
    }
    __syncthreads();
  }
  const int crow = (lane >> 4) * 4;
  #pragma unroll
  for (int fm = 0; fm < 2; ++fm) {
    #pragma unroll
    for (int fn = 0; fn < 2; ++fn) {
      int col = n0 + wn + fn*16 + lrow;
      #pragma unroll
      for (int r = 0; r < 4; ++r) {
        int row = m0 + wm + fm*16 + crow + r;
        float v = acc[fm][fn][r] + bias[col];
        if (resid) v += resid[(size_t)row*N + col];
        outf[(size_t)row*N + col] = v;
      }
    }
  }
}

// ------- logits GEMM + fused partials; 1D grid, bijective XCD swizzle -------
// 6288 blocks = 8 XCDs x 786. Each XCD gets a contiguous chunk of logical
// (m-fastest) tiles -> the 16 m-blocks sharing a tok panel run on ONE L2.
__global__ __launch_bounds__(256) void k_logits(
    const __hip_bfloat16* __restrict__ A,   // h [2048][768] bf16
    const __hip_bfloat16* __restrict__ Bh,  // tokh [V][768] bf16 (or null)
    const float* __restrict__ Bf,           // tok [V][768] f32
    float* __restrict__ C,                  // logits [2048][V_] f32
    float2* __restrict__ part)              // [2048][NS2]
{
  __shared__ __align__(16) short lds_a[128*64];
  __shared__ __align__(16) short lds_b[128*64];
  const int t = threadIdx.x;
  const int bid = blockIdx.x;
  const int lid = (bid & 7) * (NS2*16/8) + (bid >> 3);   // bijective XCD swizzle
  const int m0 = (lid & 15) * 128;
  const int nt = lid >> 4;
  const int n0 = nt * 128;
  const int lane = t & 63;
  const int wid = t >> 6;
  const int wm = (wid >> 1) * 64;
  const int wn = (wid & 1) * 64;
  const int lrow = lane & 15;
  const int lkb = (lane >> 4) * 16;
  const int wbase = (t & 192) * 16;

  f32x4 acc[4][4];
  #pragma unroll
  for (int i = 0; i < 4; ++i)
    #pragma unroll
    for (int j = 0; j < 4; ++j)
      acc[i][j] = (f32x4){0.f, 0.f, 0.f, 0.f};

  for (int k0 = 0; k0 < 768; k0 += 64) {
    #pragma unroll
    for (int p = 0; p < 4; ++p) {
      int c = p*256 + t;
      int row = c >> 3;
      int colb = (c & 7) << 4;
      const char* src = (const char*)A + ((size_t)(m0+row)*768 + k0)*2 + (colb ^ ((row & 7) << 4));
      gl_lds16(src, (char*)lds_a + p*4096 + wbase);
    }
    if (Bh) {
      #pragma unroll
      for (int p = 0; p < 4; ++p) {
        int c = p*256 + t;
        int row = c >> 3;
        int colb = (c & 7) << 4;
        const char* src = (const char*)Bh + ((size_t)(n0+row)*768 + k0)*2 + (colb ^ ((row & 7) << 4));
        gl_lds16(src, (char*)lds_b + p*4096 + wbase);
      }
    } else {
      #pragma unroll
      for (int p = 0; p < 4; ++p) {
        int c = p*256 + t;
        int row = c >> 3;
        int colb = (c & 7) << 4;
        int gn = n0 + row;
        s16x8 s = {0,0,0,0,0,0,0,0};
        if (gn < V_) {
          const char* src = (const char*)Bf + ((size_t)gn*768 + k0)*4 + colb*2;
          float4 v0 = *(const float4*)src;
          float4 v1 = *(const float4*)(src + 16);
          s[0]=f2bf(v0.x); s[1]=f2bf(v0.y); s[2]=f2bf(v0.z); s[3]=f2bf(v0.w);
          s[4]=f2bf(v1.x); s[5]=f2bf(v1.y); s[6]=f2bf(v1.z); s[7]=f2bf(v1.w);
        }
        int dst = (row*128 + colb) ^ ((row & 7) << 4);
        *(s16x8*)((char*)lds_b + dst) = s;
      }
    }
    __syncthreads();
    #pragma unroll
    for (int ks = 0; ks < 2; ++ks) {
      s16x8 af[4], bfr[4];
      #pragma unroll
      for (int f = 0; f < 4; ++f) {
        int row = wm + f*16 + lrow;
        int off = (row*128 + ks*64 + lkb) ^ ((row & 7) << 4);
        af[f] = *(const s16x8*)((const char*)lds_a + off);
      }
      #pragma unroll
      for (int f = 0; f < 4; ++f) {
        int row = wn + f*16 + lrow;
        int off = (row*128 + ks*64 + lkb) ^ ((row & 7) << 4);
        bfr[f] = *(const s16x8*)((const char*)lds_b + off);
      }
      #pragma unroll
      for (int fm = 0; fm < 4; ++fm)
        #pragma unroll
        for (int fn = 0; fn < 4; ++fn)
          acc[fm][fn] = __builtin_amdgcn_mfma_f32_16x16x32_bf16(
              af[fm], bfr[fn], acc[fm][fn], 0, 0, 0);
    }
    __syncthreads();
  }
  // ---- epilogue: nt-store C + per-row (max,sumexp) partials ----
  const int crow = (lane >> 4) * 4;
  bool valid[4];
  #pragma unroll
  for (int fn = 0; fn < 4; ++fn) valid[fn] = (n0 + wn + fn*16 + lrow) < V_;
  float2* red = (float2*)lds_a;
  #pragma unroll
  for (int fm = 0; fm < 4; ++fm) {
    #pragma unroll
    for (int r = 0; r < 4; ++r) {
      int rit = wm + fm*16 + crow + r;
      int row = m0 + rit;
      float m = -1e30f;
      #pragma unroll
      for (int fn = 0; fn < 4; ++fn) {
        if (valid[fn]) {
          float v = acc[fm][fn][r];
          __builtin_nontemporal_store(v, &C[(size_t)row*V_ + n0 + wn + fn*16 + lrow]);
          m = fmaxf(m, v);
        }
      }
      #pragma unroll
      for (int o = 1; o < 16; o <<= 1) m = fmaxf(m, __shfl_xor(m, o));
      float s = 0.f;
      #pragma unroll
      for (int fn = 0; fn < 4; ++fn)
        if (valid[fn]) s += __expf(acc[fm][fn][r] - m);
      #pragma unroll
      for (int o = 1; o < 16; o <<= 1) s += __shfl_xor(s, o);
      if (lrow == 0) red[rit*2 + (wid & 1)] = make_float2(m, s);
    }
  }
  __syncthreads();
  if (t < 128) {
    float2 a = red[t*2], b = red[t*2 + 1];
    float mn = fmaxf(a.x, b.x);
    float S = a.y*__expf(a.x - mn) + b.y*__expf(b.x - mn);
    part[(size_t)(m0 + t)*NS2 + nt] = make_float2(mn, S);
  }
}

// ------- combine per-tile partials -> per-row loss -------
__global__ void k_rowloss2(const float2* __restrict__ part,
                           const float* __restrict__ logits,
                           const int* __restrict__ tgt, float* __restrict__ rl) {
  int row = blockIdx.x;
  int lane = threadIdx.x;
  float M = -1e30f, S = 0.f;
  for (int i = lane; i < NS2; i += 64) {
    float2 p = part[(size_t)row*NS2 + i];
    float mn = fmaxf(M, p.x);
    S = S*__expf(M - mn) + p.y*__expf(p.x - mn);
    M = mn;
  }
  #pragma unroll
  for (int o = 1; o < 64; o <<= 1) {
    float Mo = __shfl_xor(M, o);
    float So = __shfl_xor(S, o);
    float mn = fmaxf(M, Mo);
    S = S*__expf(M - mn) + So*__expf(Mo - mn);
    M = mn;
  }
  if (lane == 0)
    rl[row] = (logf(S) + M) - logits[(size_t)row*V_ + tgt[row]];
}

// ------- flash attention (bf16 qkv, gl_lds staging for Q/K) -------
__global__ __launch_bounds__(256) void k_fattn(
    const __hip_bfloat16* __restrict__ qkv, const int* __restrict__ doc,
    __hip_bfloat16* __restrict__ y)
{
  __shared__ __align__(16) short q_lds[QBLK*64];
  __shared__ __align__(16) short k_lds[KVB*64];
  __shared__ __align__(16) short vt_lds[64*KVB];
  __shared__ __align__(16) short p_lds[4][16*64];
  __shared__ int doc_k[KVB];
  const int t = threadIdx.x;
  const int lane = t & 63;
  const int w = t >> 6;
  const int q0 = blockIdx.x * QBLK;
  const int h = blockIdx.y, b = blockIdx.z;
  const int lrow = lane & 15;
  const int lgrp = lane >> 4;
  const int crow = lgrp * 4;
  const int wbase = (t & 192) * 16;
  const short* qp = (const short*)qkv;

  // ---- stage Q (64 rows x 128B) via gl_lds16, pre-swizzled source ----
  #pragma unroll
  for (int p = 0; p < 2; ++p) {
    int c = p*256 + t;
    int row = c >> 3;
    int colb = (c & 7) << 4;
    const char* src = (const char*)(qp + ((size_t)(b*T_ + q0 + row))*QS3 + h*HD_)
                      + (colb ^ ((row & 7) << 4));
    gl_lds16(src, (char*)q_lds + p*4096 + wbase);
  }
  int docq[4];
  #pragma unroll
  for (int r = 0; r < 4; ++r)
    docq[r] = doc[b*T_ + q0 + w*16 + crow + r];
  __syncthreads();

  float m_r[4], l_r[4];
  #pragma unroll
  for (int r = 0; r < 4; ++r) { m_r[r] = -1e30f; l_r[r] = 0.f; }
  f32x4 o[4];
  #pragma unroll
  for (int fd = 0; fd < 4; ++fd) o[fd] = (f32x4){0.f,0.f,0.f,0.f};

  const int ntiles = q0/KVB + 1;
  for (int kt = 0; kt < ntiles; ++kt) {
    const int kv0 = kt * KVB;
    // ---- K tile via gl_lds16 ----
    #pragma unroll
    for (int p = 0; p < 2; ++p) {
      int c = p*256 + t;
      int row = c >> 3;
      int colb = (c & 7) << 4;
      const char* src = (const char*)(qp + ((size_t)(b*T_ + kv0 + row))*QS3 + D_ + h*HD_)
                        + (colb ^ ((row & 7) << 4));
      gl_lds16(src, (char*)k_lds + p*4096 + wbase);
    }
    // ---- V^T tile: vector read, scalar transpose-scatter ----
    #pragma unroll
    for (int p = 0; p < 2; ++p) {
      int c = p*256 + t;
      int kvr = c >> 3, d0 = (c & 7)*8;
      s16x8 s = *(const s16x8*)(qp + ((size_t)(b*T_ + kv0 + kvr))*QS3 + 2*D_ + h*HD_ + d0);
      #pragma unroll
      for (int j = 0; j < 8; ++j) {
        int d = d0 + j;
        int off = (d*128 + kvr*2) ^ ((d & 7) << 4);
        *(short*)((char*)vt_lds + off) = s[j];
      }
    }
    if (t < KVB) doc_k[t] = doc[b*T_ + kv0 + t];
    __syncthreads();

    f32x4 sfr[4];
    #pragma unroll
    for (int fn = 0; fn < 4; ++fn) sfr[fn] = (f32x4){0.f,0.f,0.f,0.f};
    #pragma unroll
    for (int ks = 0; ks < 2; ++ks) {
      int arow = w*16 + lrow;
      s16x8 af = *(const s16x8*)((const char*)q_lds +
                 ((arow*128 + lgrp*16 + ks*64) ^ ((arow & 7) << 4)));
      #pragma unroll
      for (int fn = 0; fn < 4; ++fn) {
        int brow = fn*16 + lrow;
        s16x8 bf = *(const s16x8*)((const char*)k_lds +
                   ((brow*128 + lgrp*16 + ks*64) ^ ((brow & 7) << 4)));
        sfr[fn] = __builtin_amdgcn_mfma_f32_16x16x32_bf16(af, bf, sfr[fn], 0, 0, 0);
      }
    }
    int dk[4];
    #pragma unroll
    for (int fn = 0; fn < 4; ++fn) dk[fn] = doc_k[fn*16 + lrow];
    float rowmax[4] = {-1e30f, -1e30f, -1e30f, -1e30f};
    #pragma unroll
    for (int fn = 0; fn < 4; ++fn) {
      int col = kv0 + fn*16 + lrow;
      #pragma unroll
      for (int r = 0; r < 4; ++r) {
        int qrow = q0 + w*16 + crow + r;
        bool ok = (col <= qrow) && (dk[fn] == docq[r]);
        float v = ok ? sfr[fn][r] * 0.125f : -1e30f;
        sfr[fn][r] = v;
        rowmax[r] = fmaxf(rowmax[r], v);
      }
    }
    #pragma unroll
    for (int r = 0; r < 4; ++r) {
      float v = rowmax[r];
      #pragma unroll
      for (int off = 1; off < 16; off <<= 1) v = fmaxf(v, __shfl_xor(v, off));
      rowmax[r] = v;
    }
    float alpha[4], psum[4];
    #pragma unroll
    for (int r = 0; r < 4; ++r) {
      float mn = fmaxf(m_r[r], rowmax[r]);
      alpha[r] = __expf(m_r[r] - mn);
      m_r[r] = mn;
      psum[r] = 0.f;
    }
    #pragma unroll
    for (int fn = 0; fn < 4; ++fn) {
      #pragma unroll
      for (int r = 0; r < 4; ++r) {
        float sv = sfr[fn][r];
        float p = (sv < -5e29f) ? 0.f : __expf(sv - m_r[r]);
        psum[r] += p;
        int rl_ = crow + r;
        int off = (rl_*128 + (fn*16 + lrow)*2) ^ ((rl_ & 7) << 4);
        *(short*)((char*)p_lds[w] + off) = f2bf(p);
      }
    }
    #pragma unroll
    for (int r = 0; r < 4; ++r) {
      float v = psum[r];
      #pragma unroll
      for (int off = 1; off < 16; off <<= 1) v += __shfl_xor(v, off);
      l_r[r] = l_r[r]*alpha[r] + v;
    }
    #pragma unroll
    for (int fd = 0; fd < 4; ++fd)
      #pragma unroll
      for (int r = 0; r < 4; ++r)
        o[fd][r] *= alpha[r];
    __syncthreads();
    #pragma unroll
    for (int ks = 0; ks < 2; ++ks) {
      s16x8 af = *(const s16x8*)((const char*)p_lds[w] +
                 ((lrow*128 + lgrp*16 + ks*64) ^ ((lrow & 7) << 4)));
      #pragma unroll
      for (int fd = 0; fd < 4; ++fd) {
        int brow = fd*16 + lrow;
        s16x8 bf = *(const s16x8*)((const char*)vt_lds +
                   ((brow*128 + lgrp*16 + ks*64) ^ ((brow & 7) << 4)));
        o[fd] = __builtin_amdgcn_mfma_f32_16x16x32_bf16(af, bf, o[fd], 0, 0, 0);
      }
    }
    __syncthreads();
  }
  #pragma unroll
  for (int r = 0; r < 4; ++r) {
    float inv = 1.f / l_r[r];
    int rowg = b*T_ + q0 + w*16 + crow + r;
    #pragma unroll
    for (int fd = 0; fd < 4; ++fd) {
      int col = h*HD_ + fd*16 + lrow;
      y[(size_t)rowg*D_ + col] = __float2bfloat16(o[fd][r] * inv);
    }
  }
}

// ---------------- fallback per-row log-softmax ----------------
__global__ void k_rowloss(const float* __restrict__ logits,
                          const int* __restrict__ tgt, float* __restrict__ rl) {
  __shared__ float red[4];
  int row = blockIdx.x;
  const float* lr = logits + (size_t)row * V_;
  int tid = threadIdx.x;
  float m = -1e30f;
  for (int v = tid; v < V_; v += 256) m = fmaxf(m, lr[v]);
  #pragma unroll
  for (int o = 1; o < 64; o <<= 1) m = fmaxf(m, __shfl_xor(m, o));
  if ((tid & 63) == 0) red[tid >> 6] = m;
  __syncthreads();
  m = fmaxf(fmaxf(red[0], red[1]), fmaxf(red[2], red[3]));
  __syncthreads();
  float s = 0.f;
  for (int v = tid; v < V_; v += 256) s += __expf(lr[v] - m);
  #pragma unroll
  for (int o = 1; o < 64; o <<= 1) s += __shfl_xor(s, o);
  if ((tid & 63) == 0) red[tid >> 6] = s;
  __syncthreads();
  if (tid == 0) {
    s = red[0]+red[1]+red[2]+red[3];
    rl[row] = (logf(s) + m) - lr[tgt[row]];
  }
}

// ---------------- final loss = mean(rl) ----------------
__global__ void k_loss(const float* __restrict__ rl, float* __restrict__ out) {
  __shared__ float red[4];
  int tid = threadIdx.x;
  float s = 0.f;
  for (int i = tid; i < NTOK; i += 256) s += rl[i];
  #pragma unroll
  for (int o = 1; o < 64; o <<= 1) s += __shfl_xor(s, o);
  if ((tid & 63) == 0) red[tid >> 6] = s;
  __syncthreads();
  if (tid == 0) {
    s = red[0]+red[1]+red[2]+red[3];
    out[0] = s / (float)NTOK;
  }
}

extern "C" void kernel_launch(void* const* d_in, const int* in_sizes, int n_in,
                              void* d_out, int out_size, void* d_ws, size_t ws_size,
                              hipStream_t stream) {
  const int*   idx   = (const int*)d_in[0];
  const int*   tgt   = (const int*)d_in[1];
  const float* tok   = (const float*)d_in[2];
  const float* pos   = (const float*)d_in[3];
  const float* ln1_g = (const float*)d_in[4];
  const float* ln1_b = (const float*)d_in[5];
  const float* ln2_g = (const float*)d_in[6];
  const float* ln2_b = (const float*)d_in[7];
  const float* W_qkv = (const float*)d_in[8];
  const float* b_qkv = (const float*)d_in[9];
  const float* W_proj= (const float*)d_in[10];
  const float* b_proj= (const float*)d_in[11];
  const float* W_fc1 = (const float*)d_in[12];
  const float* b_fc1 = (const float*)d_in[13];
  const float* W_fc2 = (const float*)d_in[14];
  const float* b_fc2 = (const float*)d_in[15];
  const float* lnf_g = (const float*)d_in[16];
  const float* lnf_b = (const float*)d_in[17];

  float* out = (float*)d_out;

  char* ob = (char*)d_out;
  float*           x    = (float*)(ob + 0);                            //  6,291,456
  __hip_bfloat16*  qkv  = (__hip_bfloat16*)(ob + (size_t)6291456);     //  9,437,184
  __hip_bfloat16*  y    = (__hip_bfloat16*)(ob + (size_t)15728640);    //  3,145,728
  __hip_bfloat16*  tff  = (__hip_bfloat16*)(ob + (size_t)18874368);    // 12,582,912 -> 31,457,280
  __hip_bfloat16*  WTq  = (__hip_bfloat16*)(ob + (size_t)40894464);
  __hip_bfloat16*  WTp  = (__hip_bfloat16*)(ob + (size_t)62128128);
  __hip_bfloat16*  WT1  = (__hip_bfloat16*)(ob + (size_t)69206016);
  __hip_bfloat16*  WT2  = (__hip_bfloat16*)(ob + (size_t)97517568);    // ends 125,829,120

  char* wb = (char*)d_ws;
  __hip_bfloat16* h    = (__hip_bfloat16*)(wb + 0);                  // 3,145,728
  int*    doc  = (int*)  (wb + (size_t)3145728);                     // 8,192
  float*  rl   = (float*)(wb + (size_t)3153920);                     // 8,192
  float2* part = (float2*)(wb + (size_t)3162112);                    // 6,438,912
  __hip_bfloat16* tokh = (__hip_bfloat16*)(wb + (size_t)9601024);    // 77,194,752 (+128K slack)
  const size_t ws_need_part = (size_t)9601024;
  const size_t ws_need_tokh = (size_t)9601024 + 77194752 + 131072;   // 86,926,848
  const bool fused_loss = (ws_size >= ws_need_part);
  const bool use_tokh   = (ws_size >= ws_need_tokh);

  dim3 tb(32, 8);
  k_wt<<<dim3(2304/32, 768/32, L_), tb, 0, stream>>>(W_qkv,  WTq,  768, 2304);
  k_wt<<<dim3( 768/32, 768/32, L_), tb, 0, stream>>>(W_proj, WTp,  768,  768);
  k_wt<<<dim3(3072/32, 768/32, L_), tb, 0, stream>>>(W_fc1,  WT1,  768, 3072);
  k_wt<<<dim3( 768/32,3072/32, L_), tb, 0, stream>>>(W_fc2,  WT2, 3072,  768);
  if (use_tokh)
    k_cast_tok<<<2048, 256, 0, stream>>>(tok, tokh, (long)V_*768/8);

  k_embed<<<(NTOK*D_ + 255)/256, 256, 0, stream>>>(idx, tok, pos, x);
  k_docid<<<1, 64, 0, stream>>>(idx, doc);

  for (int l = 0; l < L_; ++l) {
    k_ln<<<NTOK, 64, 0, stream>>>(x, ln1_g + l*D_, ln1_b + l*D_, h);
    k_mfma_nt<<<dim3(2304/128, NTOK/128), 256, 0, stream>>>(
        h, WTq + (size_t)l*2304*768, nullptr, b_qkv + (size_t)l*2304, nullptr,
        nullptr, qkv, NTOK, 2304, 768, 0);
    k_fattn<<<dim3(T_/QBLK, H_, B_), 256, 0, stream>>>(qkv, doc, y);
    k_mfma_nt64<<<dim3(768/64, NTOK/64), 256, 0, stream>>>(
        y, WTp + (size_t)l*768*768, b_proj + (size_t)l*768, x, x,
        NTOK, 768, 768);
    k_ln<<<NTOK, 64, 0, stream>>>(x, ln2_g + l*D_, ln2_b + l*D_, h);
    k_mfma_nt<<<dim3(3072/128, NTOK/128), 256, 0, stream>>>(
        h, WT1 + (size_t)l*3072*768, nullptr, b_fc1 + (size_t)l*3072, nullptr,
        nullptr, tff, NTOK, 3072, 768, 1);
    k_mfma_nt64<<<dim3(768/64, NTOK/64), 256, 0, stream>>>(
        tff, WT2 + (size_t)l*768*3072, b_fc2 + (size_t)l*768, x, x,
        NTOK, 768, 3072);
  }
  k_ln<<<NTOK, 64, 0, stream>>>(x, lnf_g, lnf_b, h);

  if (fused_loss) {
    k_logits<<<NS2*16, 256, 0, stream>>>(
        h, use_tokh ? tokh : nullptr, tok, out, part);
    k_rowloss2<<<NTOK, 64, 0, stream>>>(part, out, tgt, rl);
  } else {
    k_mfma_nt<<<dim3((V_ + 127)/128, NTOK/128), 256, 0, stream>>>(
        h, nullptr, tok, nullptr, nullptr, out, nullptr, NTOK, V_, 768, 0);
    k_rowloss<<<NTOK, 256, 0, stream>>>(out, tgt, rl);
  }
  k_loss<<<1, 256, 0, stream>>>(rl, out + (size_t)NTOK*V_);
}

// Round 12
// 1498.522 us; speedup vs baseline: 9.9630x; 1.0671x over previous
//
#include <hip/hip_runtime.h>
#include <hip/hip_bf16.h>
#include <math.h>

#define V_ 50257
#define L_ 6
#define H_ 12
#define D_ 768
#define HD_ 64
#define FF_ 3072
#define B_ 2
#define T_ 1024
#define NTOK (B_*T_)
#define EOS_ 50256
#define QBLK 64
#define KVB 64
#define NS2 393            // number of 128-col logit tiles
#define QS3 (3*D_)         // qkv row stride in elements

typedef __attribute__((ext_vector_type(8))) short s16x8;
typedef __attribute__((ext_vector_type(4))) float f32x4;

__device__ __forceinline__ short f2bf(float f) {
  __hip_bfloat16 h = __float2bfloat16(f);
  return *reinterpret_cast<short*>(&h);
}

// async global->LDS, 16B per lane; l must be the WAVE-uniform base (HW adds lane*16)
__device__ __forceinline__ void gl_lds16(const void* g, void* l) {
  __builtin_amdgcn_global_load_lds(
      (const __attribute__((address_space(1))) unsigned int*)g,
      (__attribute__((address_space(3))) unsigned int*)l, 16, 0, 0);
}

// ---------------- embedding ----------------
__global__ void k_embed(const int* __restrict__ idx, const float* __restrict__ tok,
                        const float* __restrict__ pos, float* __restrict__ x) {
  int gid = blockIdx.x * blockDim.x + threadIdx.x;
  const int total = NTOK * D_;
  if (gid >= total) return;
  int row = gid / D_;
  int d = gid - row * D_;
  int t = row & (T_ - 1);
  x[gid] = tok[(size_t)idx[row] * D_ + d] + pos[t * D_ + d];
}

// ---------------- doc ids ----------------
__global__ void k_docid(const int* __restrict__ idx, int* __restrict__ doc) {
  int b = threadIdx.x;
  if (b >= B_) return;
  int c = 0;
  for (int t = 0; t < T_; ++t) {
    int e = (idx[b*T_ + t] == EOS_) ? 1 : 0;
    doc[b*T_ + t] = c;
    c += e;
  }
}

// ---------------- tok f32 -> bf16 cast --------
__global__ void k_cast_tok(const float* __restrict__ in,
                           __hip_bfloat16* __restrict__ out, long n8) {
  long i = (long)blockIdx.x*blockDim.x + threadIdx.x;
  long stride = (long)gridDim.x*blockDim.x;
  for (; i < n8; i += stride) {
    const float4* src = (const float4*)(in + i*8);
    float4 v0 = src[0], v1 = src[1];
    s16x8 s;
    s[0]=f2bf(v0.x); s[1]=f2bf(v0.y); s[2]=f2bf(v0.z); s[3]=f2bf(v0.w);
    s[4]=f2bf(v1.x); s[5]=f2bf(v1.y); s[6]=f2bf(v1.z); s[7]=f2bf(v1.w);
    *(s16x8*)((short*)out + i*8) = s;
  }
}

// ---------------- layernorm ----------------
__global__ void k_ln(const float* __restrict__ x, const float* __restrict__ g,
                     const float* __restrict__ b, __hip_bfloat16* __restrict__ out) {
  int row = blockIdx.x;
  const float* xr = x + (size_t)row * D_;
  int lane = threadIdx.x;
  float vals[D_/64];
  float s = 0.f;
  #pragma unroll
  for (int i = 0; i < D_/64; ++i) { vals[i] = xr[lane + i*64]; s += vals[i]; }
  #pragma unroll
  for (int o = 1; o < 64; o <<= 1) s += __shfl_xor(s, o);
  float mu = s * (1.f/D_);
  float v = 0.f;
  #pragma unroll
  for (int i = 0; i < D_/64; ++i) { float d0 = vals[i]-mu; v += d0*d0; }
  #pragma unroll
  for (int o = 1; o < 64; o <<= 1) v += __shfl_xor(v, o);
  float inv = rsqrtf(v * (1.f/D_) + 1e-5f);
  #pragma unroll
  for (int i = 0; i < D_/64; ++i) {
    int d = lane + i*64;
    out[(size_t)row*D_ + d] = __float2bfloat16((vals[i]-mu)*inv*g[d] + b[d]);
  }
}

// ------- weight transpose+cast -------
__global__ void k_wt(const float* __restrict__ in, __hip_bfloat16* __restrict__ out,
                     int K, int N) {
  __shared__ float tile[32][33];
  int l = blockIdx.z;
  const float* src = in + (size_t)l*K*N;
  __hip_bfloat16* dst = out + (size_t)l*N*K;
  int n0 = blockIdx.x*32, k0 = blockIdx.y*32;
  int tx = threadIdx.x, ty = threadIdx.y;
  #pragma unroll
  for (int i = 0; i < 4; ++i)
    tile[ty + i*8][tx] = src[(size_t)(k0 + ty + i*8)*N + n0 + tx];
  __syncthreads();
  #pragma unroll
  for (int i = 0; i < 4; ++i)
    dst[(size_t)(n0 + ty + i*8)*K + k0 + tx] = __float2bfloat16(tile[tx][ty + i*8]);
}

// ------- MFMA NT GEMM (128x128x64), 512 threads = 8 waves (2x4), 64x32/wave -------
__global__ __launch_bounds__(512) void k_mfma_nt(
    const __hip_bfloat16* __restrict__ A,
    const __hip_bfloat16* __restrict__ Bh,
    const float* __restrict__ Bf,
    const float* __restrict__ bias,
    const float* resid,
    float* outf, __hip_bfloat16* outh,
    int M, int N, int K, int gelu)
{
  __shared__ __align__(16) short lds_a[128*64];
  __shared__ __align__(16) short lds_b[128*64];
  const int t = threadIdx.x;          // 0..511
  const int m0 = blockIdx.y * 128;
  const int n0 = blockIdx.x * 128;
  const int lane = t & 63;
  const int wid = t >> 6;             // 0..7
  const int wm = (wid >> 2) * 64;     // wave-row: 0/64
  const int wn = (wid & 3) * 32;      // wave-col: 0/32/64/96
  const int lrow = lane & 15;
  const int lkb = (lane >> 4) * 16;
  const int wbase = (t & 448) * 16;   // wave-uniform chunk base (bytes)

  f32x4 acc[4][2];
  #pragma unroll
  for (int i = 0; i < 4; ++i)
    #pragma unroll
    for (int j = 0; j < 2; ++j)
      acc[i][j] = (f32x4){0.f, 0.f, 0.f, 0.f};

  for (int k0 = 0; k0 < K; k0 += 64) {
    #pragma unroll
    for (int p = 0; p < 2; ++p) {
      int c = p*512 + t;
      int row = c >> 3;
      int colb = (c & 7) << 4;
      const char* src = (const char*)A + ((size_t)(m0+row)*K + k0)*2 + (colb ^ ((row & 7) << 4));
      gl_lds16(src, (char*)lds_a + p*8192 + wbase);
    }
    if (Bh) {
      #pragma unroll
      for (int p = 0; p < 2; ++p) {
        int c = p*512 + t;
        int row = c >> 3;
        int colb = (c & 7) << 4;
        const char* src = (const char*)Bh + ((size_t)(n0+row)*K + k0)*2 + (colb ^ ((row & 7) << 4));
        gl_lds16(src, (char*)lds_b + p*8192 + wbase);
      }
    } else {
      #pragma unroll
      for (int p = 0; p < 2; ++p) {
        int c = p*512 + t;
        int row = c >> 3;
        int colb = (c & 7) << 4;
        int gn = n0 + row;
        s16x8 s = {0,0,0,0,0,0,0,0};
        if (gn < N) {
          const char* src = (const char*)Bf + ((size_t)gn*K + k0)*4 + colb*2;
          float4 v0 = *(const float4*)src;
          float4 v1 = *(const float4*)(src + 16);
          s[0]=f2bf(v0.x); s[1]=f2bf(v0.y); s[2]=f2bf(v0.z); s[3]=f2bf(v0.w);
          s[4]=f2bf(v1.x); s[5]=f2bf(v1.y); s[6]=f2bf(v1.z); s[7]=f2bf(v1.w);
        }
        int dst = (row*128 + colb) ^ ((row & 7) << 4);
        *(s16x8*)((char*)lds_b + dst) = s;
      }
    }
    __syncthreads();
    #pragma unroll
    for (int ks = 0; ks < 2; ++ks) {
      s16x8 af[4], bfr[2];
      #pragma unroll
      for (int f = 0; f < 4; ++f) {
        int row = wm + f*16 + lrow;
        int off = (row*128 + ks*64 + lkb) ^ ((row & 7) << 4);
        af[f] = *(const s16x8*)((const char*)lds_a + off);
      }
      #pragma unroll
      for (int f = 0; f < 2; ++f) {
        int row = wn + f*16 + lrow;
        int off = (row*128 + ks*64 + lkb) ^ ((row & 7) << 4);
        bfr[f] = *(const s16x8*)((const char*)lds_b + off);
      }
      #pragma unroll
      for (int fm = 0; fm < 4; ++fm)
        #pragma unroll
        for (int fn = 0; fn < 2; ++fn)
          acc[fm][fn] = __builtin_amdgcn_mfma_f32_16x16x32_bf16(
              af[fm], bfr[fn], acc[fm][fn], 0, 0, 0);
    }
    __syncthreads();
  }
  const int crow = (lane >> 4) * 4;
  #pragma unroll
  for (int fm = 0; fm < 4; ++fm) {
    #pragma unroll
    for (int fn = 0; fn < 2; ++fn) {
      int col = n0 + wn + fn*16 + lrow;
      if (col >= N) continue;
      #pragma unroll
      for (int r = 0; r < 4; ++r) {
        int row = m0 + wm + fm*16 + crow + r;
        float v = acc[fm][fn][r];
        if (bias) v += bias[col];
        if (gelu) v = 0.5f * v * (1.f + erff(v * 0.70710678118654752f));
        if (resid) v += resid[(size_t)row*N + col];
        if (outf) outf[(size_t)row*N + col] = v;
        else      outh[(size_t)row*N + col] = __float2bfloat16(v);
      }
    }
  }
}

// ------- small-N MFMA NT GEMM (64x64x64): proj, fc2 -------
__global__ __launch_bounds__(256) void k_mfma_nt64(
    const __hip_bfloat16* __restrict__ A,
    const __hip_bfloat16* __restrict__ Bh,
    const float* __restrict__ bias,
    const float* resid,
    float* outf,
    int M, int N, int K)
{
  __shared__ __align__(16) short lds_a[64*64];
  __shared__ __align__(16) short lds_b[64*64];
  const int t = threadIdx.x;
  const int m0 = blockIdx.y * 64;
  const int n0 = blockIdx.x * 64;
  const int lane = t & 63;
  const int wid = t >> 6;
  const int wm = (wid >> 1) * 32;
  const int wn = (wid & 1) * 32;
  const int lrow = lane & 15;
  const int lkb = (lane >> 4) * 16;
  const int wbase = (t & 192) * 16;

  f32x4 acc[2][2];
  #pragma unroll
  for (int i = 0; i < 2; ++i)
    #pragma unroll
    for (int j = 0; j < 2; ++j)
      acc[i][j] = (f32x4){0.f, 0.f, 0.f, 0.f};

  for (int k0 = 0; k0 < K; k0 += 64) {
    #pragma unroll
    for (int p = 0; p < 2; ++p) {
      int c = p*256 + t;
      int row = c >> 3;
      int colb = (c & 7) << 4;
      const char* srcA = (const char*)A + ((size_t)(m0+row)*K + k0)*2 + (colb ^ ((row & 7) << 4));
      gl_lds16(srcA, (char*)lds_a + p*4096 + wbase);
    }
    #pragma unroll
    for (int p = 0; p < 2; ++p) {
      int c = p*256 + t;
      int row = c >> 3;
      int colb = (c & 7) << 4;
      const char* srcB = (const char*)Bh + ((size_t)(n0+row)*K + k0)*2 + (colb ^ ((row & 7) << 4));
      gl_lds16(srcB, (char*)lds_b + p*4096 + wbase);
    }
    __syncthreads();
    #pragma unroll
    for (int ks = 0; ks < 2; ++ks) {
      s16x8 af[2], bfr[2];
      #pragma unroll
      for (int f = 0; f < 2; ++f) {
        int row = wm + f*16 + lrow;
        int off = (row*128 + ks*64 + lkb) ^ ((row & 7) << 4);
        af[f] = *(const s16x8*)((const char*)lds_a + off);
      }
      #pragma unroll
      for (int f = 0; f < 2; ++f) {
        int row = wn + f*16 + lrow;
        int off = (row*128 + ks*64 + lkb) ^ ((row & 7) << 4);
        bfr[f] = *(const s16x8*)((const char*)lds_b + off);
      }
      #pragma unroll
      for (int fm = 0; fm < 2; ++fm)
        #pragma unroll
        for (int fn = 0; fn < 2; ++fn)
          acc[fm][fn] = __builtin_amdgcn_mfma_f32_16x16x32_bf16(
              af[fm], bfr[fn], acc[fm][fn], 0, 0, 0);
    }
    __syncthreads();
  }
  const int crow = (lane >> 4) * 4;
  #pragma unroll
  for (int fm = 0; fm < 2; ++fm) {
    #pragma unroll
    for (int fn = 0; fn < 2; ++fn) {
      int col = n0 + wn + fn*16 + lrow;
      #pragma unroll
      for (int r = 0; r < 4; ++r) {
        int row = m0 + wm + fm*16 + crow + r;
        float v = acc[fm][fn][r] + bias[col];
        if (resid) v += resid[(size_t)row*N + col];
        outf[(size_t)row*N + col] = v;
      }
    }
  }
}

// ------- logits GEMM + fused partials; 512 threads, 1D grid, XCD swizzle -------
__global__ __launch_bounds__(512) void k_logits(
    const __hip_bfloat16* __restrict__ A,   // h [2048][768] bf16
    const __hip_bfloat16* __restrict__ Bh,  // tokh [V][768] bf16 (or null)
    const float* __restrict__ Bf,           // tok [V][768] f32
    float* __restrict__ C,                  // logits [2048][V_] f32
    float2* __restrict__ part)              // [2048][NS2]
{
  __shared__ __align__(16) short lds_a[128*64];
  __shared__ __align__(16) short lds_b[128*64];
  const int t = threadIdx.x;
  const int bid = blockIdx.x;
  const int lid = (bid & 7) * (NS2*16/8) + (bid >> 3);   // bijective XCD swizzle
  const int m0 = (lid & 15) * 128;
  const int nt = lid >> 4;
  const int n0 = nt * 128;
  const int lane = t & 63;
  const int wid = t >> 6;
  const int wm = (wid >> 2) * 64;
  const int wn = (wid & 3) * 32;
  const int lrow = lane & 15;
  const int lkb = (lane >> 4) * 16;
  const int wbase = (t & 448) * 16;

  f32x4 acc[4][2];
  #pragma unroll
  for (int i = 0; i < 4; ++i)
    #pragma unroll
    for (int j = 0; j < 2; ++j)
      acc[i][j] = (f32x4){0.f, 0.f, 0.f, 0.f};

  for (int k0 = 0; k0 < 768; k0 += 64) {
    #pragma unroll
    for (int p = 0; p < 2; ++p) {
      int c = p*512 + t;
      int row = c >> 3;
      int colb = (c & 7) << 4;
      const char* src = (const char*)A + ((size_t)(m0+row)*768 + k0)*2 + (colb ^ ((row & 7) << 4));
      gl_lds16(src, (char*)lds_a + p*8192 + wbase);
    }
    if (Bh) {
      // OOB rows of the ragged last tile read into the 128KB slack after tokh
      #pragma unroll
      for (int p = 0; p < 2; ++p) {
        int c = p*512 + t;
        int row = c >> 3;
        int colb = (c & 7) << 4;
        const char* src = (const char*)Bh + ((size_t)(n0+row)*768 + k0)*2 + (colb ^ ((row & 7) << 4));
        gl_lds16(src, (char*)lds_b + p*8192 + wbase);
      }
    } else {
      #pragma unroll
      for (int p = 0; p < 2; ++p) {
        int c = p*512 + t;
        int row = c >> 3;
        int colb = (c & 7) << 4;
        int gn = n0 + row;
        s16x8 s = {0,0,0,0,0,0,0,0};
        if (gn < V_) {
          const char* src = (const char*)Bf + ((size_t)gn*768 + k0)*4 + colb*2;
          float4 v0 = *(const float4*)src;
          float4 v1 = *(const float4*)(src + 16);
          s[0]=f2bf(v0.x); s[1]=f2bf(v0.y); s[2]=f2bf(v0.z); s[3]=f2bf(v0.w);
          s[4]=f2bf(v1.x); s[5]=f2bf(v1.y); s[6]=f2bf(v1.z); s[7]=f2bf(v1.w);
        }
        int dst = (row*128 + colb) ^ ((row & 7) << 4);
        *(s16x8*)((char*)lds_b + dst) = s;
      }
    }
    __syncthreads();
    #pragma unroll
    for (int ks = 0; ks < 2; ++ks) {
      s16x8 af[4], bfr[2];
      #pragma unroll
      for (int f = 0; f < 4; ++f) {
        int row = wm + f*16 + lrow;
        int off = (row*128 + ks*64 + lkb) ^ ((row & 7) << 4);
        af[f] = *(const s16x8*)((const char*)lds_a + off);
      }
      #pragma unroll
      for (int f = 0; f < 2; ++f) {
        int row = wn + f*16 + lrow;
        int off = (row*128 + ks*64 + lkb) ^ ((row & 7) << 4);
        bfr[f] = *(const s16x8*)((const char*)lds_b + off);
      }
      #pragma unroll
      for (int fm = 0; fm < 4; ++fm)
        #pragma unroll
        for (int fn = 0; fn < 2; ++fn)
          acc[fm][fn] = __builtin_amdgcn_mfma_f32_16x16x32_bf16(
              af[fm], bfr[fn], acc[fm][fn], 0, 0, 0);
    }
    __syncthreads();
  }
  // ---- epilogue: nt-store C + per-row (max,sumexp) partials ----
  const int crow = (lane >> 4) * 4;
  bool valid[2];
  #pragma unroll
  for (int fn = 0; fn < 2; ++fn) valid[fn] = (n0 + wn + fn*16 + lrow) < V_;
  float2* red = (float2*)lds_a;   // [128 rows][4 wave-cols] = 4KB
  #pragma unroll
  for (int fm = 0; fm < 4; ++fm) {
    #pragma unroll
    for (int r = 0; r < 4; ++r) {
      int rit = wm + fm*16 + crow + r;
      int row = m0 + rit;
      float m = -1e30f;
      #pragma unroll
      for (int fn = 0; fn < 2; ++fn) {
        if (valid[fn]) {
          float v = acc[fm][fn][r];
          __builtin_nontemporal_store(v, &C[(size_t)row*V_ + n0 + wn + fn*16 + lrow]);
          m = fmaxf(m, v);
        }
      }
      #pragma unroll
      for (int o = 1; o < 16; o <<= 1) m = fmaxf(m, __shfl_xor(m, o));
      float s = 0.f;
      #pragma unroll
      for (int fn = 0; fn < 2; ++fn)
        if (valid[fn]) s += __expf(acc[fm][fn][r] - m);
      #pragma unroll
      for (int o = 1; o < 16; o <<= 1) s += __shfl_xor(s, o);
      if (lrow == 0) red[rit*4 + (wid & 3)] = make_float2(m, s);
    }
  }
  __syncthreads();
  if (t < 128) {
    float M = -1e30f, S = 0.f;
    #pragma unroll
    for (int wc = 0; wc < 4; ++wc) {
      float2 p = red[t*4 + wc];
      float mn = fmaxf(M, p.x);
      S = S*__expf(M - mn) + p.y*__expf(p.x - mn);
      M = mn;
    }
    part[(size_t)(m0 + t)*NS2 + nt] = make_float2(M, S);
  }
}

// ------- combine per-tile partials -> per-row loss -------
__global__ void k_rowloss2(const float2* __restrict__ part,
                           const float* __restrict__ logits,
                           const int* __restrict__ tgt, float* __restrict__ rl) {
  int row = blockIdx.x;
  int lane = threadIdx.x;
  float M = -1e30f, S = 0.f;
  for (int i = lane; i < NS2; i += 64) {
    float2 p = part[(size_t)row*NS2 + i];
    float mn = fmaxf(M, p.x);
    S = S*__expf(M - mn) + p.y*__expf(p.x - mn);
    M = mn;
  }
  #pragma unroll
  for (int o = 1; o < 64; o <<= 1) {
    float Mo = __shfl_xor(M, o);
    float So = __shfl_xor(S, o);
    float mn = fmaxf(M, Mo);
    S = S*__expf(M - mn) + So*__expf(Mo - mn);
    M = mn;
  }
  if (lane == 0)
    rl[row] = (logf(S) + M) - logits[(size_t)row*V_ + tgt[row]];
}

// ------- flash attention (bf16 qkv, gl_lds staging for Q/K) -------
__global__ __launch_bounds__(256) void k_fattn(
    const __hip_bfloat16* __restrict__ qkv, const int* __restrict__ doc,
    __hip_bfloat16* __restrict__ y)
{
  __shared__ __align__(16) short q_lds[QBLK*64];
  __shared__ __align__(16) short k_lds[KVB*64];
  __shared__ __align__(16) short vt_lds[64*KVB];
  __shared__ __align__(16) short p_lds[4][16*64];
  __shared__ int doc_k[KVB];
  const int t = threadIdx.x;
  const int lane = t & 63;
  const int w = t >> 6;
  const int q0 = (gridDim.x - 1 - blockIdx.x) * QBLK;  // long blocks first
  const int h = blockIdx.y, b = blockIdx.z;
  const int lrow = lane & 15;
  const int lgrp = lane >> 4;
  const int crow = lgrp * 4;
  const int wbase = (t & 192) * 16;
  const short* qp = (const short*)qkv;

  #pragma unroll
  for (int p = 0; p < 2; ++p) {
    int c = p*256 + t;
    int row = c >> 3;
    int colb = (c & 7) << 4;
    const char* src = (const char*)(qp + ((size_t)(b*T_ + q0 + row))*QS3 + h*HD_)
                      + (colb ^ ((row & 7) << 4));
    gl_lds16(src, (char*)q_lds + p*4096 + wbase);
  }
  int docq[4];
  #pragma unroll
  for (int r = 0; r < 4; ++r)
    docq[r] = doc[b*T_ + q0 + w*16 + crow + r];
  __syncthreads();

  float m_r[4], l_r[4];
  #pragma unroll
  for (int r = 0; r < 4; ++r) { m_r[r] = -1e30f; l_r[r] = 0.f; }
  f32x4 o[4];
  #pragma unroll
  for (int fd = 0; fd < 4; ++fd) o[fd] = (f32x4){0.f,0.f,0.f,0.f};

  const int ntiles = q0/KVB + 1;
  for (int kt = 0; kt < ntiles; ++kt) {
    const int kv0 = kt * KVB;
    #pragma unroll
    for (int p = 0; p < 2; ++p) {
      int c = p*256 + t;
      int row = c >> 3;
      int colb = (c & 7) << 4;
      const char* src = (const char*)(qp + ((size_t)(b*T_ + kv0 + row))*QS3 + D_ + h*HD_)
                        + (colb ^ ((row & 7) << 4));
      gl_lds16(src, (char*)k_lds + p*4096 + wbase);
    }
    #pragma unroll
    for (int p = 0; p < 2; ++p) {
      int c = p*256 + t;
      int kvr = c >> 3, d0 = (c & 7)*8;
      s16x8 s = *(const s16x8*)(qp + ((size_t)(b*T_ + kv0 + kvr))*QS3 + 2*D_ + h*HD_ + d0);
      #pragma unroll
      for (int j = 0; j < 8; ++j) {
        int d = d0 + j;
        int off = (d*128 + kvr*2) ^ ((d & 7) << 4);
        *(short*)((char*)vt_lds + off) = s[j];
      }
    }
    if (t < KVB) doc_k[t] = doc[b*T_ + kv0 + t];
    __syncthreads();

    f32x4 sfr[4];
    #pragma unroll
    for (int fn = 0; fn < 4; ++fn) sfr[fn] = (f32x4){0.f,0.f,0.f,0.f};
    #pragma unroll
    for (int ks = 0; ks < 2; ++ks) {
      int arow = w*16 + lrow;
      s16x8 af = *(const s16x8*)((const char*)q_lds +
                 ((arow*128 + lgrp*16 + ks*64) ^ ((arow & 7) << 4)));
      #pragma unroll
      for (int fn = 0; fn < 4; ++fn) {
        int brow = fn*16 + lrow;
        s16x8 bf = *(const s16x8*)((const char*)k_lds +
                   ((brow*128 + lgrp*16 + ks*64) ^ ((brow & 7) << 4)));
        sfr[fn] = __builtin_amdgcn_mfma_f32_16x16x32_bf16(af, bf, sfr[fn], 0, 0, 0);
      }
    }
    int dk[4];
    #pragma unroll
    for (int fn = 0; fn < 4; ++fn) dk[fn] = doc_k[fn*16 + lrow];
    float rowmax[4] = {-1e30f, -1e30f, -1e30f, -1e30f};
    #pragma unroll
    for (int fn = 0; fn < 4; ++fn) {
      int col = kv0 + fn*16 + lrow;
      #pragma unroll
      for (int r = 0; r < 4; ++r) {
        int qrow = q0 + w*16 + crow + r;
        bool ok = (col <= qrow) && (dk[fn] == docq[r]);
        float v = ok ? sfr[fn][r] * 0.125f : -1e30f;
        sfr[fn][r] = v;
        rowmax[r] = fmaxf(rowmax[r], v);
      }
    }
    #pragma unroll
    for (int r = 0; r < 4; ++r) {
      float v = rowmax[r];
      #pragma unroll
      for (int off = 1; off < 16; off <<= 1) v = fmaxf(v, __shfl_xor(v, off));
      rowmax[r] = v;
    }
    float alpha[4], psum[4];
    #pragma unroll
    for (int r = 0; r < 4; ++r) {
      float mn = fmaxf(m_r[r], rowmax[r]);
      alpha[r] = __expf(m_r[r] - mn);
      m_r[r] = mn;
      psum[r] = 0.f;
    }
    #pragma unroll
    for (int fn = 0; fn < 4; ++fn) {
      #pragma unroll
      for (int r = 0; r < 4; ++r) {
        float sv = sfr[fn][r];
        float p = (sv < -5e29f) ? 0.f : __expf(sv - m_r[r]);
        psum[r] += p;
        int rl_ = crow + r;
        int off = (rl_*128 + (fn*16 + lrow)*2) ^ ((rl_ & 7) << 4);
        *(short*)((char*)p_lds[w] + off) = f2bf(p);
      }
    }
    #pragma unroll
    for (int r = 0; r < 4; ++r) {
      float v = psum[r];
      #pragma unroll
      for (int off = 1; off < 16; off <<= 1) v += __shfl_xor(v, off);
      l_r[r] = l_r[r]*alpha[r] + v;
    }
    #pragma unroll
    for (int fd = 0; fd < 4; ++fd)
      #pragma unroll
      for (int r = 0; r < 4; ++r)
        o[fd][r] *= alpha[r];
    // no barrier needed: p_lds[w] is wave-private (same-wave RAW via lgkmcnt);
    // vt_lds reads are protected by the staging barrier above.
    #pragma unroll
    for (int ks = 0; ks < 2; ++ks) {
      s16x8 af = *(const s16x8*)((const char*)p_lds[w] +
                 ((lrow*128 + lgrp*16 + ks*64) ^ ((lrow & 7) << 4)));
      #pragma unroll
      for (int fd = 0; fd < 4; ++fd) {
        int brow = fd*16 + lrow;
        s16x8 bf = *(const s16x8*)((const char*)vt_lds +
                   ((brow*128 + lgrp*16 + ks*64) ^ ((brow & 7) << 4)));
        o[fd] = __builtin_amdgcn_mfma_f32_16x16x32_bf16(af, bf, o[fd], 0, 0, 0);
      }
    }
    __syncthreads();
  }
  #pragma unroll
  for (int r = 0; r < 4; ++r) {
    float inv = 1.f / l_r[r];
    int rowg = b*T_ + q0 + w*16 + crow + r;
    #pragma unroll
    for (int fd = 0; fd < 4; ++fd) {
      int col = h*HD_ + fd*16 + lrow;
      y[(size_t)rowg*D_ + col] = __float2bfloat16(o[fd][r] * inv);
    }
  }
}

// ---------------- fallback per-row log-softmax ----------------
__global__ void k_rowloss(const float* __restrict__ logits,
                          const int* __restrict__ tgt, float* __restrict__ rl) {
  __shared__ float red[4];
  int row = blockIdx.x;
  const float* lr = logits + (size_t)row * V_;
  int tid = threadIdx.x;
  float m = -1e30f;
  for (int v = tid; v < V_; v += 256) m = fmaxf(m, lr[v]);
  #pragma unroll
  for (int o = 1; o < 64; o <<= 1) m = fmaxf(m, __shfl_xor(m, o));
  if ((tid & 63) == 0) red[tid >> 6] = m;
  __syncthreads();
  m = fmaxf(fmaxf(red[0], red[1]), fmaxf(red[2], red[3]));
  __syncthreads();
  float s = 0.f;
  for (int v = tid; v < V_; v += 256) s += __expf(lr[v] - m);
  #pragma unroll
  for (int o = 1; o < 64; o <<= 1) s += __shfl_xor(s, o);
  if ((tid & 63) == 0) red[tid >> 6] = s;
  __syncthreads();
  if (tid == 0) {
    s = red[0]+red[1]+red[2]+red[3];
    rl[row] = (logf(s) + m) - lr[tgt[row]];
  }
}

// ---------------- final loss = mean(rl) ----------------
__global__ void k_loss(const float* __restrict__ rl, float* __restrict__ out) {
  __shared__ float red[4];
  int tid = threadIdx.x;
  float s = 0.f;
  for (int i = tid; i < NTOK; i += 256) s += rl[i];
  #pragma unroll
  for (int o = 1; o < 64; o <<= 1) s += __shfl_xor(s, o);
  if ((tid & 63) == 0) red[tid >> 6] = s;
  __syncthreads();
  if (tid == 0) {
    s = red[0]+red[1]+red[2]+red[3];
    out[0] = s / (float)NTOK;
  }
}

extern "C" void kernel_launch(void* const* d_in, const int* in_sizes, int n_in,
                              void* d_out, int out_size, void* d_ws, size_t ws_size,
                              hipStream_t stream) {
  const int*   idx   = (const int*)d_in[0];
  const int*   tgt   = (const int*)d_in[1];
  const float* tok   = (const float*)d_in[2];
  const float* pos   = (const float*)d_in[3];
  const float* ln1_g = (const float*)d_in[4];
  const float* ln1_b = (const float*)d_in[5];
  const float* ln2_g = (const float*)d_in[6];
  const float* ln2_b = (const float*)d_in[7];
  const float* W_qkv = (const float*)d_in[8];
  const float* b_qkv = (const float*)d_in[9];
  const float* W_proj= (const float*)d_in[10];
  const float* b_proj= (const float*)d_in[11];
  const float* W_fc1 = (const float*)d_in[12];
  const float* b_fc1 = (const float*)d_in[13];
  const float* W_fc2 = (const float*)d_in[14];
  const float* b_fc2 = (const float*)d_in[15];
  const float* lnf_g = (const float*)d_in[16];
  const float* lnf_b = (const float*)d_in[17];

  float* out = (float*)d_out;

  char* ob = (char*)d_out;
  float*           x    = (float*)(ob + 0);
  __hip_bfloat16*  qkv  = (__hip_bfloat16*)(ob + (size_t)6291456);
  __hip_bfloat16*  y    = (__hip_bfloat16*)(ob + (size_t)15728640);
  __hip_bfloat16*  tff  = (__hip_bfloat16*)(ob + (size_t)18874368);
  __hip_bfloat16*  WTq  = (__hip_bfloat16*)(ob + (size_t)40894464);
  __hip_bfloat16*  WTp  = (__hip_bfloat16*)(ob + (size_t)62128128);
  __hip_bfloat16*  WT1  = (__hip_bfloat16*)(ob + (size_t)69206016);
  __hip_bfloat16*  WT2  = (__hip_bfloat16*)(ob + (size_t)97517568);  // ends 125,829,120

  char* wb = (char*)d_ws;
  __hip_bfloat16* h    = (__hip_bfloat16*)(wb + 0);                  // 3,145,728
  int*    doc  = (int*)  (wb + (size_t)3145728);                     // 8,192
  float*  rl   = (float*)(wb + (size_t)3153920);                     // 8,192
  float2* part = (float2*)(wb + (size_t)3162112);                    // 6,438,912
  __hip_bfloat16* tokh = (__hip_bfloat16*)(wb + (size_t)9601024);    // 77,194,752 (+128K slack)
  const size_t ws_need_part = (size_t)9601024;
  const size_t ws_need_tokh = (size_t)9601024 + 77194752 + 131072;   // 86,926,848
  const bool fused_loss = (ws_size >= ws_need_part);
  const bool use_tokh   = (ws_size >= ws_need_tokh);

  dim3 tb(32, 8);
  k_wt<<<dim3(2304/32, 768/32, L_), tb, 0, stream>>>(W_qkv,  WTq,  768, 2304);
  k_wt<<<dim3( 768/32, 768/32, L_), tb, 0, stream>>>(W_proj, WTp,  768,  768);
  k_wt<<<dim3(3072/32, 768/32, L_), tb, 0, stream>>>(W_fc1,  WT1,  768, 3072);
  k_wt<<<dim3( 768/32,3072/32, L_), tb, 0, stream>>>(W_fc2,  WT2, 3072,  768);
  if (use_tokh)
    k_cast_tok<<<2048, 256, 0, stream>>>(tok, tokh, (long)V_*768/8);

  k_embed<<<(NTOK*D_ + 255)/256, 256, 0, stream>>>(idx, tok, pos, x);
  k_docid<<<1, 64, 0, stream>>>(idx, doc);

  for (int l = 0; l < L_; ++l) {
    k_ln<<<NTOK, 64, 0, stream>>>(x, ln1_g + l*D_, ln1_b + l*D_, h);
    k_mfma_nt<<<dim3(2304/128, NTOK/128), 512, 0, stream>>>(
        h, WTq + (size_t)l*2304*768, nullptr, b_qkv + (size_t)l*2304, nullptr,
        nullptr, qkv, NTOK, 2304, 768, 0);
    k_fattn<<<dim3(T_/QBLK, H_, B_), 256, 0, stream>>>(qkv, doc, y);
    k_mfma_nt64<<<dim3(768/64, NTOK/64), 256, 0, stream>>>(
        y, WTp + (size_t)l*768*768, b_proj + (size_t)l*768, x, x,
        NTOK, 768, 768);
    k_ln<<<NTOK, 64, 0, stream>>>(x, ln2_g + l*D_, ln2_b + l*D_, h);
    k_mfma_nt<<<dim3(3072/128, NTOK/128), 512, 0, stream>>>(
        h, WT1 + (size_t)l*3072*768, nullptr, b_fc1 + (size_t)l*3072, nullptr,
        nullptr, tff, NTOK, 3072, 768, 1);
    k_mfma_nt64<<<dim3(768/64, NTOK/64), 256, 0, stream>>>(
        tff, WT2 + (size_t)l*768*3072, b_fc2 + (size_t)l*768, x, x,
        NTOK, 768, 3072);
  }
  k_ln<<<NTOK, 64, 0, stream>>>(x, lnf_g, lnf_b, h);

  if (fused_loss) {
    k_logits<<<NS2*16, 512, 0, stream>>>(
        h, use_tokh ? tokh : nullptr, tok, out, part);
    k_rowloss2<<<NTOK, 64, 0, stream>>>(part, out, tgt, rl);
  } else {
    k_mfma_nt<<<dim3((V_ + 127)/128, NTOK/128), 512, 0, stream>>>(
        h, nullptr, tok, nullptr, nullptr, out, nullptr, NTOK, V_, 768, 0);
    k_rowloss<<<NTOK, 256, 0, stream>>>(out, tgt, rl);
  }
  k_loss<<<1, 256, 0, stream>>>(rl, out + (size_t)NTOK*V_);
}